// Round 1
// baseline (12954.730 us; speedup 1.0000x reference)
//
#include <hip/hip_runtime.h>
#include <math.h>

#define NN   50000
#define TT   16
#define EE   800000
#define BB   2000
#define EMBD 32
#define ENC  64
#define DEC  128
#define OUTL 25
#define BN_EPS 1e-5f

__device__ __forceinline__ float lrelu(float v){ return v >= 0.f ? v : 0.1f*v; }
__device__ __forceinline__ float sigmoidf_(float v){ return 1.f/(1.f+expf(-v)); }
__device__ __forceinline__ float softplusf_(float v){
    return v > 0.f ? v + log1pf(expf(-v)) : log1pf(expf(v));
}
__device__ __forceinline__ void fma44(float4& a, float4 w, float4 h){
    a.x += w.x*h.x; a.y += w.y*h.y; a.z += w.z*h.z; a.w += w.w*h.w;
}
__device__ __forceinline__ void fma4s(float4& a, float4 w, float b0,float b1,float b2,float b3){
    a.x += w.x*b0; a.y += w.y*b1; a.z += w.z*b2; a.w += w.w*b3;
}
__device__ __forceinline__ float hsum(float4 a){ return (a.x+a.y)+(a.z+a.w); }

// ---------------- GRU encoder: thread per node ----------------
__global__ __launch_bounds__(64) void encoder_kernel(
    const float* __restrict__ x,
    const float* __restrict__ Wip, const float* __restrict__ bip,
    const float* __restrict__ Wih, const float* __restrict__ Whh,
    const float* __restrict__ bih, const float* __restrict__ bhh,
    const float* __restrict__ Wdyn, const float* __restrict__ bdyn,
    float* __restrict__ hist)
{
    __shared__ float hbuf[ENC*64];   // per-thread column: resolves dynamic-index h[j]
    const int tid = threadIdx.x;
    const int n = blockIdx.x*64 + tid;
    const bool act = (n < NN);

    float h[ENC];
#pragma unroll
    for (int j=0;j<ENC;j++){ h[j]=0.f; hbuf[j*64+tid]=0.f; }

    float emb[EMBD];
    for (int t=0;t<TT;t++){
        float x0=0.f,x1=0.f;
        if (act){ x0=x[((size_t)n*TT+t)*2]; x1=x[((size_t)n*TT+t)*2+1]; }
#pragma unroll
        for (int j=0;j<EMBD;j++) emb[j] = lrelu(Wip[2*j]*x0 + Wip[2*j+1]*x1 + bip[j]);
#pragma unroll 1
        for (int j=0;j<ENC;j++){
            const float4* wr = (const float4*)(Wih + (size_t)(j)*EMBD);
            const float4* wz = (const float4*)(Wih + (size_t)(ENC+j)*EMBD);
            const float4* wn = (const float4*)(Wih + (size_t)(2*ENC+j)*EMBD);
            float4 ar={0,0,0,0}, az={0,0,0,0}, ani={0,0,0,0}, anh={0,0,0,0};
#pragma unroll
            for (int k=0;k<EMBD/4;k++){
                fma4s(ar,  wr[k], emb[4*k],emb[4*k+1],emb[4*k+2],emb[4*k+3]);
                fma4s(az,  wz[k], emb[4*k],emb[4*k+1],emb[4*k+2],emb[4*k+3]);
                fma4s(ani, wn[k], emb[4*k],emb[4*k+1],emb[4*k+2],emb[4*k+3]);
            }
            const float4* vr = (const float4*)(Whh + (size_t)(j)*ENC);
            const float4* vz = (const float4*)(Whh + (size_t)(ENC+j)*ENC);
            const float4* vn = (const float4*)(Whh + (size_t)(2*ENC+j)*ENC);
#pragma unroll
            for (int k=0;k<ENC/4;k++){
                fma4s(ar,  vr[k], h[4*k],h[4*k+1],h[4*k+2],h[4*k+3]);
                fma4s(az,  vz[k], h[4*k],h[4*k+1],h[4*k+2],h[4*k+3]);
                fma4s(anh, vn[k], h[4*k],h[4*k+1],h[4*k+2],h[4*k+3]);
            }
            float r  = sigmoidf_(hsum(ar) + bih[j] + bhh[j]);
            float z  = sigmoidf_(hsum(az) + bih[ENC+j] + bhh[ENC+j]);
            float nn2 = tanhf(hsum(ani) + bih[2*ENC+j] + r*(hsum(anh) + bhh[2*ENC+j]));
            float hp = hbuf[j*64+tid];                 // old h[j]
            hbuf[j*64+tid] = (1.f-z)*nn2 + z*hp;       // new h[j]
        }
#pragma unroll
        for (int j=0;j<ENC;j++) h[j] = hbuf[j*64+tid];
    }
    if (act){
#pragma unroll
        for (int j=0;j<ENC;j++) h[j] = lrelu(h[j]);
#pragma unroll 1
        for (int j=0;j<ENC;j++){
            const float4* wd = (const float4*)(Wdyn + (size_t)j*ENC);
            float4 a={0,0,0,0};
#pragma unroll
            for (int k=0;k<ENC/4;k++) fma4s(a, wd[k], h[4*k],h[4*k+1],h[4*k+2],h[4*k+3]);
            hist[(size_t)n*ENC+j] = lrelu(hsum(a) + bdyn[j]);
        }
    }
}

// ---------------- CGConv node projections: A = W[:,0:64] x, B = W[:,64:128] x ----------------
#define PROJ_NODES 32
__global__ __launch_bounds__(256) void proj_kernel(
    const float* __restrict__ xin,
    const float* __restrict__ Wf, const float* __restrict__ Ws,
    float* __restrict__ Af, float* __restrict__ Bf,
    float* __restrict__ As, float* __restrict__ Bs)
{
    __shared__ float sW[2][ENC*ENC];          // transposed: [m][k*64+c]
    __shared__ float sx[PROJ_NODES*ENC];
    const int tid = threadIdx.x;
    const int n0 = blockIdx.x*PROJ_NODES;
    for (int idx=tid; idx<PROJ_NODES*ENC; idx+=256){
        int nn = idx>>6, k = idx&63;
        int n = n0+nn;
        sx[idx] = (n<NN) ? xin[(size_t)n*ENC+k] : 0.f;
    }
    const int c = tid&63, q = tid>>6;
#pragma unroll
    for (int p=0;p<2;p++){
        const float* W = p ? Ws : Wf;
        float* oD = p ? As : Af;
        float* oS = p ? Bs : Bf;
        __syncthreads();
        for (int idx=tid; idx<2*ENC*ENC; idx+=256){
            int m = idx>>12, r = idx&4095;
            int cc = r>>6, k = r&63;
            sW[m][k*64+cc] = W[cc*130 + m*64 + k];
        }
        __syncthreads();
        for (int nn=q; nn<PROJ_NODES; nn+=4){
            int n = n0+nn;
            if (n>=NN) break;
            float aD=0.f, aS=0.f;
#pragma unroll
            for (int k=0;k<ENC;k++){
                float xv = sx[nn*ENC+k];
                aD += sW[0][k*64+c]*xv;
                aS += sW[1][k*64+c]*xv;
            }
            oD[(size_t)n*ENC+c]=aD;
            oS[(size_t)n*ENC+c]=aS;
        }
    }
}

// ---------------- CGConv edge kernel: wave per edge (lane = channel), atomic scatter ----------------
__global__ __launch_bounds__(256) void edge_kernel(
    const int* __restrict__ ei, const float* __restrict__ ea,
    const float* __restrict__ Wf, const float* __restrict__ bf,
    const float* __restrict__ Ws, const float* __restrict__ bs,
    const float* __restrict__ Af, const float* __restrict__ Bf,
    const float* __restrict__ As, const float* __restrict__ Bs,
    float* __restrict__ agg)
{
    __shared__ float cf0[64], cf1[64], cfb[64], cs0[64], cs1[64], csb[64];
    const int tid=threadIdx.x;
    if (tid<64){
        cf0[tid]=Wf[tid*130+128]; cf1[tid]=Wf[tid*130+129]; cfb[tid]=bf[tid];
        cs0[tid]=Ws[tid*130+128]; cs1[tid]=Ws[tid*130+129]; csb[tid]=bs[tid];
    }
    __syncthreads();
    const int wid = tid>>6, c = tid&63;
    const int ebase = blockIdx.x*16 + wid*4;
#pragma unroll 1
    for (int i=0;i<4;i++){
        int e = ebase + i;
        if (e >= EE) break;
        int src = ei[e], dst = ei[EE+e];
        float e0 = ea[2*(size_t)e], e1 = ea[2*(size_t)e+1];
        float gf = Af[(size_t)dst*64+c] + Bf[(size_t)src*64+c] + cf0[c]*e0 + cf1[c]*e1 + cfb[c];
        float gs = As[(size_t)dst*64+c] + Bs[(size_t)src*64+c] + cs0[c]*e0 + cs1[c]*e1 + csb[c];
        float m = sigmoidf_(gf)*softplusf_(gs);
        atomicAdd(&agg[(size_t)dst*64+c], m);
    }
}

// ---------------- BN (inference) + residual ----------------
__global__ void bnres_kernel(const float* __restrict__ xin, const float* __restrict__ agg,
    const float* __restrict__ gamma, const float* __restrict__ beta,
    const float* __restrict__ mean, const float* __restrict__ var,
    float* __restrict__ outp)
{
    size_t i = (size_t)blockIdx.x*256 + threadIdx.x;
    if (i >= (size_t)NN*ENC) return;
    int c = (int)(i&63);
    float a = (agg[i]-mean[c])*rsqrtf(var[c]+BN_EPS)*gamma[c] + beta[c];
    outp[i] = xin[i] + a;
}

// ---------------- target gather + nbrs linear + concat ----------------
__global__ __launch_bounds__(256) void target_kernel(
    const float* __restrict__ hist, const float* __restrict__ f2,
    const int* __restrict__ tgt,
    const float* __restrict__ Wn, const float* __restrict__ bn_,
    float* __restrict__ enc)
{
    const int tid=threadIdx.x;
    const int c = tid&63, q = tid>>6;
    const int b = blockIdx.x*4 + q;
    if (b>=BB) return;
    const int n = tgt[b];
    float a = bn_[c];
#pragma unroll
    for (int k=0;k<ENC;k++) a += Wn[c*64+k]*f2[(size_t)n*64+k];
    enc[(size_t)b*128 + 64 + c] = lrelu(a);
    enc[(size_t)b*128 + c]      = hist[(size_t)n*64+c];
}

// ---------------- transpose lstm0_Wih [512][128] -> [128][512] ----------------
__global__ void transpose_w0(const float* __restrict__ W, float* __restrict__ WT){
    int i = blockIdx.x*256+threadIdx.x;
    if (i >= 512*DEC) return;
    int g = i>>7, k = i&127;
    WT[k*512+g] = W[i];
}

// ---------------- gi0 = enc @ Wih0^T + bih0 + bhh0 (time-invariant) ----------------
__global__ __launch_bounds__(512) void gi0_kernel(
    const float* __restrict__ enc, const float* __restrict__ W0T,
    const float* __restrict__ bih0, const float* __restrict__ bhh0,
    float* __restrict__ gi0)
{
    __shared__ float se[128];
    const int b = blockIdx.x, g = threadIdx.x;
    if (g < 128) se[g] = enc[(size_t)b*128+g];
    __syncthreads();
    float a = bih0[g]+bhh0[g];
#pragma unroll 4
    for (int k=0;k<128;k++) a += W0T[k*512+g]*se[k];
    gi0[(size_t)b*512+g] = a;
}

// ---------------- 2-layer LSTM decoder, persistent over 25 steps ----------------
#define MB 8
#define HP 132   // padded stride: 132*4B = 528 = 33*16 -> float4-aligned, conflict-free
__global__ __launch_bounds__(256) void lstm_kernel(
    const float* __restrict__ gi0,
    const float* __restrict__ Whh0,
    const float* __restrict__ Wih1, const float* __restrict__ Whh1,
    const float* __restrict__ bih1, const float* __restrict__ bhh1,
    const float* __restrict__ Wop, const float* __restrict__ bop,
    float* __restrict__ outp)
{
    __shared__ float sh0a[MB*HP], sh0b[MB*HP], sh1a[MB*HP], sh1b[MB*HP];
    __shared__ float sc0[MB*HP], sc1[MB*HP];
    __shared__ float sgi[MB*512];
    __shared__ float sb1[512];
    const int tid = threadIdx.x;
    const int b = tid & (MB-1);
    const int jg = tid >> 3;            // 0..31, each owns 4 hidden units
    const int b0 = blockIdx.x*MB;
    for (int i=tid;i<MB*512;i+=256) sgi[i] = gi0[(size_t)b0*512 + i];
    for (int i=tid;i<512;i+=256) sb1[i] = bih1[i]+bhh1[i];
    for (int i=tid;i<MB*HP;i+=256){ sh0a[i]=0.f; sh0b[i]=0.f; sh1a[i]=0.f; sh1b[i]=0.f; sc0[i]=0.f; sc1[i]=0.f; }
    __syncthreads();
    float* h0in=sh0a; float* h0out=sh0b; float* h1in=sh1a; float* h1out=sh1b;
    const float bo0 = bop[0], bo1 = bop[1];
    for (int t=0;t<OUTL;t++){
        // ---- layer 0 (input part precomputed in sgi) ----
#pragma unroll 1
        for (int i=0;i<4;i++){
            int j = jg*4+i;
            const float4* wi = (const float4*)(Whh0 + (size_t)j*DEC);
            const float4* wf = (const float4*)(Whh0 + (size_t)(DEC+j)*DEC);
            const float4* wg = (const float4*)(Whh0 + (size_t)(2*DEC+j)*DEC);
            const float4* wo = (const float4*)(Whh0 + (size_t)(3*DEC+j)*DEC);
            const float4* hp = (const float4*)(h0in + b*HP);
            float4 ai={0,0,0,0}, af={0,0,0,0}, ag={0,0,0,0}, ao={0,0,0,0};
#pragma unroll
            for (int k=0;k<32;k++){
                float4 hv = hp[k];
                fma44(ai, wi[k], hv); fma44(af, wf[k], hv);
                fma44(ag, wg[k], hv); fma44(ao, wo[k], hv);
            }
            float gi_=sgi[b*512+j]        +hsum(ai);
            float gf_=sgi[b*512+DEC+j]    +hsum(af);
            float gg_=sgi[b*512+2*DEC+j]  +hsum(ag);
            float go_=sgi[b*512+3*DEC+j]  +hsum(ao);
            float cc = sigmoidf_(gf_)*sc0[b*HP+j] + sigmoidf_(gi_)*tanhf(gg_);
            sc0[b*HP+j]=cc;
            h0out[b*HP+j] = sigmoidf_(go_)*tanhf(cc);
        }
        __syncthreads();
        // ---- layer 1 ----
#pragma unroll 1
        for (int i=0;i<4;i++){
            int j = jg*4+i;
            const float4* xi = (const float4*)(Wih1 + (size_t)j*DEC);
            const float4* xf = (const float4*)(Wih1 + (size_t)(DEC+j)*DEC);
            const float4* xg = (const float4*)(Wih1 + (size_t)(2*DEC+j)*DEC);
            const float4* xo = (const float4*)(Wih1 + (size_t)(3*DEC+j)*DEC);
            const float4* ri = (const float4*)(Whh1 + (size_t)j*DEC);
            const float4* rf = (const float4*)(Whh1 + (size_t)(DEC+j)*DEC);
            const float4* rg = (const float4*)(Whh1 + (size_t)(2*DEC+j)*DEC);
            const float4* ro = (const float4*)(Whh1 + (size_t)(3*DEC+j)*DEC);
            const float4* hx = (const float4*)(h0out + b*HP);
            const float4* hr = (const float4*)(h1in + b*HP);
            float4 ai={0,0,0,0}, af={0,0,0,0}, ag={0,0,0,0}, ao={0,0,0,0};
#pragma unroll
            for (int k=0;k<32;k++){
                float4 hv = hx[k];
                fma44(ai, xi[k], hv); fma44(af, xf[k], hv);
                fma44(ag, xg[k], hv); fma44(ao, xo[k], hv);
                float4 rv = hr[k];
                fma44(ai, ri[k], rv); fma44(af, rf[k], rv);
                fma44(ag, rg[k], rv); fma44(ao, ro[k], rv);
            }
            float gi_=sb1[j]        +hsum(ai);
            float gf_=sb1[DEC+j]    +hsum(af);
            float gg_=sb1[2*DEC+j]  +hsum(ag);
            float go_=sb1[3*DEC+j]  +hsum(ao);
            float cc = sigmoidf_(gf_)*sc1[b*HP+j] + sigmoidf_(gi_)*tanhf(gg_);
            sc1[b*HP+j]=cc;
            h1out[b*HP+j] = sigmoidf_(go_)*tanhf(cc);
        }
        __syncthreads();
        // ---- output projection for this step ----
        if (tid < 16){
            int bb=tid>>1, o=tid&1;
            const float4* hv=(const float4*)(h1out + bb*HP);
            const float4* wv=(const float4*)(Wop + o*DEC);
            float4 a={0,0,0,0};
#pragma unroll
            for (int k=0;k<32;k++) fma44(a, wv[k], hv[k]);
            outp[(size_t)(b0+bb)*(OUTL*2) + t*2 + o] = hsum(a) + (o ? bo1 : bo0);
        }
        float* tp;
        tp=h0in; h0in=h0out; h0out=tp;
        tp=h1in; h1in=h1out; h1out=tp;
    }
}

extern "C" void kernel_launch(void* const* d_in, const int* in_sizes, int n_in,
                              void* d_out, int out_size, void* d_ws, size_t ws_size,
                              hipStream_t stream)
{
    const float* x    = (const float*)d_in[0];
    const int*   ei   = (const int*)d_in[1];
    const float* ea   = (const float*)d_in[2];
    const int*   tgt  = (const int*)d_in[3];
    const float* Wip  = (const float*)d_in[4];
    const float* bip  = (const float*)d_in[5];
    const float* gWih = (const float*)d_in[6];
    const float* gWhh = (const float*)d_in[7];
    const float* gbih = (const float*)d_in[8];
    const float* gbhh = (const float*)d_in[9];
    const float* Wdyn = (const float*)d_in[10];
    const float* bdyn = (const float*)d_in[11];
    const float* c1Wf=(const float*)d_in[12]; const float* c1bf=(const float*)d_in[13];
    const float* c1Ws=(const float*)d_in[14]; const float* c1bs=(const float*)d_in[15];
    const float* c1g =(const float*)d_in[16]; const float* c1b =(const float*)d_in[17];
    const float* c1m =(const float*)d_in[18]; const float* c1v =(const float*)d_in[19];
    const float* c2Wf=(const float*)d_in[20]; const float* c2bf=(const float*)d_in[21];
    const float* c2Ws=(const float*)d_in[22]; const float* c2bs=(const float*)d_in[23];
    const float* c2g =(const float*)d_in[24]; const float* c2b =(const float*)d_in[25];
    const float* c2m =(const float*)d_in[26]; const float* c2v =(const float*)d_in[27];
    const float* Wn  =(const float*)d_in[28]; const float* bn_ =(const float*)d_in[29];
    const float* l0Wih=(const float*)d_in[30]; const float* l0Whh=(const float*)d_in[31];
    const float* l0bih=(const float*)d_in[32]; const float* l0bhh=(const float*)d_in[33];
    const float* l1Wih=(const float*)d_in[34]; const float* l1Whh=(const float*)d_in[35];
    const float* l1bih=(const float*)d_in[36]; const float* l1bhh=(const float*)d_in[37];
    const float* Wop =(const float*)d_in[38]; const float* bop=(const float*)d_in[39];

    float* ws = (float*)d_ws;
    size_t o = 0;
    float* hist = ws + o; o += (size_t)NN*ENC;
    float* f1   = ws + o; o += (size_t)NN*ENC;
    float* f2   = ws + o; o += (size_t)NN*ENC;
    float* Af   = ws + o; o += (size_t)NN*ENC;
    float* Bf   = ws + o; o += (size_t)NN*ENC;
    float* As   = ws + o; o += (size_t)NN*ENC;
    float* Bs   = ws + o; o += (size_t)NN*ENC;
    float* agg  = ws + o; o += (size_t)NN*ENC;
    float* enc  = ws + o; o += (size_t)BB*2*ENC;
    float* gi0  = ws + o; o += (size_t)BB*4*DEC;
    float* W0T  = ws + o; o += (size_t)128*512;

    // --- history encoder ---
    encoder_kernel<<<(NN+63)/64, 64, 0, stream>>>(x, Wip,bip,gWih,gWhh,gbih,gbhh,Wdyn,bdyn,hist);

    // --- CGConv 1 ---
    proj_kernel<<<(NN+PROJ_NODES-1)/PROJ_NODES, 256, 0, stream>>>(hist, c1Wf, c1Ws, Af,Bf,As,Bs);
    (void)hipMemsetAsync(agg, 0, (size_t)NN*ENC*sizeof(float), stream);
    edge_kernel<<<EE/16, 256, 0, stream>>>(ei, ea, c1Wf,c1bf,c1Ws,c1bs, Af,Bf,As,Bs, agg);
    bnres_kernel<<<(NN*ENC)/256, 256, 0, stream>>>(hist, agg, c1g,c1b,c1m,c1v, f1);

    // --- CGConv 2 ---
    proj_kernel<<<(NN+PROJ_NODES-1)/PROJ_NODES, 256, 0, stream>>>(f1, c2Wf, c2Ws, Af,Bf,As,Bs);
    (void)hipMemsetAsync(agg, 0, (size_t)NN*ENC*sizeof(float), stream);
    edge_kernel<<<EE/16, 256, 0, stream>>>(ei, ea, c2Wf,c2bf,c2Ws,c2bs, Af,Bf,As,Bs, agg);
    bnres_kernel<<<(NN*ENC)/256, 256, 0, stream>>>(f1, agg, c2g,c2b,c2m,c2v, f2);

    // --- target encoding ---
    target_kernel<<<(BB+3)/4, 256, 0, stream>>>(hist, f2, tgt, Wn, bn_, enc);

    // --- LSTM decoder ---
    transpose_w0<<<(512*DEC+255)/256, 256, 0, stream>>>(l0Wih, W0T);
    gi0_kernel<<<BB, 512, 0, stream>>>(enc, W0T, l0bih, l0bhh, gi0);
    lstm_kernel<<<BB/MB, 256, 0, stream>>>(gi0, l0Whh, l1Wih, l1Whh, l1bih, l1bhh, Wop, bop, (float*)d_out);
}

// Round 2
// 4835.639 us; speedup vs baseline: 2.6790x; 2.6790x over previous
//
#include <hip/hip_runtime.h>
#include <math.h>

#define NN   50000
#define TT   16
#define EE   800000
#define BB   2000
#define EMBD 32
#define ENC  64
#define DEC  128
#define OUTL 25
#define BN_EPS 1e-5f

__device__ __forceinline__ float lrelu(float v){ return v >= 0.f ? v : 0.1f*v; }
__device__ __forceinline__ float sigmoidf_(float v){ return 1.f/(1.f+expf(-v)); }
__device__ __forceinline__ float softplusf_(float v){
    return v > 0.f ? v + log1pf(expf(-v)) : log1pf(expf(v));
}
__device__ __forceinline__ void fma44(float4& a, float4 w, float4 h){
    a.x += w.x*h.x; a.y += w.y*h.y; a.z += w.z*h.z; a.w += w.w*h.w;
}
__device__ __forceinline__ void fma4s(float4& a, float4 w, float b0,float b1,float b2,float b3){
    a.x += w.x*b0; a.y += w.y*b1; a.z += w.z*b2; a.w += w.w*b3;
}
__device__ __forceinline__ float hsum(float4 a){ return (a.x+a.y)+(a.z+a.w); }
__device__ __forceinline__ float dot4(float4 w, float4 h){ return (w.x*h.x+w.y*h.y)+(w.z*h.z+w.w*h.w); }

// ---------------- GRU encoder: thread per node ----------------
__global__ __launch_bounds__(64) void encoder_kernel(
    const float* __restrict__ x,
    const float* __restrict__ Wip, const float* __restrict__ bip,
    const float* __restrict__ Wih, const float* __restrict__ Whh,
    const float* __restrict__ bih, const float* __restrict__ bhh,
    const float* __restrict__ Wdyn, const float* __restrict__ bdyn,
    float* __restrict__ hist)
{
    __shared__ float hbuf[ENC*64];   // per-thread column: resolves dynamic-index h[j]
    const int tid = threadIdx.x;
    const int n = blockIdx.x*64 + tid;
    const bool act = (n < NN);

    float h[ENC];
#pragma unroll
    for (int j=0;j<ENC;j++){ h[j]=0.f; hbuf[j*64+tid]=0.f; }

    float emb[EMBD];
    for (int t=0;t<TT;t++){
        float x0=0.f,x1=0.f;
        if (act){ x0=x[((size_t)n*TT+t)*2]; x1=x[((size_t)n*TT+t)*2+1]; }
#pragma unroll
        for (int j=0;j<EMBD;j++) emb[j] = lrelu(Wip[2*j]*x0 + Wip[2*j+1]*x1 + bip[j]);
#pragma unroll 1
        for (int j=0;j<ENC;j++){
            const float4* wr = (const float4*)(Wih + (size_t)(j)*EMBD);
            const float4* wz = (const float4*)(Wih + (size_t)(ENC+j)*EMBD);
            const float4* wn = (const float4*)(Wih + (size_t)(2*ENC+j)*EMBD);
            float4 ar={0,0,0,0}, az={0,0,0,0}, ani={0,0,0,0}, anh={0,0,0,0};
#pragma unroll
            for (int k=0;k<EMBD/4;k++){
                fma4s(ar,  wr[k], emb[4*k],emb[4*k+1],emb[4*k+2],emb[4*k+3]);
                fma4s(az,  wz[k], emb[4*k],emb[4*k+1],emb[4*k+2],emb[4*k+3]);
                fma4s(ani, wn[k], emb[4*k],emb[4*k+1],emb[4*k+2],emb[4*k+3]);
            }
            const float4* vr = (const float4*)(Whh + (size_t)(j)*ENC);
            const float4* vz = (const float4*)(Whh + (size_t)(ENC+j)*ENC);
            const float4* vn = (const float4*)(Whh + (size_t)(2*ENC+j)*ENC);
#pragma unroll
            for (int k=0;k<ENC/4;k++){
                fma4s(ar,  vr[k], h[4*k],h[4*k+1],h[4*k+2],h[4*k+3]);
                fma4s(az,  vz[k], h[4*k],h[4*k+1],h[4*k+2],h[4*k+3]);
                fma4s(anh, vn[k], h[4*k],h[4*k+1],h[4*k+2],h[4*k+3]);
            }
            float r  = sigmoidf_(hsum(ar) + bih[j] + bhh[j]);
            float z  = sigmoidf_(hsum(az) + bih[ENC+j] + bhh[ENC+j]);
            float nn2 = tanhf(hsum(ani) + bih[2*ENC+j] + r*(hsum(anh) + bhh[2*ENC+j]));
            float hp = hbuf[j*64+tid];                 // old h[j]
            hbuf[j*64+tid] = (1.f-z)*nn2 + z*hp;       // new h[j]
        }
#pragma unroll
        for (int j=0;j<ENC;j++) h[j] = hbuf[j*64+tid];
    }
    if (act){
#pragma unroll
        for (int j=0;j<ENC;j++) h[j] = lrelu(h[j]);
#pragma unroll 1
        for (int j=0;j<ENC;j++){
            const float4* wd = (const float4*)(Wdyn + (size_t)j*ENC);
            float4 a={0,0,0,0};
#pragma unroll
            for (int k=0;k<ENC/4;k++) fma4s(a, wd[k], h[4*k],h[4*k+1],h[4*k+2],h[4*k+3]);
            hist[(size_t)n*ENC+j] = lrelu(hsum(a) + bdyn[j]);
        }
    }
}

// ---------------- CGConv node projections: A = W[:,0:64] x, B = W[:,64:128] x ----------------
#define PROJ_NODES 32
__global__ __launch_bounds__(256) void proj_kernel(
    const float* __restrict__ xin,
    const float* __restrict__ Wf, const float* __restrict__ Ws,
    float* __restrict__ Af, float* __restrict__ Bf,
    float* __restrict__ As, float* __restrict__ Bs)
{
    __shared__ float sW[2][ENC*ENC];          // transposed: [m][k*64+c]
    __shared__ float sx[PROJ_NODES*ENC];
    const int tid = threadIdx.x;
    const int n0 = blockIdx.x*PROJ_NODES;
    for (int idx=tid; idx<PROJ_NODES*ENC; idx+=256){
        int nn = idx>>6, k = idx&63;
        int n = n0+nn;
        sx[idx] = (n<NN) ? xin[(size_t)n*ENC+k] : 0.f;
    }
    const int c = tid&63, q = tid>>6;
#pragma unroll
    for (int p=0;p<2;p++){
        const float* W = p ? Ws : Wf;
        float* oD = p ? As : Af;
        float* oS = p ? Bs : Bf;
        __syncthreads();
        for (int idx=tid; idx<2*ENC*ENC; idx+=256){
            int m = idx>>12, r = idx&4095;
            int cc = r>>6, k = r&63;
            sW[m][k*64+cc] = W[cc*130 + m*64 + k];
        }
        __syncthreads();
        for (int nn=q; nn<PROJ_NODES; nn+=4){
            int n = n0+nn;
            if (n>=NN) break;
            float aD=0.f, aS=0.f;
#pragma unroll
            for (int k=0;k<ENC;k++){
                float xv = sx[nn*ENC+k];
                aD += sW[0][k*64+c]*xv;
                aS += sW[1][k*64+c]*xv;
            }
            oD[(size_t)n*ENC+c]=aD;
            oS[(size_t)n*ENC+c]=aS;
        }
    }
}

// ---------------- CGConv edge kernel: wave per edge (lane = channel), atomic scatter ----------------
__global__ __launch_bounds__(256) void edge_kernel(
    const int* __restrict__ ei, const float* __restrict__ ea,
    const float* __restrict__ Wf, const float* __restrict__ bf,
    const float* __restrict__ Ws, const float* __restrict__ bs,
    const float* __restrict__ Af, const float* __restrict__ Bf,
    const float* __restrict__ As, const float* __restrict__ Bs,
    float* __restrict__ agg)
{
    __shared__ float cf0[64], cf1[64], cfb[64], cs0[64], cs1[64], csb[64];
    const int tid=threadIdx.x;
    if (tid<64){
        cf0[tid]=Wf[tid*130+128]; cf1[tid]=Wf[tid*130+129]; cfb[tid]=bf[tid];
        cs0[tid]=Ws[tid*130+128]; cs1[tid]=Ws[tid*130+129]; csb[tid]=bs[tid];
    }
    __syncthreads();
    const int wid = tid>>6, c = tid&63;
    const int ebase = blockIdx.x*16 + wid*4;
#pragma unroll 1
    for (int i=0;i<4;i++){
        int e = ebase + i;
        if (e >= EE) break;
        int src = ei[e], dst = ei[EE+e];
        float e0 = ea[2*(size_t)e], e1 = ea[2*(size_t)e+1];
        float gf = Af[(size_t)dst*64+c] + Bf[(size_t)src*64+c] + cf0[c]*e0 + cf1[c]*e1 + cfb[c];
        float gs = As[(size_t)dst*64+c] + Bs[(size_t)src*64+c] + cs0[c]*e0 + cs1[c]*e1 + csb[c];
        float m = sigmoidf_(gf)*softplusf_(gs);
        atomicAdd(&agg[(size_t)dst*64+c], m);
    }
}

// ---------------- BN (inference) + residual ----------------
__global__ void bnres_kernel(const float* __restrict__ xin, const float* __restrict__ agg,
    const float* __restrict__ gamma, const float* __restrict__ beta,
    const float* __restrict__ mean, const float* __restrict__ var,
    float* __restrict__ outp)
{
    size_t i = (size_t)blockIdx.x*256 + threadIdx.x;
    if (i >= (size_t)NN*ENC) return;
    int c = (int)(i&63);
    float a = (agg[i]-mean[c])*rsqrtf(var[c]+BN_EPS)*gamma[c] + beta[c];
    outp[i] = xin[i] + a;
}

// ---------------- target gather + nbrs linear + concat ----------------
__global__ __launch_bounds__(256) void target_kernel(
    const float* __restrict__ hist, const float* __restrict__ f2,
    const int* __restrict__ tgt,
    const float* __restrict__ Wn, const float* __restrict__ bn_,
    float* __restrict__ enc)
{
    const int tid=threadIdx.x;
    const int c = tid&63, q = tid>>6;
    const int b = blockIdx.x*4 + q;
    if (b>=BB) return;
    const int n = tgt[b];
    float a = bn_[c];
#pragma unroll
    for (int k=0;k<ENC;k++) a += Wn[c*64+k]*f2[(size_t)n*64+k];
    enc[(size_t)b*128 + 64 + c] = lrelu(a);
    enc[(size_t)b*128 + c]      = hist[(size_t)n*64+c];
}

// ---------------- transpose lstm0_Wih [512][128] -> [128][512] ----------------
__global__ void transpose_w0(const float* __restrict__ W, float* __restrict__ WT){
    int i = blockIdx.x*256+threadIdx.x;
    if (i >= 512*DEC) return;
    int g = i>>7, k = i&127;
    WT[k*512+g] = W[i];
}

// ---------------- pack W[512][128] -> P[k4][g] float4 (float4 along k) ----------------
__global__ void pack_w(const float* __restrict__ W, float4* __restrict__ P){
    int i = blockIdx.x*256+threadIdx.x;     // over 512*32
    if (i >= 512*32) return;
    int g = i & 511, k4 = i >> 9;
    const float4* r = (const float4*)(W + (size_t)g*128 + k4*4);
    P[k4*512+g] = *r;
}

// ---------------- gi0 = enc @ Wih0^T + bih0 + bhh0 (time-invariant) ----------------
__global__ __launch_bounds__(512) void gi0_kernel(
    const float* __restrict__ enc, const float* __restrict__ W0T,
    const float* __restrict__ bih0, const float* __restrict__ bhh0,
    float* __restrict__ gi0)
{
    __shared__ float se[128];
    const int b = blockIdx.x, g = threadIdx.x;
    if (g < 128) se[g] = enc[(size_t)b*128+g];
    __syncthreads();
    float a = bih0[g]+bhh0[g];
#pragma unroll 4
    for (int k=0;k<128;k++) a += W0T[k*512+g]*se[k];
    gi0[(size_t)b*512+g] = a;
}

// ---------------- 2-layer LSTM decoder, persistent over 25 steps ----------------
// 512 threads, one gate-row g=tid per thread, MB=8 samples/block.
// Weights streamed coalesced from L2 via pre-packed P[k4][g] float4.
// ~8 scalar accumulators/thread -> no spills (R1 post-mortem: VGPR=256 + 22.5GB
// scratch traffic from the old 8-stream fully-unrolled layout).
#define MB 8
__global__ __launch_bounds__(512) void lstm_kernel(
    const float* __restrict__ gi0,
    const float4* __restrict__ P0,    // Whh0 packed [32][512]
    const float4* __restrict__ P1i,   // Wih1 packed
    const float4* __restrict__ P1h,   // Whh1 packed
    const float* __restrict__ bih1, const float* __restrict__ bhh1,
    const float* __restrict__ Wop, const float* __restrict__ bop,
    float* __restrict__ outp)
{
    __shared__ float sgi[MB*512];     // 16KB: precomputed layer0 input-gates
    __shared__ float sb1v[512];       // layer1 combined bias
    __shared__ float sg[4*MB*DEC];    // 16KB gate scratch: [gt*1024 + b*128 + j]
    __shared__ float sh0[MB*DEC], sh1[MB*DEC];
    __shared__ float sc0[MB*DEC], sc1[MB*DEC];
    const int tid = threadIdx.x;
    const int g = tid;                // gate row 0..511
    const int b0 = blockIdx.x*MB;
    const int gt = g>>7, jj = g&127;

    for (int i=tid;i<MB*512;i+=512) sgi[i] = gi0[(size_t)b0*512 + i];
    sb1v[tid] = bih1[tid]+bhh1[tid];
    for (int i=tid;i<MB*DEC;i+=512){ sh0[i]=0.f; sh1[i]=0.f; sc0[i]=0.f; sc1[i]=0.f; }
    __syncthreads();

    const float bo0 = bop[0], bo1 = bop[1];
    for (int t=0;t<OUTL;t++){
        // ---- layer 0 recurrent GEMV: acc[b] = Whh0[g] . h0[b] ----
        {
            float acc[MB];
#pragma unroll
            for (int b=0;b<MB;b++) acc[b]=0.f;
#pragma unroll 4
            for (int k4=0;k4<32;k4++){
                float4 wv = P0[k4*512+g];
#pragma unroll
                for (int b=0;b<MB;b++){
                    float4 hv = *(const float4*)&sh0[b*DEC + k4*4];
                    acc[b] += dot4(wv, hv);
                }
            }
#pragma unroll
            for (int b=0;b<MB;b++) sg[gt*1024 + b*DEC + jj] = acc[b];
        }
        __syncthreads();
        // ---- combine layer 0: 1024 (b,j) items, 2 per thread ----
#pragma unroll
        for (int r=0;r<2;r++){
            int it = tid + r*512;
            int b = it>>7, j = it&127;
            float gi_ = sgi[b*512       + j] + sg[           b*DEC + j];
            float gf_ = sgi[b*512 + 128 + j] + sg[1*MB*DEC + b*DEC + j];
            float gg_ = sgi[b*512 + 256 + j] + sg[2*MB*DEC + b*DEC + j];
            float go_ = sgi[b*512 + 384 + j] + sg[3*MB*DEC + b*DEC + j];
            float cc = sigmoidf_(gf_)*sc0[b*DEC+j] + sigmoidf_(gi_)*tanhf(gg_);
            sc0[b*DEC+j] = cc;
            sh0[b*DEC+j] = sigmoidf_(go_)*tanhf(cc);
        }
        __syncthreads();
        // ---- layer 1 GEMV: acc[b] = Wih1[g].h0[b] + Whh1[g].h1[b] ----
        {
            float acc[MB];
#pragma unroll
            for (int b=0;b<MB;b++) acc[b]=0.f;
#pragma unroll 4
            for (int k4=0;k4<32;k4++){
                float4 wv = P1i[k4*512+g];
#pragma unroll
                for (int b=0;b<MB;b++){
                    float4 hv = *(const float4*)&sh0[b*DEC + k4*4];
                    acc[b] += dot4(wv, hv);
                }
            }
#pragma unroll 4
            for (int k4=0;k4<32;k4++){
                float4 wv = P1h[k4*512+g];
#pragma unroll
                for (int b=0;b<MB;b++){
                    float4 hv = *(const float4*)&sh1[b*DEC + k4*4];
                    acc[b] += dot4(wv, hv);
                }
            }
#pragma unroll
            for (int b=0;b<MB;b++) sg[gt*1024 + b*DEC + jj] = acc[b];
        }
        __syncthreads();
        // ---- combine layer 1 ----
#pragma unroll
        for (int r=0;r<2;r++){
            int it = tid + r*512;
            int b = it>>7, j = it&127;
            float gi_ = sg[           b*DEC + j] + sb1v[j];
            float gf_ = sg[1*MB*DEC + b*DEC + j] + sb1v[128+j];
            float gg_ = sg[2*MB*DEC + b*DEC + j] + sb1v[256+j];
            float go_ = sg[3*MB*DEC + b*DEC + j] + sb1v[384+j];
            float cc = sigmoidf_(gf_)*sc1[b*DEC+j] + sigmoidf_(gi_)*tanhf(gg_);
            sc1[b*DEC+j] = cc;
            sh1[b*DEC+j] = sigmoidf_(go_)*tanhf(cc);
        }
        __syncthreads();
        // ---- output projection for this step ----
        if (tid < 16){
            int bb=tid>>1, o=tid&1;
            const float4* hv=(const float4*)(sh1 + bb*DEC);
            const float4* wv=(const float4*)(Wop + o*DEC);
            float4 a={0,0,0,0};
#pragma unroll
            for (int k=0;k<32;k++) fma44(a, wv[k], hv[k]);
            outp[(size_t)(b0+bb)*(OUTL*2) + t*2 + o] = hsum(a) + (o ? bo1 : bo0);
        }
        // next step's layer0 k-loop only reads sh0 (rewritten after sync1 of
        // next step), out-readers of sh1 finish before next sync1 -> safe.
    }
}

extern "C" void kernel_launch(void* const* d_in, const int* in_sizes, int n_in,
                              void* d_out, int out_size, void* d_ws, size_t ws_size,
                              hipStream_t stream)
{
    const float* x    = (const float*)d_in[0];
    const int*   ei   = (const int*)d_in[1];
    const float* ea   = (const float*)d_in[2];
    const int*   tgt  = (const int*)d_in[3];
    const float* Wip  = (const float*)d_in[4];
    const float* bip  = (const float*)d_in[5];
    const float* gWih = (const float*)d_in[6];
    const float* gWhh = (const float*)d_in[7];
    const float* gbih = (const float*)d_in[8];
    const float* gbhh = (const float*)d_in[9];
    const float* Wdyn = (const float*)d_in[10];
    const float* bdyn = (const float*)d_in[11];
    const float* c1Wf=(const float*)d_in[12]; const float* c1bf=(const float*)d_in[13];
    const float* c1Ws=(const float*)d_in[14]; const float* c1bs=(const float*)d_in[15];
    const float* c1g =(const float*)d_in[16]; const float* c1b =(const float*)d_in[17];
    const float* c1m =(const float*)d_in[18]; const float* c1v =(const float*)d_in[19];
    const float* c2Wf=(const float*)d_in[20]; const float* c2bf=(const float*)d_in[21];
    const float* c2Ws=(const float*)d_in[22]; const float* c2bs=(const float*)d_in[23];
    const float* c2g =(const float*)d_in[24]; const float* c2b =(const float*)d_in[25];
    const float* c2m =(const float*)d_in[26]; const float* c2v =(const float*)d_in[27];
    const float* Wn  =(const float*)d_in[28]; const float* bn_ =(const float*)d_in[29];
    const float* l0Wih=(const float*)d_in[30]; const float* l0Whh=(const float*)d_in[31];
    const float* l0bih=(const float*)d_in[32]; const float* l0bhh=(const float*)d_in[33];
    const float* l1Wih=(const float*)d_in[34]; const float* l1Whh=(const float*)d_in[35];
    const float* l1bih=(const float*)d_in[36]; const float* l1bhh=(const float*)d_in[37];
    const float* Wop =(const float*)d_in[38]; const float* bop=(const float*)d_in[39];

    float* ws = (float*)d_ws;
    size_t o = 0;
    float* hist = ws + o; o += (size_t)NN*ENC;
    float* f1   = ws + o; o += (size_t)NN*ENC;
    float* f2   = ws + o; o += (size_t)NN*ENC;
    float* Af   = ws + o; o += (size_t)NN*ENC;
    float* Bf   = ws + o; o += (size_t)NN*ENC;
    float* As   = ws + o; o += (size_t)NN*ENC;
    float* Bs   = ws + o; o += (size_t)NN*ENC;
    float* agg  = ws + o; o += (size_t)NN*ENC;
    float* enc  = ws + o; o += (size_t)BB*2*ENC;
    float* gi0  = ws + o; o += (size_t)BB*4*DEC;
    float* W0T  = ws + o; o += (size_t)128*512;
    float* P0   = ws + o; o += (size_t)512*128;
    float* P1i  = ws + o; o += (size_t)512*128;
    float* P1h  = ws + o; o += (size_t)512*128;

    // --- history encoder ---
    encoder_kernel<<<(NN+63)/64, 64, 0, stream>>>(x, Wip,bip,gWih,gWhh,gbih,gbhh,Wdyn,bdyn,hist);

    // --- CGConv 1 ---
    proj_kernel<<<(NN+PROJ_NODES-1)/PROJ_NODES, 256, 0, stream>>>(hist, c1Wf, c1Ws, Af,Bf,As,Bs);
    (void)hipMemsetAsync(agg, 0, (size_t)NN*ENC*sizeof(float), stream);
    edge_kernel<<<EE/16, 256, 0, stream>>>(ei, ea, c1Wf,c1bf,c1Ws,c1bs, Af,Bf,As,Bs, agg);
    bnres_kernel<<<(NN*ENC)/256, 256, 0, stream>>>(hist, agg, c1g,c1b,c1m,c1v, f1);

    // --- CGConv 2 ---
    proj_kernel<<<(NN+PROJ_NODES-1)/PROJ_NODES, 256, 0, stream>>>(f1, c2Wf, c2Ws, Af,Bf,As,Bs);
    (void)hipMemsetAsync(agg, 0, (size_t)NN*ENC*sizeof(float), stream);
    edge_kernel<<<EE/16, 256, 0, stream>>>(ei, ea, c2Wf,c2bf,c2Ws,c2bs, Af,Bf,As,Bs, agg);
    bnres_kernel<<<(NN*ENC)/256, 256, 0, stream>>>(f1, agg, c2g,c2b,c2m,c2v, f2);

    // --- target encoding ---
    target_kernel<<<(BB+3)/4, 256, 0, stream>>>(hist, f2, tgt, Wn, bn_, enc);

    // --- LSTM decoder prep ---
    transpose_w0<<<(512*DEC+255)/256, 256, 0, stream>>>(l0Wih, W0T);
    pack_w<<<64, 256, 0, stream>>>(l0Whh, (float4*)P0);
    pack_w<<<64, 256, 0, stream>>>(l1Wih, (float4*)P1i);
    pack_w<<<64, 256, 0, stream>>>(l1Whh, (float4*)P1h);
    gi0_kernel<<<BB, 512, 0, stream>>>(enc, W0T, l0bih, l0bhh, gi0);

    // --- LSTM decoder ---
    lstm_kernel<<<BB/MB, 512, 0, stream>>>(gi0, (const float4*)P0, (const float4*)P1i, (const float4*)P1h,
                                           l1bih, l1bhh, Wop, bop, (float*)d_out);
}

// Round 3
// 2978.943 us; speedup vs baseline: 4.3488x; 1.6233x over previous
//
#include <hip/hip_runtime.h>
#include <math.h>

#define NN   50000
#define TT   16
#define EE   800000
#define BB   2000
#define EMBD 32
#define ENC  64
#define DEC  128
#define OUTL 25
#define BN_EPS 1e-5f

__device__ __forceinline__ float lrelu(float v){ return v >= 0.f ? v : 0.1f*v; }
__device__ __forceinline__ float sigmoidf_(float v){ return 1.f/(1.f+expf(-v)); }
__device__ __forceinline__ float softplusf_(float v){
    return v > 0.f ? v + log1pf(expf(-v)) : log1pf(expf(v));
}
// fast gate math (encoder only): v_rcp + v_exp, ~1ulp each — margin is 5.8x
__device__ __forceinline__ float fsig(float v){ return __builtin_amdgcn_rcpf(1.f + __expf(-v)); }
__device__ __forceinline__ float ftanh(float v){ return 2.f*__builtin_amdgcn_rcpf(1.f + __expf(-2.f*v)) - 1.f; }
__device__ __forceinline__ void fma44(float4& a, float4 w, float4 h){
    a.x += w.x*h.x; a.y += w.y*h.y; a.z += w.z*h.z; a.w += w.w*h.w;
}
__device__ __forceinline__ float hsum(float4 a){ return (a.x+a.y)+(a.z+a.w); }
__device__ __forceinline__ float dot4(float4 w, float4 h){ return (w.x*h.x+w.y*h.y)+(w.z*h.z+w.w*h.w); }

// ---------------- GRU encoder v2 ----------------
// R2 post-mortem: v1 was 64-thr blocks = 0.76 waves/SIMD, Occ 7.5%, VALUBusy 20%.
// v2: 512 threads / 64 nodes / 8 row-groups; wave-uniform weight rows -> s_load
// (scalar pipe, free); h/emb transposed in LDS [k][n] (lane=n, conflict-free);
// h double-buffered. VALU floor 188us.
__global__ __launch_bounds__(512) void encoder_kernel(
    const float* __restrict__ x,
    const float* __restrict__ Wip, const float* __restrict__ bip,
    const float* __restrict__ Wih, const float* __restrict__ Whh,
    const float* __restrict__ bih, const float* __restrict__ bhh,
    const float* __restrict__ Wdyn, const float* __restrict__ bdyn,
    float* __restrict__ hist)
{
    __shared__ float xsT[32*64];       // [i=t*2+c][n]
    __shared__ float embT[32*64];      // [k][n]
    __shared__ float hT[2][64*64];     // [k][n], double-buffered
    const int tid = threadIdx.x;
    const int n   = tid & 63;
    const int q   = __builtin_amdgcn_readfirstlane(tid >> 6);   // row-group, wave-uniform
    const int n0  = blockIdx.x * 64;

    // ---- stage x tile: 64 nodes x 32 floats contiguous -> transposed LDS ----
    {
        const float4* xsrc = (const float4*)x;
        size_t g4 = (size_t)n0*8 + tid;            // 512 float4s = 2048 floats
        float4 v = {0.f,0.f,0.f,0.f};
        if (g4 < (size_t)NN*8) v = xsrc[g4];
        int nn = tid >> 3;                         // node within tile
        int ii = (tid & 7) * 4;                    // float index within node
        xsT[(ii+0)*64+nn]=v.x; xsT[(ii+1)*64+nn]=v.y;
        xsT[(ii+2)*64+nn]=v.z; xsT[(ii+3)*64+nn]=v.w;
    }
    for (int i=tid;i<64*64;i+=512) hT[0][i]=0.f;

    // wave-uniform weight row bases (q*8 .. q*8+8)
    const float* Wr  = Wih + (size_t)(      q*8)*EMBD;
    const float* Wz  = Wih + (size_t)( 64 + q*8)*EMBD;
    const float* Wnn = Wih + (size_t)(128 + q*8)*EMBD;
    const float* Vr  = Whh + (size_t)(      q*8)*ENC;
    const float* Vz  = Whh + (size_t)( 64 + q*8)*ENC;
    const float* Vn  = Whh + (size_t)(128 + q*8)*ENC;
    float br[8], bz[8], bin[8], bhn[8];
#pragma unroll
    for (int i=0;i<8;i++){
        br[i]  = bih[      q*8+i] + bhh[      q*8+i];
        bz[i]  = bih[ 64 + q*8+i] + bhh[ 64 + q*8+i];
        bin[i] = bih[128 + q*8+i];
        bhn[i] = bhh[128 + q*8+i];
    }
    __syncthreads();

    int p = 0;
#pragma unroll 1
    for (int t=0;t<TT;t++){
        // ---- emb = lrelu(x @ Wip^T + bip), cooperative, transposed ----
#pragma unroll
        for (int r=0;r<4;r++){
            int idx = r*512 + tid;
            int k   = __builtin_amdgcn_readfirstlane(idx >> 6);
            int nn2 = idx & 63;
            float x0 = xsT[(2*t  )*64 + nn2];
            float x1 = xsT[(2*t+1)*64 + nn2];
            embT[idx] = lrelu(Wip[2*k]*x0 + Wip[2*k+1]*x1 + bip[k]);
        }
        __syncthreads();

        float ar[8], az[8], ain[8], ahn[8];
#pragma unroll
        for (int i=0;i<8;i++){ ar[i]=br[i]; az[i]=bz[i]; ain[i]=bin[i]; ahn[i]=bhn[i]; }
        // gi part: k over EMBD
#pragma unroll 8
        for (int k=0;k<EMBD;k++){
            float e = embT[k*64+n];
#pragma unroll
            for (int i=0;i<8;i++){
                ar[i]  += Wr [i*EMBD+k]*e;
                az[i]  += Wz [i*EMBD+k]*e;
                ain[i] += Wnn[i*EMBD+k]*e;
            }
        }
        // gh part: k over ENC
#pragma unroll 8
        for (int k=0;k<ENC;k++){
            float hv = hT[p][k*64+n];
#pragma unroll
            for (int i=0;i<8;i++){
                ar[i]  += Vr[i*ENC+k]*hv;
                az[i]  += Vz[i*ENC+k]*hv;
                ahn[i] += Vn[i*ENC+k]*hv;
            }
        }
        // gates + h update into other buffer
#pragma unroll
        for (int i=0;i<8;i++){
            float r_ = fsig(ar[i]);
            float z_ = fsig(az[i]);
            float nn_ = ftanh(ain[i] + r_*ahn[i]);
            float hold = hT[p][(q*8+i)*64 + n];
            hT[1-p][(q*8+i)*64 + n] = (1.f-z_)*nn_ + z_*hold;
        }
        __syncthreads();
        p ^= 1;
    }

    // ---- hist = lrelu(lrelu(h) @ Wdyn^T + bdyn) ----
    {
        const float* Wd = Wdyn + (size_t)(q*8)*ENC;
        float acc[8];
#pragma unroll
        for (int i=0;i<8;i++) acc[i] = bdyn[q*8+i];
#pragma unroll 8
        for (int k=0;k<ENC;k++){
            float hv = lrelu(hT[p][k*64+n]);
#pragma unroll
            for (int i=0;i<8;i++) acc[i] += Wd[i*ENC+k]*hv;
        }
        if (n0+n < NN){
            float4 o0 = { lrelu(acc[0]), lrelu(acc[1]), lrelu(acc[2]), lrelu(acc[3]) };
            float4 o1 = { lrelu(acc[4]), lrelu(acc[5]), lrelu(acc[6]), lrelu(acc[7]) };
            float4* dst = (float4*)(hist + (size_t)(n0+n)*ENC + q*8);
            dst[0] = o0; dst[1] = o1;
        }
    }
}

// ---------------- CGConv node projections: A = W[:,0:64] x, B = W[:,64:128] x ----------------
#define PROJ_NODES 32
__global__ __launch_bounds__(256) void proj_kernel(
    const float* __restrict__ xin,
    const float* __restrict__ Wf, const float* __restrict__ Ws,
    float* __restrict__ Af, float* __restrict__ Bf,
    float* __restrict__ As, float* __restrict__ Bs)
{
    __shared__ float sW[2][ENC*ENC];          // transposed: [m][k*64+c]
    __shared__ float sx[PROJ_NODES*ENC];
    const int tid = threadIdx.x;
    const int n0 = blockIdx.x*PROJ_NODES;
    for (int idx=tid; idx<PROJ_NODES*ENC; idx+=256){
        int nn = idx>>6, k = idx&63;
        int n = n0+nn;
        sx[idx] = (n<NN) ? xin[(size_t)n*ENC+k] : 0.f;
    }
    const int c = tid&63, q = tid>>6;
#pragma unroll
    for (int p=0;p<2;p++){
        const float* W = p ? Ws : Wf;
        float* oD = p ? As : Af;
        float* oS = p ? Bs : Bf;
        __syncthreads();
        for (int idx=tid; idx<2*ENC*ENC; idx+=256){
            int m = idx>>12, r = idx&4095;
            int cc = r>>6, k = r&63;
            sW[m][k*64+cc] = W[cc*130 + m*64 + k];
        }
        __syncthreads();
        for (int nn=q; nn<PROJ_NODES; nn+=4){
            int n = n0+nn;
            if (n>=NN) break;
            float aD=0.f, aS=0.f;
#pragma unroll
            for (int k=0;k<ENC;k++){
                float xv = sx[nn*ENC+k];
                aD += sW[0][k*64+c]*xv;
                aS += sW[1][k*64+c]*xv;
            }
            oD[(size_t)n*ENC+c]=aD;
            oS[(size_t)n*ENC+c]=aS;
        }
    }
}

// ---------------- CGConv edge kernel: wave per edge (lane = channel), atomic scatter ----------------
__global__ __launch_bounds__(256) void edge_kernel(
    const int* __restrict__ ei, const float* __restrict__ ea,
    const float* __restrict__ Wf, const float* __restrict__ bf,
    const float* __restrict__ Ws, const float* __restrict__ bs,
    const float* __restrict__ Af, const float* __restrict__ Bf,
    const float* __restrict__ As, const float* __restrict__ Bs,
    float* __restrict__ agg)
{
    __shared__ float cf0[64], cf1[64], cfb[64], cs0[64], cs1[64], csb[64];
    const int tid=threadIdx.x;
    if (tid<64){
        cf0[tid]=Wf[tid*130+128]; cf1[tid]=Wf[tid*130+129]; cfb[tid]=bf[tid];
        cs0[tid]=Ws[tid*130+128]; cs1[tid]=Ws[tid*130+129]; csb[tid]=bs[tid];
    }
    __syncthreads();
    const int wid = tid>>6, c = tid&63;
    const int ebase = blockIdx.x*16 + wid*4;
#pragma unroll 1
    for (int i=0;i<4;i++){
        int e = ebase + i;
        if (e >= EE) break;
        int src = ei[e], dst = ei[EE+e];
        float e0 = ea[2*(size_t)e], e1 = ea[2*(size_t)e+1];
        float gf = Af[(size_t)dst*64+c] + Bf[(size_t)src*64+c] + cf0[c]*e0 + cf1[c]*e1 + cfb[c];
        float gs = As[(size_t)dst*64+c] + Bs[(size_t)src*64+c] + cs0[c]*e0 + cs1[c]*e1 + csb[c];
        float m = sigmoidf_(gf)*softplusf_(gs);
        atomicAdd(&agg[(size_t)dst*64+c], m);
    }
}

// ---------------- BN (inference) + residual ----------------
__global__ void bnres_kernel(const float* __restrict__ xin, const float* __restrict__ agg,
    const float* __restrict__ gamma, const float* __restrict__ beta,
    const float* __restrict__ mean, const float* __restrict__ var,
    float* __restrict__ outp)
{
    size_t i = (size_t)blockIdx.x*256 + threadIdx.x;
    if (i >= (size_t)NN*ENC) return;
    int c = (int)(i&63);
    float a = (agg[i]-mean[c])*rsqrtf(var[c]+BN_EPS)*gamma[c] + beta[c];
    outp[i] = xin[i] + a;
}

// ---------------- target gather + nbrs linear + concat ----------------
__global__ __launch_bounds__(256) void target_kernel(
    const float* __restrict__ hist, const float* __restrict__ f2,
    const int* __restrict__ tgt,
    const float* __restrict__ Wn, const float* __restrict__ bn_,
    float* __restrict__ enc)
{
    const int tid=threadIdx.x;
    const int c = tid&63, q = tid>>6;
    const int b = blockIdx.x*4 + q;
    if (b>=BB) return;
    const int n = tgt[b];
    float a = bn_[c];
#pragma unroll
    for (int k=0;k<ENC;k++) a += Wn[c*64+k]*f2[(size_t)n*64+k];
    enc[(size_t)b*128 + 64 + c] = lrelu(a);
    enc[(size_t)b*128 + c]      = hist[(size_t)n*64+c];
}

// ---------------- transpose lstm0_Wih [512][128] -> [128][512] ----------------
__global__ void transpose_w0(const float* __restrict__ W, float* __restrict__ WT){
    int i = blockIdx.x*256+threadIdx.x;
    if (i >= 512*DEC) return;
    int g = i>>7, k = i&127;
    WT[k*512+g] = W[i];
}

// ---------------- pack W[512][128] -> P[k4][g] float4 (float4 along k) ----------------
__global__ void pack_w(const float* __restrict__ W, float4* __restrict__ P){
    int i = blockIdx.x*256+threadIdx.x;     // over 512*32
    if (i >= 512*32) return;
    int g = i & 511, k4 = i >> 9;
    const float4* r = (const float4*)(W + (size_t)g*128 + k4*4);
    P[k4*512+g] = *r;
}

// ---------------- gi0 = enc @ Wih0^T + bih0 + bhh0 (time-invariant) ----------------
__global__ __launch_bounds__(512) void gi0_kernel(
    const float* __restrict__ enc, const float* __restrict__ W0T,
    const float* __restrict__ bih0, const float* __restrict__ bhh0,
    float* __restrict__ gi0)
{
    __shared__ float se[128];
    const int b = blockIdx.x, g = threadIdx.x;
    if (g < 128) se[g] = enc[(size_t)b*128+g];
    __syncthreads();
    float a = bih0[g]+bhh0[g];
#pragma unroll 4
    for (int k=0;k<128;k++) a += W0T[k*512+g]*se[k];
    gi0[(size_t)b*512+g] = a;
}

// ---------------- 2-layer LSTM decoder, persistent over 25 steps ----------------
#define MB 8
__global__ __launch_bounds__(512) void lstm_kernel(
    const float* __restrict__ gi0,
    const float4* __restrict__ P0,    // Whh0 packed [32][512]
    const float4* __restrict__ P1i,   // Wih1 packed
    const float4* __restrict__ P1h,   // Whh1 packed
    const float* __restrict__ bih1, const float* __restrict__ bhh1,
    const float* __restrict__ Wop, const float* __restrict__ bop,
    float* __restrict__ outp)
{
    __shared__ float sgi[MB*512];     // 16KB: precomputed layer0 input-gates
    __shared__ float sb1v[512];       // layer1 combined bias
    __shared__ float sg[4*MB*DEC];    // 16KB gate scratch: [gt*1024 + b*128 + j]
    __shared__ float sh0[MB*DEC], sh1[MB*DEC];
    __shared__ float sc0[MB*DEC], sc1[MB*DEC];
    const int tid = threadIdx.x;
    const int g = tid;                // gate row 0..511
    const int b0 = blockIdx.x*MB;
    const int gt = g>>7, jj = g&127;

    for (int i=tid;i<MB*512;i+=512) sgi[i] = gi0[(size_t)b0*512 + i];
    sb1v[tid] = bih1[tid]+bhh1[tid];
    for (int i=tid;i<MB*DEC;i+=512){ sh0[i]=0.f; sh1[i]=0.f; sc0[i]=0.f; sc1[i]=0.f; }
    __syncthreads();

    const float bo0 = bop[0], bo1 = bop[1];
    for (int t=0;t<OUTL;t++){
        // ---- layer 0 recurrent GEMV: acc[b] = Whh0[g] . h0[b] ----
        {
            float acc[MB];
#pragma unroll
            for (int b=0;b<MB;b++) acc[b]=0.f;
#pragma unroll 4
            for (int k4=0;k4<32;k4++){
                float4 wv = P0[k4*512+g];
#pragma unroll
                for (int b=0;b<MB;b++){
                    float4 hv = *(const float4*)&sh0[b*DEC + k4*4];
                    acc[b] += dot4(wv, hv);
                }
            }
#pragma unroll
            for (int b=0;b<MB;b++) sg[gt*1024 + b*DEC + jj] = acc[b];
        }
        __syncthreads();
        // ---- combine layer 0: 1024 (b,j) items, 2 per thread ----
#pragma unroll
        for (int r=0;r<2;r++){
            int it = tid + r*512;
            int b = it>>7, j = it&127;
            float gi_ = sgi[b*512       + j] + sg[           b*DEC + j];
            float gf_ = sgi[b*512 + 128 + j] + sg[1*MB*DEC + b*DEC + j];
            float gg_ = sgi[b*512 + 256 + j] + sg[2*MB*DEC + b*DEC + j];
            float go_ = sgi[b*512 + 384 + j] + sg[3*MB*DEC + b*DEC + j];
            float cc = sigmoidf_(gf_)*sc0[b*DEC+j] + sigmoidf_(gi_)*tanhf(gg_);
            sc0[b*DEC+j] = cc;
            sh0[b*DEC+j] = sigmoidf_(go_)*tanhf(cc);
        }
        __syncthreads();
        // ---- layer 1 GEMV: acc[b] = Wih1[g].h0[b] + Whh1[g].h1[b] ----
        {
            float acc[MB];
#pragma unroll
            for (int b=0;b<MB;b++) acc[b]=0.f;
#pragma unroll 4
            for (int k4=0;k4<32;k4++){
                float4 wv = P1i[k4*512+g];
#pragma unroll
                for (int b=0;b<MB;b++){
                    float4 hv = *(const float4*)&sh0[b*DEC + k4*4];
                    acc[b] += dot4(wv, hv);
                }
            }
#pragma unroll 4
            for (int k4=0;k4<32;k4++){
                float4 wv = P1h[k4*512+g];
#pragma unroll
                for (int b=0;b<MB;b++){
                    float4 hv = *(const float4*)&sh1[b*DEC + k4*4];
                    acc[b] += dot4(wv, hv);
                }
            }
#pragma unroll
            for (int b=0;b<MB;b++) sg[gt*1024 + b*DEC + jj] = acc[b];
        }
        __syncthreads();
        // ---- combine layer 1 ----
#pragma unroll
        for (int r=0;r<2;r++){
            int it = tid + r*512;
            int b = it>>7, j = it&127;
            float gi_ = sg[           b*DEC + j] + sb1v[j];
            float gf_ = sg[1*MB*DEC + b*DEC + j] + sb1v[128+j];
            float gg_ = sg[2*MB*DEC + b*DEC + j] + sb1v[256+j];
            float go_ = sg[3*MB*DEC + b*DEC + j] + sb1v[384+j];
            float cc = sigmoidf_(gf_)*sc1[b*DEC+j] + sigmoidf_(gi_)*tanhf(gg_);
            sc1[b*DEC+j] = cc;
            sh1[b*DEC+j] = sigmoidf_(go_)*tanhf(cc);
        }
        __syncthreads();
        // ---- output projection for this step ----
        if (tid < 16){
            int bb=tid>>1, o=tid&1;
            const float4* hv=(const float4*)(sh1 + bb*DEC);
            const float4* wv=(const float4*)(Wop + o*DEC);
            float4 a={0,0,0,0};
#pragma unroll
            for (int k=0;k<32;k++) fma44(a, wv[k], hv[k]);
            outp[(size_t)(b0+bb)*(OUTL*2) + t*2 + o] = hsum(a) + (o ? bo1 : bo0);
        }
    }
}

extern "C" void kernel_launch(void* const* d_in, const int* in_sizes, int n_in,
                              void* d_out, int out_size, void* d_ws, size_t ws_size,
                              hipStream_t stream)
{
    const float* x    = (const float*)d_in[0];
    const int*   ei   = (const int*)d_in[1];
    const float* ea   = (const float*)d_in[2];
    const int*   tgt  = (const int*)d_in[3];
    const float* Wip  = (const float*)d_in[4];
    const float* bip  = (const float*)d_in[5];
    const float* gWih = (const float*)d_in[6];
    const float* gWhh = (const float*)d_in[7];
    const float* gbih = (const float*)d_in[8];
    const float* gbhh = (const float*)d_in[9];
    const float* Wdyn = (const float*)d_in[10];
    const float* bdyn = (const float*)d_in[11];
    const float* c1Wf=(const float*)d_in[12]; const float* c1bf=(const float*)d_in[13];
    const float* c1Ws=(const float*)d_in[14]; const float* c1bs=(const float*)d_in[15];
    const float* c1g =(const float*)d_in[16]; const float* c1b =(const float*)d_in[17];
    const float* c1m =(const float*)d_in[18]; const float* c1v =(const float*)d_in[19];
    const float* c2Wf=(const float*)d_in[20]; const float* c2bf=(const float*)d_in[21];
    const float* c2Ws=(const float*)d_in[22]; const float* c2bs=(const float*)d_in[23];
    const float* c2g =(const float*)d_in[24]; const float* c2b =(const float*)d_in[25];
    const float* c2m =(const float*)d_in[26]; const float* c2v =(const float*)d_in[27];
    const float* Wn  =(const float*)d_in[28]; const float* bn_ =(const float*)d_in[29];
    const float* l0Wih=(const float*)d_in[30]; const float* l0Whh=(const float*)d_in[31];
    const float* l0bih=(const float*)d_in[32]; const float* l0bhh=(const float*)d_in[33];
    const float* l1Wih=(const float*)d_in[34]; const float* l1Whh=(const float*)d_in[35];
    const float* l1bih=(const float*)d_in[36]; const float* l1bhh=(const float*)d_in[37];
    const float* Wop =(const float*)d_in[38]; const float* bop=(const float*)d_in[39];

    float* ws = (float*)d_ws;
    size_t o = 0;
    float* hist = ws + o; o += (size_t)NN*ENC;
    float* f1   = ws + o; o += (size_t)NN*ENC;
    float* f2   = ws + o; o += (size_t)NN*ENC;
    float* Af   = ws + o; o += (size_t)NN*ENC;
    float* Bf   = ws + o; o += (size_t)NN*ENC;
    float* As   = ws + o; o += (size_t)NN*ENC;
    float* Bs   = ws + o; o += (size_t)NN*ENC;
    float* agg  = ws + o; o += (size_t)NN*ENC;
    float* enc  = ws + o; o += (size_t)BB*2*ENC;
    float* gi0  = ws + o; o += (size_t)BB*4*DEC;
    float* W0T  = ws + o; o += (size_t)128*512;
    float* P0   = ws + o; o += (size_t)512*128;
    float* P1i  = ws + o; o += (size_t)512*128;
    float* P1h  = ws + o; o += (size_t)512*128;

    // --- history encoder ---
    encoder_kernel<<<(NN+63)/64, 512, 0, stream>>>(x, Wip,bip,gWih,gWhh,gbih,gbhh,Wdyn,bdyn,hist);

    // --- CGConv 1 ---
    proj_kernel<<<(NN+PROJ_NODES-1)/PROJ_NODES, 256, 0, stream>>>(hist, c1Wf, c1Ws, Af,Bf,As,Bs);
    (void)hipMemsetAsync(agg, 0, (size_t)NN*ENC*sizeof(float), stream);
    edge_kernel<<<EE/16, 256, 0, stream>>>(ei, ea, c1Wf,c1bf,c1Ws,c1bs, Af,Bf,As,Bs, agg);
    bnres_kernel<<<(NN*ENC)/256, 256, 0, stream>>>(hist, agg, c1g,c1b,c1m,c1v, f1);

    // --- CGConv 2 ---
    proj_kernel<<<(NN+PROJ_NODES-1)/PROJ_NODES, 256, 0, stream>>>(f1, c2Wf, c2Ws, Af,Bf,As,Bs);
    (void)hipMemsetAsync(agg, 0, (size_t)NN*ENC*sizeof(float), stream);
    edge_kernel<<<EE/16, 256, 0, stream>>>(ei, ea, c2Wf,c2bf,c2Ws,c2bs, Af,Bf,As,Bs, agg);
    bnres_kernel<<<(NN*ENC)/256, 256, 0, stream>>>(f1, agg, c2g,c2b,c2m,c2v, f2);

    // --- target encoding ---
    target_kernel<<<(BB+3)/4, 256, 0, stream>>>(hist, f2, tgt, Wn, bn_, enc);

    // --- LSTM decoder prep ---
    transpose_w0<<<(512*DEC+255)/256, 256, 0, stream>>>(l0Wih, W0T);
    pack_w<<<64, 256, 0, stream>>>(l0Whh, (float4*)P0);
    pack_w<<<64, 256, 0, stream>>>(l1Wih, (float4*)P1i);
    pack_w<<<64, 256, 0, stream>>>(l1Whh, (float4*)P1h);
    gi0_kernel<<<BB, 512, 0, stream>>>(enc, W0T, l0bih, l0bhh, gi0);

    // --- LSTM decoder ---
    lstm_kernel<<<BB/MB, 512, 0, stream>>>(gi0, (const float4*)P0, (const float4*)P1i, (const float4*)P1h,
                                           l1bih, l1bhh, Wop, bop, (float*)d_out);
}

// Round 4
// 2008.228 us; speedup vs baseline: 6.4508x; 1.4834x over previous
//
#include <hip/hip_runtime.h>
#include <math.h>

#define NN   50000
#define TT   16
#define EE   800000
#define BB   2000
#define EMBD 32
#define ENC  64
#define DEC  128
#define OUTL 25
#define BN_EPS 1e-5f

typedef short v8s __attribute__((ext_vector_type(8)));
typedef float v4f __attribute__((ext_vector_type(4)));
#define MFMA16(a,b,c) __builtin_amdgcn_mfma_f32_16x16x32_bf16((a),(b),(c),0,0,0)

__device__ __forceinline__ float lrelu(float v){ return v >= 0.f ? v : 0.1f*v; }
__device__ __forceinline__ float sigmoidf_(float v){ return 1.f/(1.f+expf(-v)); }
__device__ __forceinline__ float softplusf_(float v){
    return v > 0.f ? v + log1pf(expf(-v)) : log1pf(expf(v));
}
__device__ __forceinline__ float fsig(float v){ return __builtin_amdgcn_rcpf(1.f + __expf(-v)); }
__device__ __forceinline__ float ftanh(float v){ return 2.f*__builtin_amdgcn_rcpf(1.f + __expf(-2.f*v)) - 1.f; }
__device__ __forceinline__ void fma44(float4& a, float4 w, float4 h){
    a.x += w.x*h.x; a.y += w.y*h.y; a.z += w.z*h.z; a.w += w.w*h.w;
}
__device__ __forceinline__ float hsum(float4 a){ return (a.x+a.y)+(a.z+a.w); }
__device__ __forceinline__ float dot4(float4 w, float4 h){ return (w.x*h.x+w.y*h.y)+(w.z*h.z+w.w*h.w); }

__device__ __forceinline__ unsigned short f2bf(float f){
    unsigned u = __float_as_uint(f);
    u = u + 0x7FFFu + ((u>>16)&1u);
    return (unsigned short)(u>>16);
}
__device__ __forceinline__ float bf2f(unsigned short s){ return __uint_as_float(((unsigned)s)<<16); }

// split-convert 8 consecutive fp32 -> (hi, lo) bf16 fragments
__device__ __forceinline__ void cvt8(const float* p, v8s& hi, v8s& lo){
    float4 a0 = *(const float4*)p;
    float4 a1 = *(const float4*)(p+4);
    float av[8] = {a0.x,a0.y,a0.z,a0.w,a1.x,a1.y,a1.z,a1.w};
#pragma unroll
    for (int j=0;j<8;j++){
        unsigned short h = f2bf(av[j]);
        hi[j] = (short)h;
        lo[j] = (short)f2bf(av[j] - bf2f(h));
    }
}
__device__ __forceinline__ void cvt8_lrelu(const float* p, v8s& hi, v8s& lo){
    float4 a0 = *(const float4*)p;
    float4 a1 = *(const float4*)(p+4);
    float av[8] = {a0.x,a0.y,a0.z,a0.w,a1.x,a1.y,a1.z,a1.w};
#pragma unroll
    for (int j=0;j<8;j++){
        float a = lrelu(av[j]);
        unsigned short h = f2bf(a);
        hi[j] = (short)h;
        lo[j] = (short)f2bf(a - bf2f(h));
    }
}

// ---------------- pack W[N][K] rows into bf16 B-fragment order ----------------
// frag-block fb = nt*KB + kb; element j of lane l: W[nt*16+(l&15)][kb*32+(l>>4)*8+j]
__global__ void pack_frag(const float* __restrict__ W, int K, int KB,
                          unsigned short* __restrict__ out, int total /* NT*KB*64 */){
    int i = blockIdx.x*256 + threadIdx.x;
    if (i >= total) return;
    int l = i & 63, fb = i >> 6;
    int kb = fb % KB, nt = fb / KB;
    int n = nt*16 + (l&15);
    int k0 = kb*32 + ((l>>4)*8);
#pragma unroll
    for (int j=0;j<8;j++) out[i*8+j] = f2bf(W[(size_t)n*K + k0 + j]);
}

// ---------------- GRU encoder v3: MFMA ----------------
// R3 post-mortem: fp32 VALU formulation is issue-bound (696us VALU vs 200us FMA
// floor: weight delivery overhead). v3: 16-node tile per 128-thr block; gates via
// 16x16x32 bf16 MFMA; A-operands hi+lo split (fp32-like A); weights single bf16,
// pre-packed in B-frag order (coalesced dwordx4 streams from L2).
#define ESTR 68
__global__ __launch_bounds__(128) void encoder_mfma(
    const float* __restrict__ x,
    const float* __restrict__ Wip, const float* __restrict__ bip,
    const unsigned short* __restrict__ pWih,   // NT=12 KB=1
    const unsigned short* __restrict__ pWhh,   // NT=12 KB=2
    const float* __restrict__ bih, const float* __restrict__ bhh,
    const unsigned short* __restrict__ pWdyn,  // NT=4  KB=2
    const float* __restrict__ bdyn,
    float* __restrict__ hist)
{
    __shared__ float sxl[512];        // [m][32] node-major x tile
    __shared__ float femb[16*36];     // [m][k] fp32 emb, padded
    __shared__ float sh[16*ESTR];     // [m][k] fp32 h, padded
    const int tid = threadIdx.x;
    const int l   = tid & 63;
    const int w   = tid >> 6;         // wave 0/1
    const int ln  = l & 15, q = l >> 4;
    const int blk = blockIdx.x;

    ((float4*)sxl)[tid] = ((const float4*)x)[(size_t)blk*128 + tid];
    for (int i=tid;i<16*ESTR;i+=128) sh[i]=0.f;

    // per-thread emb constants (k fixed = tid&31)
    const int ek = tid & 31;
    const float w0 = Wip[2*ek], w1 = Wip[2*ek+1], bk = bip[ek];
    const int em0 = tid >> 5;         // m = em0 + 4r

    // unit setup: wave w owns gate-column units g = 2w, 2w+1
    float bR[2], bZ[2], bNI[2], bNH[2];
#pragma unroll
    for (int u=0;u<2;u++){
        int g = 2*w + u;
        int c = g*16 + ln;
        bR[u]  = bih[c]       + bhh[c];
        bZ[u]  = bih[64 + c]  + bhh[64 + c];
        bNI[u] = bih[128 + c];
        bNH[u] = bhh[128 + c];
    }
    const v8s* FIH = (const v8s*)pWih;    // idx: nt*64 + l
    const v8s* FHH = (const v8s*)pWhh;    // idx: (nt*2+kb)*64 + l
    const v8s* FDY = (const v8s*)pWdyn;   // idx: (nt*2+kb)*64 + l
    __syncthreads();

#pragma unroll 1
    for (int t=0;t<TT;t++){
        // ---- emb = lrelu(x W_ip^T + b) ----
#pragma unroll
        for (int r=0;r<4;r++){
            int m = em0 + r*4;
            float e = w0*sxl[m*32 + 2*t] + w1*sxl[m*32 + 2*t + 1] + bk;
            femb[m*36 + ek] = lrelu(e);
        }
        __syncthreads();                       // barrier A: femb + prev-step sh ready
        // ---- A fragments ----
        v8s eh, el; cvt8(&femb[ln*36 + q*8], eh, el);
        v8s h0h, h0l, h1h, h1l;
        cvt8(&sh[ln*ESTR +      q*8], h0h, h0l);
        cvt8(&sh[ln*ESTR + 32 + q*8], h1h, h1l);
        __syncthreads();                       // barrier B: all sh/femb reads done
        // ---- units ----
#pragma unroll
        for (int u=0;u<2;u++){
            int g = 2*w + u;
            v4f aR = {bR[u],bR[u],bR[u],bR[u]};
            v4f aZ = {bZ[u],bZ[u],bZ[u],bZ[u]};
            v4f aNI= {bNI[u],bNI[u],bNI[u],bNI[u]};
            v4f aNH= {bNH[u],bNH[u],bNH[u],bNH[u]};
            v8s b;
            // r gate: tile g
            b = FIH[(g   )*64 + l];   aR = MFMA16(eh,b,aR);  aR = MFMA16(el,b,aR);
            b = FHH[((g)*2+0)*64+l];  aR = MFMA16(h0h,b,aR); aR = MFMA16(h0l,b,aR);
            b = FHH[((g)*2+1)*64+l];  aR = MFMA16(h1h,b,aR); aR = MFMA16(h1l,b,aR);
            // z gate: tile 4+g
            b = FIH[(4+g )*64 + l];   aZ = MFMA16(eh,b,aZ);  aZ = MFMA16(el,b,aZ);
            b = FHH[((4+g)*2+0)*64+l];aZ = MFMA16(h0h,b,aZ); aZ = MFMA16(h0l,b,aZ);
            b = FHH[((4+g)*2+1)*64+l];aZ = MFMA16(h1h,b,aZ); aZ = MFMA16(h1l,b,aZ);
            // n gate input part: tile 8+g
            b = FIH[(8+g )*64 + l];   aNI= MFMA16(eh,b,aNI); aNI= MFMA16(el,b,aNI);
            // n gate hidden part
            b = FHH[((8+g)*2+0)*64+l];aNH= MFMA16(h0h,b,aNH);aNH= MFMA16(h0l,b,aNH);
            b = FHH[((8+g)*2+1)*64+l];aNH= MFMA16(h1h,b,aNH);aNH= MFMA16(h1l,b,aNH);
            // ---- gates + h update (cols g*16..+16 owned exclusively by unit) ----
#pragma unroll
            for (int i=0;i<4;i++){
                float r_ = fsig(aR[i]);
                float z_ = fsig(aZ[i]);
                float nn_ = ftanh(aNI[i] + r_*aNH[i]);
                int row = q*4 + i, col = g*16 + ln;
                float old = sh[row*ESTR + col];
                sh[row*ESTR + col] = (1.f - z_)*nn_ + z_*old;
            }
        }
    }
    __syncthreads();
    // ---- hist = lrelu(lrelu(h) @ Wdyn^T + b) ----
    {
        v8s a0h,a0l,a1h,a1l;
        cvt8_lrelu(&sh[ln*ESTR +      q*8], a0h, a0l);
        cvt8_lrelu(&sh[ln*ESTR + 32 + q*8], a1h, a1l);
#pragma unroll
        for (int u=0;u<2;u++){
            int nt = 2*w + u;
            float bb = bdyn[nt*16 + ln];
            v4f acc = {bb,bb,bb,bb};
            v8s b;
            b = FDY[(nt*2+0)*64 + l]; acc = MFMA16(a0h,b,acc); acc = MFMA16(a0l,b,acc);
            b = FDY[(nt*2+1)*64 + l]; acc = MFMA16(a1h,b,acc); acc = MFMA16(a1l,b,acc);
#pragma unroll
            for (int i=0;i<4;i++){
                hist[(size_t)(blk*16 + q*4 + i)*64 + nt*16 + ln] = lrelu(acc[i]);
            }
        }
    }
}

// ---------------- CGConv node projections: A = W[:,0:64] x, B = W[:,64:128] x ----------------
#define PROJ_NODES 32
__global__ __launch_bounds__(256) void proj_kernel(
    const float* __restrict__ xin,
    const float* __restrict__ Wf, const float* __restrict__ Ws,
    float* __restrict__ Af, float* __restrict__ Bf,
    float* __restrict__ As, float* __restrict__ Bs)
{
    __shared__ float sW[2][ENC*ENC];          // transposed: [m][k*64+c]
    __shared__ float sx[PROJ_NODES*ENC];
    const int tid = threadIdx.x;
    const int n0 = blockIdx.x*PROJ_NODES;
    for (int idx=tid; idx<PROJ_NODES*ENC; idx+=256){
        int nn = idx>>6, k = idx&63;
        int n = n0+nn;
        sx[idx] = (n<NN) ? xin[(size_t)n*ENC+k] : 0.f;
    }
    const int c = tid&63, q = tid>>6;
#pragma unroll
    for (int p=0;p<2;p++){
        const float* W = p ? Ws : Wf;
        float* oD = p ? As : Af;
        float* oS = p ? Bs : Bf;
        __syncthreads();
        for (int idx=tid; idx<2*ENC*ENC; idx+=256){
            int m = idx>>12, r = idx&4095;
            int cc = r>>6, k = r&63;
            sW[m][k*64+cc] = W[cc*130 + m*64 + k];
        }
        __syncthreads();
        for (int nn=q; nn<PROJ_NODES; nn+=4){
            int n = n0+nn;
            if (n>=NN) break;
            float aD=0.f, aS=0.f;
#pragma unroll
            for (int k=0;k<ENC;k++){
                float xv = sx[nn*ENC+k];
                aD += sW[0][k*64+c]*xv;
                aS += sW[1][k*64+c]*xv;
            }
            oD[(size_t)n*ENC+c]=aD;
            oS[(size_t)n*ENC+c]=aS;
        }
    }
}

// ---------------- CGConv edge kernel: wave per edge (lane = channel), atomic scatter ----------------
__global__ __launch_bounds__(256) void edge_kernel(
    const int* __restrict__ ei, const float* __restrict__ ea,
    const float* __restrict__ Wf, const float* __restrict__ bf,
    const float* __restrict__ Ws, const float* __restrict__ bs,
    const float* __restrict__ Af, const float* __restrict__ Bf,
    const float* __restrict__ As, const float* __restrict__ Bs,
    float* __restrict__ agg)
{
    __shared__ float cf0[64], cf1[64], cfb[64], cs0[64], cs1[64], csb[64];
    const int tid=threadIdx.x;
    if (tid<64){
        cf0[tid]=Wf[tid*130+128]; cf1[tid]=Wf[tid*130+129]; cfb[tid]=bf[tid];
        cs0[tid]=Ws[tid*130+128]; cs1[tid]=Ws[tid*130+129]; csb[tid]=bs[tid];
    }
    __syncthreads();
    const int wid = tid>>6, c = tid&63;
    const int ebase = blockIdx.x*16 + wid*4;
#pragma unroll 1
    for (int i=0;i<4;i++){
        int e = ebase + i;
        if (e >= EE) break;
        int src = ei[e], dst = ei[EE+e];
        float e0 = ea[2*(size_t)e], e1 = ea[2*(size_t)e+1];
        float gf = Af[(size_t)dst*64+c] + Bf[(size_t)src*64+c] + cf0[c]*e0 + cf1[c]*e1 + cfb[c];
        float gs = As[(size_t)dst*64+c] + Bs[(size_t)src*64+c] + cs0[c]*e0 + cs1[c]*e1 + csb[c];
        float m = sigmoidf_(gf)*softplusf_(gs);
        atomicAdd(&agg[(size_t)dst*64+c], m);
    }
}

// ---------------- BN (inference) + residual ----------------
__global__ void bnres_kernel(const float* __restrict__ xin, const float* __restrict__ agg,
    const float* __restrict__ gamma, const float* __restrict__ beta,
    const float* __restrict__ mean, const float* __restrict__ var,
    float* __restrict__ outp)
{
    size_t i = (size_t)blockIdx.x*256 + threadIdx.x;
    if (i >= (size_t)NN*ENC) return;
    int c = (int)(i&63);
    float a = (agg[i]-mean[c])*rsqrtf(var[c]+BN_EPS)*gamma[c] + beta[c];
    outp[i] = xin[i] + a;
}

// ---------------- target gather + nbrs linear + concat ----------------
__global__ __launch_bounds__(256) void target_kernel(
    const float* __restrict__ hist, const float* __restrict__ f2,
    const int* __restrict__ tgt,
    const float* __restrict__ Wn, const float* __restrict__ bn_,
    float* __restrict__ enc)
{
    const int tid=threadIdx.x;
    const int c = tid&63, q = tid>>6;
    const int b = blockIdx.x*4 + q;
    if (b>=BB) return;
    const int n = tgt[b];
    float a = bn_[c];
#pragma unroll
    for (int k=0;k<ENC;k++) a += Wn[c*64+k]*f2[(size_t)n*64+k];
    enc[(size_t)b*128 + 64 + c] = lrelu(a);
    enc[(size_t)b*128 + c]      = hist[(size_t)n*64+c];
}

// ---------------- transpose lstm0_Wih [512][128] -> [128][512] ----------------
__global__ void transpose_w0(const float* __restrict__ W, float* __restrict__ WT){
    int i = blockIdx.x*256+threadIdx.x;
    if (i >= 512*DEC) return;
    int g = i>>7, k = i&127;
    WT[k*512+g] = W[i];
}

// ---------------- pack W[512][128] -> P[k4][g] float4 (float4 along k) ----------------
__global__ void pack_w(const float* __restrict__ W, float4* __restrict__ P){
    int i = blockIdx.x*256+threadIdx.x;     // over 512*32
    if (i >= 512*32) return;
    int g = i & 511, k4 = i >> 9;
    const float4* r = (const float4*)(W + (size_t)g*128 + k4*4);
    P[k4*512+g] = *r;
}

// ---------------- gi0 = enc @ Wih0^T + bih0 + bhh0 (time-invariant) ----------------
__global__ __launch_bounds__(512) void gi0_kernel(
    const float* __restrict__ enc, const float* __restrict__ W0T,
    const float* __restrict__ bih0, const float* __restrict__ bhh0,
    float* __restrict__ gi0)
{
    __shared__ float se[128];
    const int b = blockIdx.x, g = threadIdx.x;
    if (g < 128) se[g] = enc[(size_t)b*128+g];
    __syncthreads();
    float a = bih0[g]+bhh0[g];
#pragma unroll 4
    for (int k=0;k<128;k++) a += W0T[k*512+g]*se[k];
    gi0[(size_t)b*512+g] = a;
}

// ---------------- 2-layer LSTM decoder, persistent over 25 steps ----------------
#define MB 8
__global__ __launch_bounds__(512) void lstm_kernel(
    const float* __restrict__ gi0,
    const float4* __restrict__ P0,    // Whh0 packed [32][512]
    const float4* __restrict__ P1i,   // Wih1 packed
    const float4* __restrict__ P1h,   // Whh1 packed
    const float* __restrict__ bih1, const float* __restrict__ bhh1,
    const float* __restrict__ Wop, const float* __restrict__ bop,
    float* __restrict__ outp)
{
    __shared__ float sgi[MB*512];     // 16KB: precomputed layer0 input-gates
    __shared__ float sb1v[512];       // layer1 combined bias
    __shared__ float sg[4*MB*DEC];    // 16KB gate scratch: [gt*1024 + b*128 + j]
    __shared__ float sh0[MB*DEC], sh1[MB*DEC];
    __shared__ float sc0[MB*DEC], sc1[MB*DEC];
    const int tid = threadIdx.x;
    const int g = tid;                // gate row 0..511
    const int b0 = blockIdx.x*MB;
    const int gt = g>>7, jj = g&127;

    for (int i=tid;i<MB*512;i+=512) sgi[i] = gi0[(size_t)b0*512 + i];
    sb1v[tid] = bih1[tid]+bhh1[tid];
    for (int i=tid;i<MB*DEC;i+=512){ sh0[i]=0.f; sh1[i]=0.f; sc0[i]=0.f; sc1[i]=0.f; }
    __syncthreads();

    const float bo0 = bop[0], bo1 = bop[1];
    for (int t=0;t<OUTL;t++){
        // ---- layer 0 recurrent GEMV: acc[b] = Whh0[g] . h0[b] ----
        {
            float acc[MB];
#pragma unroll
            for (int b=0;b<MB;b++) acc[b]=0.f;
#pragma unroll 4
            for (int k4=0;k4<32;k4++){
                float4 wv = P0[k4*512+g];
#pragma unroll
                for (int b=0;b<MB;b++){
                    float4 hv = *(const float4*)&sh0[b*DEC + k4*4];
                    acc[b] += dot4(wv, hv);
                }
            }
#pragma unroll
            for (int b=0;b<MB;b++) sg[gt*1024 + b*DEC + jj] = acc[b];
        }
        __syncthreads();
        // ---- combine layer 0: 1024 (b,j) items, 2 per thread ----
#pragma unroll
        for (int r=0;r<2;r++){
            int it = tid + r*512;
            int b = it>>7, j = it&127;
            float gi_ = sgi[b*512       + j] + sg[           b*DEC + j];
            float gf_ = sgi[b*512 + 128 + j] + sg[1*MB*DEC + b*DEC + j];
            float gg_ = sgi[b*512 + 256 + j] + sg[2*MB*DEC + b*DEC + j];
            float go_ = sgi[b*512 + 384 + j] + sg[3*MB*DEC + b*DEC + j];
            float cc = sigmoidf_(gf_)*sc0[b*DEC+j] + sigmoidf_(gi_)*tanhf(gg_);
            sc0[b*DEC+j] = cc;
            sh0[b*DEC+j] = sigmoidf_(go_)*tanhf(cc);
        }
        __syncthreads();
        // ---- layer 1 GEMV: acc[b] = Wih1[g].h0[b] + Whh1[g].h1[b] ----
        {
            float acc[MB];
#pragma unroll
            for (int b=0;b<MB;b++) acc[b]=0.f;
#pragma unroll 4
            for (int k4=0;k4<32;k4++){
                float4 wv = P1i[k4*512+g];
#pragma unroll
                for (int b=0;b<MB;b++){
                    float4 hv = *(const float4*)&sh0[b*DEC + k4*4];
                    acc[b] += dot4(wv, hv);
                }
            }
#pragma unroll 4
            for (int k4=0;k4<32;k4++){
                float4 wv = P1h[k4*512+g];
#pragma unroll
                for (int b=0;b<MB;b++){
                    float4 hv = *(const float4*)&sh1[b*DEC + k4*4];
                    acc[b] += dot4(wv, hv);
                }
            }
#pragma unroll
            for (int b=0;b<MB;b++) sg[gt*1024 + b*DEC + jj] = acc[b];
        }
        __syncthreads();
        // ---- combine layer 1 ----
#pragma unroll
        for (int r=0;r<2;r++){
            int it = tid + r*512;
            int b = it>>7, j = it&127;
            float gi_ = sg[           b*DEC + j] + sb1v[j];
            float gf_ = sg[1*MB*DEC + b*DEC + j] + sb1v[128+j];
            float gg_ = sg[2*MB*DEC + b*DEC + j] + sb1v[256+j];
            float go_ = sg[3*MB*DEC + b*DEC + j] + sb1v[384+j];
            float cc = sigmoidf_(gf_)*sc1[b*DEC+j] + sigmoidf_(gi_)*tanhf(gg_);
            sc1[b*DEC+j] = cc;
            sh1[b*DEC+j] = sigmoidf_(go_)*tanhf(cc);
        }
        __syncthreads();
        // ---- output projection for this step ----
        if (tid < 16){
            int bb=tid>>1, o=tid&1;
            const float4* hv=(const float4*)(sh1 + bb*DEC);
            const float4* wv=(const float4*)(Wop + o*DEC);
            float4 a={0,0,0,0};
#pragma unroll
            for (int k=0;k<32;k++) fma44(a, wv[k], hv[k]);
            outp[(size_t)(b0+bb)*(OUTL*2) + t*2 + o] = hsum(a) + (o ? bo1 : bo0);
        }
    }
}

extern "C" void kernel_launch(void* const* d_in, const int* in_sizes, int n_in,
                              void* d_out, int out_size, void* d_ws, size_t ws_size,
                              hipStream_t stream)
{
    const float* x    = (const float*)d_in[0];
    const int*   ei   = (const int*)d_in[1];
    const float* ea   = (const float*)d_in[2];
    const int*   tgt  = (const int*)d_in[3];
    const float* Wip  = (const float*)d_in[4];
    const float* bip  = (const float*)d_in[5];
    const float* gWih = (const float*)d_in[6];
    const float* gWhh = (const float*)d_in[7];
    const float* gbih = (const float*)d_in[8];
    const float* gbhh = (const float*)d_in[9];
    const float* Wdyn = (const float*)d_in[10];
    const float* bdyn = (const float*)d_in[11];
    const float* c1Wf=(const float*)d_in[12]; const float* c1bf=(const float*)d_in[13];
    const float* c1Ws=(const float*)d_in[14]; const float* c1bs=(const float*)d_in[15];
    const float* c1g =(const float*)d_in[16]; const float* c1b =(const float*)d_in[17];
    const float* c1m =(const float*)d_in[18]; const float* c1v =(const float*)d_in[19];
    const float* c2Wf=(const float*)d_in[20]; const float* c2bf=(const float*)d_in[21];
    const float* c2Ws=(const float*)d_in[22]; const float* c2bs=(const float*)d_in[23];
    const float* c2g =(const float*)d_in[24]; const float* c2b =(const float*)d_in[25];
    const float* c2m =(const float*)d_in[26]; const float* c2v =(const float*)d_in[27];
    const float* Wn  =(const float*)d_in[28]; const float* bn_ =(const float*)d_in[29];
    const float* l0Wih=(const float*)d_in[30]; const float* l0Whh=(const float*)d_in[31];
    const float* l0bih=(const float*)d_in[32]; const float* l0bhh=(const float*)d_in[33];
    const float* l1Wih=(const float*)d_in[34]; const float* l1Whh=(const float*)d_in[35];
    const float* l1bih=(const float*)d_in[36]; const float* l1bhh=(const float*)d_in[37];
    const float* Wop =(const float*)d_in[38]; const float* bop=(const float*)d_in[39];

    float* ws = (float*)d_ws;
    size_t o = 0;
    float* hist = ws + o; o += (size_t)NN*ENC;
    float* f1   = ws + o; o += (size_t)NN*ENC;
    float* f2   = ws + o; o += (size_t)NN*ENC;
    float* Af   = ws + o; o += (size_t)NN*ENC;
    float* Bf   = ws + o; o += (size_t)NN*ENC;
    float* As   = ws + o; o += (size_t)NN*ENC;
    float* Bs   = ws + o; o += (size_t)NN*ENC;
    float* agg  = ws + o; o += (size_t)NN*ENC;
    float* enc  = ws + o; o += (size_t)BB*2*ENC;
    float* gi0  = ws + o; o += (size_t)BB*4*DEC;
    float* W0T  = ws + o; o += (size_t)128*512;
    float* P0   = ws + o; o += (size_t)512*128;
    float* P1i  = ws + o; o += (size_t)512*128;
    float* P1h  = ws + o; o += (size_t)512*128;
    unsigned short* pWih  = (unsigned short*)(ws + o); o += (size_t)12*64*8/2;   // 6144 us
    unsigned short* pWhh  = (unsigned short*)(ws + o); o += (size_t)24*64*8/2;   // 12288 us
    unsigned short* pWdyn = (unsigned short*)(ws + o); o += (size_t)8*64*8/2;    // 4096 us

    // --- weight packing (bf16 B-fragment order) ---
    pack_frag<<<(12*64+255)/256, 256, 0, stream>>>(gWih, 32, 1, pWih, 12*64);
    pack_frag<<<(24*64+255)/256, 256, 0, stream>>>(gWhh, 64, 2, pWhh, 24*64);
    pack_frag<<<(8*64+255)/256, 256, 0, stream>>>(Wdyn, 64, 2, pWdyn, 8*64);

    // --- history encoder (MFMA) ---
    encoder_mfma<<<NN/16, 128, 0, stream>>>(x, Wip, bip, pWih, pWhh, gbih, gbhh, pWdyn, bdyn, hist);

    // --- CGConv 1 ---
    proj_kernel<<<(NN+PROJ_NODES-1)/PROJ_NODES, 256, 0, stream>>>(hist, c1Wf, c1Ws, Af,Bf,As,Bs);
    (void)hipMemsetAsync(agg, 0, (size_t)NN*ENC*sizeof(float), stream);
    edge_kernel<<<EE/16, 256, 0, stream>>>(ei, ea, c1Wf,c1bf,c1Ws,c1bs, Af,Bf,As,Bs, agg);
    bnres_kernel<<<(NN*ENC)/256, 256, 0, stream>>>(hist, agg, c1g,c1b,c1m,c1v, f1);

    // --- CGConv 2 ---
    proj_kernel<<<(NN+PROJ_NODES-1)/PROJ_NODES, 256, 0, stream>>>(f1, c2Wf, c2Ws, Af,Bf,As,Bs);
    (void)hipMemsetAsync(agg, 0, (size_t)NN*ENC*sizeof(float), stream);
    edge_kernel<<<EE/16, 256, 0, stream>>>(ei, ea, c2Wf,c2bf,c2Ws,c2bs, Af,Bf,As,Bs, agg);
    bnres_kernel<<<(NN*ENC)/256, 256, 0, stream>>>(f1, agg, c2g,c2b,c2m,c2v, f2);

    // --- target encoding ---
    target_kernel<<<(BB+3)/4, 256, 0, stream>>>(hist, f2, tgt, Wn, bn_, enc);

    // --- LSTM decoder prep ---
    transpose_w0<<<(512*DEC+255)/256, 256, 0, stream>>>(l0Wih, W0T);
    pack_w<<<64, 256, 0, stream>>>(l0Whh, (float4*)P0);
    pack_w<<<64, 256, 0, stream>>>(l1Wih, (float4*)P1i);
    pack_w<<<64, 256, 0, stream>>>(l1Whh, (float4*)P1h);
    gi0_kernel<<<BB, 512, 0, stream>>>(enc, W0T, l0bih, l0bhh, gi0);

    // --- LSTM decoder ---
    lstm_kernel<<<BB/MB, 512, 0, stream>>>(gi0, (const float4*)P0, (const float4*)P1i, (const float4*)P1h,
                                           l1bih, l1bhh, Wop, bop, (float*)d_out);
}

// Round 5
// 1747.968 us; speedup vs baseline: 7.4113x; 1.1489x over previous
//
#include <hip/hip_runtime.h>
#include <math.h>

#define NN   50000
#define TT   16
#define EE   800000
#define BB   2000
#define EMBD 32
#define ENC  64
#define DEC  128
#define OUTL 25
#define BN_EPS 1e-5f

typedef short v8s __attribute__((ext_vector_type(8)));
typedef float v4f __attribute__((ext_vector_type(4)));
#define MFMA16(a,b,c) __builtin_amdgcn_mfma_f32_16x16x32_bf16((a),(b),(c),0,0,0)

__device__ __forceinline__ float lrelu(float v){ return v >= 0.f ? v : 0.1f*v; }
__device__ __forceinline__ float sigmoidf_(float v){ return 1.f/(1.f+expf(-v)); }
__device__ __forceinline__ float softplusf_(float v){
    return v > 0.f ? v + log1pf(expf(-v)) : log1pf(expf(v));
}
__device__ __forceinline__ float fsig(float v){ return __builtin_amdgcn_rcpf(1.f + __expf(-v)); }
__device__ __forceinline__ float ftanh(float v){ return 2.f*__builtin_amdgcn_rcpf(1.f + __expf(-2.f*v)) - 1.f; }
__device__ __forceinline__ void fma44(float4& a, float4 w, float4 h){
    a.x += w.x*h.x; a.y += w.y*h.y; a.z += w.z*h.z; a.w += w.w*h.w;
}
__device__ __forceinline__ float hsum(float4 a){ return (a.x+a.y)+(a.z+a.w); }

__device__ __forceinline__ unsigned short f2bf(float f){
    unsigned u = __float_as_uint(f);
    u = u + 0x7FFFu + ((u>>16)&1u);
    return (unsigned short)(u>>16);
}
__device__ __forceinline__ float bf2f(unsigned short s){ return __uint_as_float(((unsigned)s)<<16); }

// split-convert 8 consecutive fp32 -> (hi, lo) bf16 fragments
__device__ __forceinline__ void cvt8(const float* p, v8s& hi, v8s& lo){
    float4 a0 = *(const float4*)p;
    float4 a1 = *(const float4*)(p+4);
    float av[8] = {a0.x,a0.y,a0.z,a0.w,a1.x,a1.y,a1.z,a1.w};
#pragma unroll
    for (int j=0;j<8;j++){
        unsigned short h = f2bf(av[j]);
        hi[j] = (short)h;
        lo[j] = (short)f2bf(av[j] - bf2f(h));
    }
}
__device__ __forceinline__ void cvt8_lrelu(const float* p, v8s& hi, v8s& lo){
    float4 a0 = *(const float4*)p;
    float4 a1 = *(const float4*)(p+4);
    float av[8] = {a0.x,a0.y,a0.z,a0.w,a1.x,a1.y,a1.z,a1.w};
#pragma unroll
    for (int j=0;j<8;j++){
        float a = lrelu(av[j]);
        unsigned short h = f2bf(a);
        hi[j] = (short)h;
        lo[j] = (short)f2bf(a - bf2f(h));
    }
}

// ---------------- pack W[N][K] rows into bf16 B-fragment order (hi only) ----------------
__global__ void pack_frag(const float* __restrict__ W, int K, int KB,
                          unsigned short* __restrict__ out, int total /* NT*KB*64 */){
    int i = blockIdx.x*256 + threadIdx.x;
    if (i >= total) return;
    int l = i & 63, fb = i >> 6;
    int kb = fb % KB, nt = fb / KB;
    int n = nt*16 + (l&15);
    int k0 = kb*32 + ((l>>4)*8);
#pragma unroll
    for (int j=0;j<8;j++) out[i*8+j] = f2bf(W[(size_t)n*K + k0 + j]);
}

// ---------------- pack (Wa | Wb) rows into bf16 hi/lo B-fragment order ----------------
// k < K1 from Wa[n][k], else Wb[n][k-K1]; K = total K, KB = K/32
__global__ void pack_frag_hl(const float* __restrict__ Wa, const float* __restrict__ Wb,
                             int K1, int K, int KB,
                             unsigned short* __restrict__ hi, unsigned short* __restrict__ lo,
                             int total /* NT*KB*64 */){
    int i = blockIdx.x*256 + threadIdx.x;
    if (i >= total) return;
    int l = i & 63, fb = i >> 6;
    int kb = fb % KB, nt = fb / KB;
    int n = nt*16 + (l&15);
    int k0 = kb*32 + ((l>>4)*8);
#pragma unroll
    for (int j=0;j<8;j++){
        int k = k0 + j;
        float v = (k < K1) ? Wa[(size_t)n*K1 + k] : Wb[(size_t)n*(K-K1) + (k-K1)];
        unsigned short h = f2bf(v);
        hi[i*8+j] = h;
        lo[i*8+j] = f2bf(v - bf2f(h));
    }
}

// ---------------- GRU encoder v3: MFMA (R4, unchanged) ----------------
#define ESTR 68
__global__ __launch_bounds__(128) void encoder_mfma(
    const float* __restrict__ x,
    const float* __restrict__ Wip, const float* __restrict__ bip,
    const unsigned short* __restrict__ pWih,   // NT=12 KB=1
    const unsigned short* __restrict__ pWhh,   // NT=12 KB=2
    const float* __restrict__ bih, const float* __restrict__ bhh,
    const unsigned short* __restrict__ pWdyn,  // NT=4  KB=2
    const float* __restrict__ bdyn,
    float* __restrict__ hist)
{
    __shared__ float sxl[512];
    __shared__ float femb[16*36];
    __shared__ float sh[16*ESTR];
    const int tid = threadIdx.x;
    const int l   = tid & 63;
    const int w   = tid >> 6;
    const int ln  = l & 15, q = l >> 4;
    const int blk = blockIdx.x;

    ((float4*)sxl)[tid] = ((const float4*)x)[(size_t)blk*128 + tid];
    for (int i=tid;i<16*ESTR;i+=128) sh[i]=0.f;

    const int ek = tid & 31;
    const float w0 = Wip[2*ek], w1 = Wip[2*ek+1], bk = bip[ek];
    const int em0 = tid >> 5;

    float bR[2], bZ[2], bNI[2], bNH[2];
#pragma unroll
    for (int u=0;u<2;u++){
        int g = 2*w + u;
        int c = g*16 + ln;
        bR[u]  = bih[c]       + bhh[c];
        bZ[u]  = bih[64 + c]  + bhh[64 + c];
        bNI[u] = bih[128 + c];
        bNH[u] = bhh[128 + c];
    }
    const v8s* FIH = (const v8s*)pWih;
    const v8s* FHH = (const v8s*)pWhh;
    const v8s* FDY = (const v8s*)pWdyn;
    __syncthreads();

#pragma unroll 1
    for (int t=0;t<TT;t++){
#pragma unroll
        for (int r=0;r<4;r++){
            int m = em0 + r*4;
            float e = w0*sxl[m*32 + 2*t] + w1*sxl[m*32 + 2*t + 1] + bk;
            femb[m*36 + ek] = lrelu(e);
        }
        __syncthreads();
        v8s eh, el; cvt8(&femb[ln*36 + q*8], eh, el);
        v8s h0h, h0l, h1h, h1l;
        cvt8(&sh[ln*ESTR +      q*8], h0h, h0l);
        cvt8(&sh[ln*ESTR + 32 + q*8], h1h, h1l);
        __syncthreads();
#pragma unroll
        for (int u=0;u<2;u++){
            int g = 2*w + u;
            v4f aR = {bR[u],bR[u],bR[u],bR[u]};
            v4f aZ = {bZ[u],bZ[u],bZ[u],bZ[u]};
            v4f aNI= {bNI[u],bNI[u],bNI[u],bNI[u]};
            v4f aNH= {bNH[u],bNH[u],bNH[u],bNH[u]};
            v8s b;
            b = FIH[(g   )*64 + l];   aR = MFMA16(eh,b,aR);  aR = MFMA16(el,b,aR);
            b = FHH[((g)*2+0)*64+l];  aR = MFMA16(h0h,b,aR); aR = MFMA16(h0l,b,aR);
            b = FHH[((g)*2+1)*64+l];  aR = MFMA16(h1h,b,aR); aR = MFMA16(h1l,b,aR);
            b = FIH[(4+g )*64 + l];   aZ = MFMA16(eh,b,aZ);  aZ = MFMA16(el,b,aZ);
            b = FHH[((4+g)*2+0)*64+l];aZ = MFMA16(h0h,b,aZ); aZ = MFMA16(h0l,b,aZ);
            b = FHH[((4+g)*2+1)*64+l];aZ = MFMA16(h1h,b,aZ); aZ = MFMA16(h1l,b,aZ);
            b = FIH[(8+g )*64 + l];   aNI= MFMA16(eh,b,aNI); aNI= MFMA16(el,b,aNI);
            b = FHH[((8+g)*2+0)*64+l];aNH= MFMA16(h0h,b,aNH);aNH= MFMA16(h0l,b,aNH);
            b = FHH[((8+g)*2+1)*64+l];aNH= MFMA16(h1h,b,aNH);aNH= MFMA16(h1l,b,aNH);
#pragma unroll
            for (int i=0;i<4;i++){
                float r_ = fsig(aR[i]);
                float z_ = fsig(aZ[i]);
                float nn_ = ftanh(aNI[i] + r_*aNH[i]);
                int row = q*4 + i, col = g*16 + ln;
                float old = sh[row*ESTR + col];
                sh[row*ESTR + col] = (1.f - z_)*nn_ + z_*old;
            }
        }
    }
    __syncthreads();
    {
        v8s a0h,a0l,a1h,a1l;
        cvt8_lrelu(&sh[ln*ESTR +      q*8], a0h, a0l);
        cvt8_lrelu(&sh[ln*ESTR + 32 + q*8], a1h, a1l);
#pragma unroll
        for (int u=0;u<2;u++){
            int nt = 2*w + u;
            float bb = bdyn[nt*16 + ln];
            v4f acc = {bb,bb,bb,bb};
            v8s b;
            b = FDY[(nt*2+0)*64 + l]; acc = MFMA16(a0h,b,acc); acc = MFMA16(a0l,b,acc);
            b = FDY[(nt*2+1)*64 + l]; acc = MFMA16(a1h,b,acc); acc = MFMA16(a1l,b,acc);
#pragma unroll
            for (int i=0;i<4;i++){
                hist[(size_t)(blk*16 + q*4 + i)*64 + nt*16 + ln] = lrelu(acc[i]);
            }
        }
    }
}

// ---------------- CGConv node projections (unchanged) ----------------
#define PROJ_NODES 32
__global__ __launch_bounds__(256) void proj_kernel(
    const float* __restrict__ xin,
    const float* __restrict__ Wf, const float* __restrict__ Ws,
    float* __restrict__ Af, float* __restrict__ Bf,
    float* __restrict__ As, float* __restrict__ Bs)
{
    __shared__ float sW[2][ENC*ENC];
    __shared__ float sx[PROJ_NODES*ENC];
    const int tid = threadIdx.x;
    const int n0 = blockIdx.x*PROJ_NODES;
    for (int idx=tid; idx<PROJ_NODES*ENC; idx+=256){
        int nn = idx>>6, k = idx&63;
        int n = n0+nn;
        sx[idx] = (n<NN) ? xin[(size_t)n*ENC+k] : 0.f;
    }
    const int c = tid&63, q = tid>>6;
#pragma unroll
    for (int p=0;p<2;p++){
        const float* W = p ? Ws : Wf;
        float* oD = p ? As : Af;
        float* oS = p ? Bs : Bf;
        __syncthreads();
        for (int idx=tid; idx<2*ENC*ENC; idx+=256){
            int m = idx>>12, r = idx&4095;
            int cc = r>>6, k = r&63;
            sW[m][k*64+cc] = W[cc*130 + m*64 + k];
        }
        __syncthreads();
        for (int nn=q; nn<PROJ_NODES; nn+=4){
            int n = n0+nn;
            if (n>=NN) break;
            float aD=0.f, aS=0.f;
#pragma unroll
            for (int k=0;k<ENC;k++){
                float xv = sx[nn*ENC+k];
                aD += sW[0][k*64+c]*xv;
                aS += sW[1][k*64+c]*xv;
            }
            oD[(size_t)n*ENC+c]=aD;
            oS[(size_t)n*ENC+c]=aS;
        }
    }
}

// ---------------- CGConv edge kernel (unchanged) ----------------
__global__ __launch_bounds__(256) void edge_kernel(
    const int* __restrict__ ei, const float* __restrict__ ea,
    const float* __restrict__ Wf, const float* __restrict__ bf,
    const float* __restrict__ Ws, const float* __restrict__ bs,
    const float* __restrict__ Af, const float* __restrict__ Bf,
    const float* __restrict__ As, const float* __restrict__ Bs,
    float* __restrict__ agg)
{
    __shared__ float cf0[64], cf1[64], cfb[64], cs0[64], cs1[64], csb[64];
    const int tid=threadIdx.x;
    if (tid<64){
        cf0[tid]=Wf[tid*130+128]; cf1[tid]=Wf[tid*130+129]; cfb[tid]=bf[tid];
        cs0[tid]=Ws[tid*130+128]; cs1[tid]=Ws[tid*130+129]; csb[tid]=bs[tid];
    }
    __syncthreads();
    const int wid = tid>>6, c = tid&63;
    const int ebase = blockIdx.x*16 + wid*4;
#pragma unroll 1
    for (int i=0;i<4;i++){
        int e = ebase + i;
        if (e >= EE) break;
        int src = ei[e], dst = ei[EE+e];
        float e0 = ea[2*(size_t)e], e1 = ea[2*(size_t)e+1];
        float gf = Af[(size_t)dst*64+c] + Bf[(size_t)src*64+c] + cf0[c]*e0 + cf1[c]*e1 + cfb[c];
        float gs = As[(size_t)dst*64+c] + Bs[(size_t)src*64+c] + cs0[c]*e0 + cs1[c]*e1 + csb[c];
        float m = sigmoidf_(gf)*softplusf_(gs);
        atomicAdd(&agg[(size_t)dst*64+c], m);
    }
}

// ---------------- BN (inference) + residual (unchanged) ----------------
__global__ void bnres_kernel(const float* __restrict__ xin, const float* __restrict__ agg,
    const float* __restrict__ gamma, const float* __restrict__ beta,
    const float* __restrict__ mean, const float* __restrict__ var,
    float* __restrict__ outp)
{
    size_t i = (size_t)blockIdx.x*256 + threadIdx.x;
    if (i >= (size_t)NN*ENC) return;
    int c = (int)(i&63);
    float a = (agg[i]-mean[c])*rsqrtf(var[c]+BN_EPS)*gamma[c] + beta[c];
    outp[i] = xin[i] + a;
}

// ---------------- target gather + nbrs linear + concat (unchanged) ----------------
__global__ __launch_bounds__(256) void target_kernel(
    const float* __restrict__ hist, const float* __restrict__ f2,
    const int* __restrict__ tgt,
    const float* __restrict__ Wn, const float* __restrict__ bn_,
    float* __restrict__ enc)
{
    const int tid=threadIdx.x;
    const int c = tid&63, q = tid>>6;
    const int b = blockIdx.x*4 + q;
    if (b>=BB) return;
    const int n = tgt[b];
    float a = bn_[c];
#pragma unroll
    for (int k=0;k<ENC;k++) a += Wn[c*64+k]*f2[(size_t)n*64+k];
    enc[(size_t)b*128 + 64 + c] = lrelu(a);
    enc[(size_t)b*128 + c]      = hist[(size_t)n*64+c];
}

// ---------------- transpose lstm0_Wih [512][128] -> [128][512] ----------------
__global__ void transpose_w0(const float* __restrict__ W, float* __restrict__ WT){
    int i = blockIdx.x*256+threadIdx.x;
    if (i >= 512*DEC) return;
    int g = i>>7, k = i&127;
    WT[k*512+g] = W[i];
}

// ---------------- gi0 = enc @ Wih0^T + bih0 + bhh0 (time-invariant) ----------------
__global__ __launch_bounds__(512) void gi0_kernel(
    const float* __restrict__ enc, const float* __restrict__ W0T,
    const float* __restrict__ bih0, const float* __restrict__ bhh0,
    float* __restrict__ gi0)
{
    __shared__ float se[128];
    const int b = blockIdx.x, g = threadIdx.x;
    if (g < 128) se[g] = enc[(size_t)b*128+g];
    __syncthreads();
    float a = bih0[g]+bhh0[g];
#pragma unroll 4
    for (int k=0;k<128;k++) a += W0T[k*512+g]*se[k];
    gi0[(size_t)b*512+g] = a;
}

// ---------------- 2-layer LSTM decoder v2: MFMA ----------------
// R4 post-mortem: fp32 GEMV was VALU-issue + LDS-pipe bound (dot4 = 2x FMA ops,
// 768 broadcast ds_read/thread/step, 1.2M conflict cycles). v2: M=16 sample tile,
// wave w owns units [16w,16w+16) for ALL 4 gates -> gate combine + c-state fully
// in registers; h stored in LDS pre-split bf16 hi/lo in A-frag order (writer
// converts once, readers do 1 conflict-free ds_read_b128/frag); weights bf16
// hi/lo B-frags streamed from L2; 3-term MFMA ~= fp32 accuracy.
#define LMB 16
__global__ __launch_bounds__(512) void lstm_mfma(
    const float* __restrict__ gi0,
    const unsigned short* __restrict__ B0h, const unsigned short* __restrict__ B0l, // NT=32 KB=4
    const unsigned short* __restrict__ B1h, const unsigned short* __restrict__ B1l, // NT=32 KB=8
    const float* __restrict__ bih1, const float* __restrict__ bhh1,
    const float* __restrict__ Wop, const float* __restrict__ bop,
    float* __restrict__ outp)
{
    __shared__ unsigned short h0hi[4*512], h0lo[4*512];   // frag order: kb*512 + lane*8 + j
    __shared__ unsigned short h1hi[4*512], h1lo[4*512];
    __shared__ float sh1f[16*132];                        // row-layout h1 for out-proj
    __shared__ float sWop[256];
    const int tid = threadIdx.x;
    const int l = tid & 63;
    const int w = tid >> 6;           // wave 0..7
    const int c = l & 15;             // col within tile
    const int q = l >> 4;             // quad -> rows m = q*4+i
    const int j = w*16 + c;           // owned hidden unit (all 4 gates)
    const int b0 = blockIdx.x*LMB;

    for (int i=tid;i<4*512;i+=512){ h0hi[i]=0; h0lo[i]=0; h1hi[i]=0; h1lo[i]=0; }
    if (tid < 256) sWop[tid] = Wop[tid];

    // gi0 (incl. layer0 biases) into registers: 4 gates x 4 rows
    float rgi[4][4];
#pragma unroll
    for (int g=0;g<4;g++)
#pragma unroll
        for (int i=0;i<4;i++)
            rgi[g][i] = gi0[(size_t)(b0 + q*4 + i)*512 + g*128 + j];
    float b1[4];
#pragma unroll
    for (int g=0;g<4;g++) b1[g] = bih1[g*128+j] + bhh1[g*128+j];
    float c0[4] = {0,0,0,0}, c1[4] = {0,0,0,0};
    const float bo0 = bop[0], bo1 = bop[1];

    const v8s* F0h = (const v8s*)B0h; const v8s* F0l = (const v8s*)B0l;
    const v8s* F1h = (const v8s*)B1h; const v8s* F1l = (const v8s*)B1l;
    const int kbw = j>>5, qw = (j>>3)&3, jw = j&7;   // write-back frag coords for unit j
    __syncthreads();

#pragma unroll 1
    for (int t=0;t<OUTL;t++){
        // ---- layer 0: gates[m][g*128+j] = gi0 + h0_prev @ Whh0^T ----
        v4f acc[4];
#pragma unroll
        for (int g=0;g<4;g++){ v4f t4={rgi[g][0],rgi[g][1],rgi[g][2],rgi[g][3]}; acc[g]=t4; }
#pragma unroll
        for (int kb=0;kb<4;kb++){
            v8s ah = *(const v8s*)&h0hi[kb*512 + l*8];
            v8s al = *(const v8s*)&h0lo[kb*512 + l*8];
#pragma unroll
            for (int g=0;g<4;g++){
                v8s bh = F0h[((g*8+w)*4 + kb)*64 + l];
                v8s bl = F0l[((g*8+w)*4 + kb)*64 + l];
                acc[g] = MFMA16(ah, bh, acc[g]);
                acc[g] = MFMA16(al, bh, acc[g]);
                acc[g] = MFMA16(ah, bl, acc[g]);
            }
        }
        float hnew[4];
#pragma unroll
        for (int i=0;i<4;i++){
            c0[i] = fsig(acc[1][i])*c0[i] + fsig(acc[0][i])*ftanh(acc[2][i]);
            hnew[i] = fsig(acc[3][i])*ftanh(c0[i]);
        }
        __syncthreads();     // all waves done reading h0_prev
#pragma unroll
        for (int i=0;i<4;i++){
            int off = kbw*512 + (qw*16 + q*4 + i)*8 + jw;
            unsigned short h = f2bf(hnew[i]);
            h0hi[off] = h;
            h0lo[off] = f2bf(hnew[i] - bf2f(h));
        }
        __syncthreads();     // h0_new visible

        // ---- layer 1: gates = b1 + [h0_new | h1_prev] @ [Wih1|Whh1]^T ----
        v4f a1[4];
#pragma unroll
        for (int g=0;g<4;g++){ v4f t4={b1[g],b1[g],b1[g],b1[g]}; a1[g]=t4; }
#pragma unroll
        for (int kb=0;kb<8;kb++){
            const unsigned short* hb = (kb<4) ? h0hi : h1hi;
            const unsigned short* lb = (kb<4) ? h0lo : h1lo;
            int kk = kb & 3;
            v8s ah = *(const v8s*)&hb[kk*512 + l*8];
            v8s al = *(const v8s*)&lb[kk*512 + l*8];
#pragma unroll
            for (int g=0;g<4;g++){
                v8s bh = F1h[((g*8+w)*8 + kb)*64 + l];
                v8s bl = F1l[((g*8+w)*8 + kb)*64 + l];
                a1[g] = MFMA16(ah, bh, a1[g]);
                a1[g] = MFMA16(al, bh, a1[g]);
                a1[g] = MFMA16(ah, bl, a1[g]);
            }
        }
        float h1new[4];
#pragma unroll
        for (int i=0;i<4;i++){
            c1[i] = fsig(a1[1][i])*c1[i] + fsig(a1[0][i])*ftanh(a1[2][i]);
            h1new[i] = fsig(a1[3][i])*ftanh(c1[i]);
        }
        __syncthreads();     // all waves done reading h1_prev
#pragma unroll
        for (int i=0;i<4;i++){
            int off = kbw*512 + (qw*16 + q*4 + i)*8 + jw;
            unsigned short h = f2bf(h1new[i]);
            h1hi[off] = h;
            h1lo[off] = f2bf(h1new[i] - bf2f(h));
            sh1f[(q*4+i)*132 + j] = h1new[i];
        }
        __syncthreads();     // h1_new + sh1f visible

        // ---- output projection: fut[b0+m][t][o] ----
        if (tid < 32){
            int m = tid>>1, o = tid&1;
            const float4* hv = (const float4*)&sh1f[m*132];
            const float4* wv = (const float4*)&sWop[o*128];
            float4 s4={0,0,0,0};
#pragma unroll
            for (int k4=0;k4<32;k4++) fma44(s4, wv[k4], hv[k4]);
            outp[(size_t)(b0+m)*(OUTL*2) + t*2 + o] = hsum(s4) + (o ? bo1 : bo0);
        }
        // out-proj readers finish before next write to sh1f (2 barriers away)
    }
}

extern "C" void kernel_launch(void* const* d_in, const int* in_sizes, int n_in,
                              void* d_out, int out_size, void* d_ws, size_t ws_size,
                              hipStream_t stream)
{
    const float* x    = (const float*)d_in[0];
    const int*   ei   = (const int*)d_in[1];
    const float* ea   = (const float*)d_in[2];
    const int*   tgt  = (const int*)d_in[3];
    const float* Wip  = (const float*)d_in[4];
    const float* bip  = (const float*)d_in[5];
    const float* gWih = (const float*)d_in[6];
    const float* gWhh = (const float*)d_in[7];
    const float* gbih = (const float*)d_in[8];
    const float* gbhh = (const float*)d_in[9];
    const float* Wdyn = (const float*)d_in[10];
    const float* bdyn = (const float*)d_in[11];
    const float* c1Wf=(const float*)d_in[12]; const float* c1bf=(const float*)d_in[13];
    const float* c1Ws=(const float*)d_in[14]; const float* c1bs=(const float*)d_in[15];
    const float* c1g =(const float*)d_in[16]; const float* c1b =(const float*)d_in[17];
    const float* c1m =(const float*)d_in[18]; const float* c1v =(const float*)d_in[19];
    const float* c2Wf=(const float*)d_in[20]; const float* c2bf=(const float*)d_in[21];
    const float* c2Ws=(const float*)d_in[22]; const float* c2bs=(const float*)d_in[23];
    const float* c2g =(const float*)d_in[24]; const float* c2b =(const float*)d_in[25];
    const float* c2m =(const float*)d_in[26]; const float* c2v =(const float*)d_in[27];
    const float* Wn  =(const float*)d_in[28]; const float* bn_ =(const float*)d_in[29];
    const float* l0Wih=(const float*)d_in[30]; const float* l0Whh=(const float*)d_in[31];
    const float* l0bih=(const float*)d_in[32]; const float* l0bhh=(const float*)d_in[33];
    const float* l1Wih=(const float*)d_in[34]; const float* l1Whh=(const float*)d_in[35];
    const float* l1bih=(const float*)d_in[36]; const float* l1bhh=(const float*)d_in[37];
    const float* Wop =(const float*)d_in[38]; const float* bop=(const float*)d_in[39];

    float* ws = (float*)d_ws;
    size_t o = 0;
    float* hist = ws + o; o += (size_t)NN*ENC;
    float* f1   = ws + o; o += (size_t)NN*ENC;
    float* f2   = ws + o; o += (size_t)NN*ENC;
    float* Af   = ws + o; o += (size_t)NN*ENC;
    float* Bf   = ws + o; o += (size_t)NN*ENC;
    float* As   = ws + o; o += (size_t)NN*ENC;
    float* Bs   = ws + o; o += (size_t)NN*ENC;
    float* agg  = ws + o; o += (size_t)NN*ENC;
    float* enc  = ws + o; o += (size_t)BB*2*ENC;
    float* gi0  = ws + o; o += (size_t)BB*4*DEC;
    float* W0T  = ws + o; o += (size_t)128*512;
    unsigned short* pWih  = (unsigned short*)(ws + o); o += (size_t)12*64*8/2;
    unsigned short* pWhh  = (unsigned short*)(ws + o); o += (size_t)24*64*8/2;
    unsigned short* pWdyn = (unsigned short*)(ws + o); o += (size_t)8*64*8/2;
    unsigned short* B0h = (unsigned short*)(ws + o); o += (size_t)32*4*64*8/2;   // 64K shorts
    unsigned short* B0l = (unsigned short*)(ws + o); o += (size_t)32*4*64*8/2;
    unsigned short* B1h = (unsigned short*)(ws + o); o += (size_t)32*8*64*8/2;   // 128K shorts
    unsigned short* B1l = (unsigned short*)(ws + o); o += (size_t)32*8*64*8/2;

    // --- weight packing ---
    pack_frag<<<(12*64+255)/256, 256, 0, stream>>>(gWih, 32, 1, pWih, 12*64);
    pack_frag<<<(24*64+255)/256, 256, 0, stream>>>(gWhh, 64, 2, pWhh, 24*64);
    pack_frag<<<(8*64+255)/256, 256, 0, stream>>>(Wdyn, 64, 2, pWdyn, 8*64);
    pack_frag_hl<<<(32*4*64+255)/256, 256, 0, stream>>>(l0Whh, l0Whh, 128, 128, 4, B0h, B0l, 32*4*64);
    pack_frag_hl<<<(32*8*64+255)/256, 256, 0, stream>>>(l1Wih, l1Whh, 128, 256, 8, B1h, B1l, 32*8*64);

    // --- history encoder (MFMA) ---
    encoder_mfma<<<NN/16, 128, 0, stream>>>(x, Wip, bip, pWih, pWhh, gbih, gbhh, pWdyn, bdyn, hist);

    // --- CGConv 1 ---
    proj_kernel<<<(NN+PROJ_NODES-1)/PROJ_NODES, 256, 0, stream>>>(hist, c1Wf, c1Ws, Af,Bf,As,Bs);
    (void)hipMemsetAsync(agg, 0, (size_t)NN*ENC*sizeof(float), stream);
    edge_kernel<<<EE/16, 256, 0, stream>>>(ei, ea, c1Wf,c1bf,c1Ws,c1bs, Af,Bf,As,Bs, agg);
    bnres_kernel<<<(NN*ENC)/256, 256, 0, stream>>>(hist, agg, c1g,c1b,c1m,c1v, f1);

    // --- CGConv 2 ---
    proj_kernel<<<(NN+PROJ_NODES-1)/PROJ_NODES, 256, 0, stream>>>(f1, c2Wf, c2Ws, Af,Bf,As,Bs);
    (void)hipMemsetAsync(agg, 0, (size_t)NN*ENC*sizeof(float), stream);
    edge_kernel<<<EE/16, 256, 0, stream>>>(ei, ea, c2Wf,c2bf,c2Ws,c2bs, Af,Bf,As,Bs, agg);
    bnres_kernel<<<(NN*ENC)/256, 256, 0, stream>>>(f1, agg, c2g,c2b,c2m,c2v, f2);

    // --- target encoding ---
    target_kernel<<<(BB+3)/4, 256, 0, stream>>>(hist, f2, tgt, Wn, bn_, enc);

    // --- LSTM decoder prep ---
    transpose_w0<<<(512*DEC+255)/256, 256, 0, stream>>>(l0Wih, W0T);
    gi0_kernel<<<BB, 512, 0, stream>>>(enc, W0T, l0bih, l0bhh, gi0);

    // --- LSTM decoder (MFMA) ---
    lstm_mfma<<<BB/LMB, 512, 0, stream>>>(gi0, B0h, B0l, B1h, B1l,
                                          l1bih, l1bhh, Wop, bop, (float*)d_out);
}

// Round 6
// 1358.497 us; speedup vs baseline: 9.5361x; 1.2867x over previous
//
#include <hip/hip_runtime.h>
#include <math.h>

#define NN   50000
#define TT   16
#define EE   800000
#define BB   2000
#define EMBD 32
#define ENC  64
#define DEC  128
#define OUTL 25
#define BN_EPS 1e-5f

typedef short v8s __attribute__((ext_vector_type(8)));
typedef float v4f __attribute__((ext_vector_type(4)));
#define MFMA16(a,b,c) __builtin_amdgcn_mfma_f32_16x16x32_bf16((a),(b),(c),0,0,0)

__device__ __forceinline__ float lrelu(float v){ return v >= 0.f ? v : 0.1f*v; }
__device__ __forceinline__ float sigmoidf_(float v){ return 1.f/(1.f+expf(-v)); }
__device__ __forceinline__ float softplusf_(float v){
    return v > 0.f ? v + log1pf(expf(-v)) : log1pf(expf(v));
}
__device__ __forceinline__ float fsig(float v){ return __builtin_amdgcn_rcpf(1.f + __expf(-v)); }
__device__ __forceinline__ float ftanh(float v){ return 2.f*__builtin_amdgcn_rcpf(1.f + __expf(-2.f*v)) - 1.f; }
__device__ __forceinline__ void fma44(float4& a, float4 w, float4 h){
    a.x += w.x*h.x; a.y += w.y*h.y; a.z += w.z*h.z; a.w += w.w*h.w;
}
__device__ __forceinline__ float hsum(float4 a){ return (a.x+a.y)+(a.z+a.w); }

__device__ __forceinline__ unsigned short f2bf(float f){
    unsigned u = __float_as_uint(f);
    u = u + 0x7FFFu + ((u>>16)&1u);
    return (unsigned short)(u>>16);
}
__device__ __forceinline__ float bf2f(unsigned short s){ return __uint_as_float(((unsigned)s)<<16); }

// split-convert 8 consecutive fp32 -> (hi, lo) bf16 fragments
__device__ __forceinline__ void cvt8(const float* p, v8s& hi, v8s& lo){
    float4 a0 = *(const float4*)p;
    float4 a1 = *(const float4*)(p+4);
    float av[8] = {a0.x,a0.y,a0.z,a0.w,a1.x,a1.y,a1.z,a1.w};
#pragma unroll
    for (int j=0;j<8;j++){
        unsigned short h = f2bf(av[j]);
        hi[j] = (short)h;
        lo[j] = (short)f2bf(av[j] - bf2f(h));
    }
}
__device__ __forceinline__ void cvt8_lrelu(const float* p, v8s& hi, v8s& lo){
    float4 a0 = *(const float4*)p;
    float4 a1 = *(const float4*)(p+4);
    float av[8] = {a0.x,a0.y,a0.z,a0.w,a1.x,a1.y,a1.z,a1.w};
#pragma unroll
    for (int j=0;j<8;j++){
        float a = lrelu(av[j]);
        unsigned short h = f2bf(a);
        hi[j] = (short)h;
        lo[j] = (short)f2bf(a - bf2f(h));
    }
}

// ---------------- pack W[N][K] rows into bf16 B-fragment order (hi only) ----------------
__global__ void pack_frag(const float* __restrict__ W, int K, int KB,
                          unsigned short* __restrict__ out, int total /* NT*KB*64 */){
    int i = blockIdx.x*256 + threadIdx.x;
    if (i >= total) return;
    int l = i & 63, fb = i >> 6;
    int kb = fb % KB, nt = fb / KB;
    int n = nt*16 + (l&15);
    int k0 = kb*32 + ((l>>4)*8);
#pragma unroll
    for (int j=0;j<8;j++) out[i*8+j] = f2bf(W[(size_t)n*K + k0 + j]);
}

// ---------------- pack (Wa | Wb) rows into bf16 B-fragment order (hi only) ----------------
// k < K1 from Wa[n][k], else Wb[n][k-K1]; K = total K, KB = K/32
__global__ void pack_frag_cat(const float* __restrict__ Wa, const float* __restrict__ Wb,
                              int K1, int K, int KB,
                              unsigned short* __restrict__ hi, int total /* NT*KB*64 */){
    int i = blockIdx.x*256 + threadIdx.x;
    if (i >= total) return;
    int l = i & 63, fb = i >> 6;
    int kb = fb % KB, nt = fb / KB;
    int n = nt*16 + (l&15);
    int k0 = kb*32 + ((l>>4)*8);
#pragma unroll
    for (int j=0;j<8;j++){
        int k = k0 + j;
        float v = (k < K1) ? Wa[(size_t)n*K1 + k] : Wb[(size_t)n*(K-K1) + (k-K1)];
        hi[i*8+j] = f2bf(v);
    }
}

// ---------------- GRU encoder v3: MFMA (R4, unchanged) ----------------
#define ESTR 68
__global__ __launch_bounds__(128) void encoder_mfma(
    const float* __restrict__ x,
    const float* __restrict__ Wip, const float* __restrict__ bip,
    const unsigned short* __restrict__ pWih,   // NT=12 KB=1
    const unsigned short* __restrict__ pWhh,   // NT=12 KB=2
    const float* __restrict__ bih, const float* __restrict__ bhh,
    const unsigned short* __restrict__ pWdyn,  // NT=4  KB=2
    const float* __restrict__ bdyn,
    float* __restrict__ hist)
{
    __shared__ float sxl[512];
    __shared__ float femb[16*36];
    __shared__ float sh[16*ESTR];
    const int tid = threadIdx.x;
    const int l   = tid & 63;
    const int w   = tid >> 6;
    const int ln  = l & 15, q = l >> 4;
    const int blk = blockIdx.x;

    ((float4*)sxl)[tid] = ((const float4*)x)[(size_t)blk*128 + tid];
    for (int i=tid;i<16*ESTR;i+=128) sh[i]=0.f;

    const int ek = tid & 31;
    const float w0 = Wip[2*ek], w1 = Wip[2*ek+1], bk = bip[ek];
    const int em0 = tid >> 5;

    float bR[2], bZ[2], bNI[2], bNH[2];
#pragma unroll
    for (int u=0;u<2;u++){
        int g = 2*w + u;
        int c = g*16 + ln;
        bR[u]  = bih[c]       + bhh[c];
        bZ[u]  = bih[64 + c]  + bhh[64 + c];
        bNI[u] = bih[128 + c];
        bNH[u] = bhh[128 + c];
    }
    const v8s* FIH = (const v8s*)pWih;
    const v8s* FHH = (const v8s*)pWhh;
    const v8s* FDY = (const v8s*)pWdyn;
    __syncthreads();

#pragma unroll 1
    for (int t=0;t<TT;t++){
#pragma unroll
        for (int r=0;r<4;r++){
            int m = em0 + r*4;
            float e = w0*sxl[m*32 + 2*t] + w1*sxl[m*32 + 2*t + 1] + bk;
            femb[m*36 + ek] = lrelu(e);
        }
        __syncthreads();
        v8s eh, el; cvt8(&femb[ln*36 + q*8], eh, el);
        v8s h0h, h0l, h1h, h1l;
        cvt8(&sh[ln*ESTR +      q*8], h0h, h0l);
        cvt8(&sh[ln*ESTR + 32 + q*8], h1h, h1l);
        __syncthreads();
#pragma unroll
        for (int u=0;u<2;u++){
            int g = 2*w + u;
            v4f aR = {bR[u],bR[u],bR[u],bR[u]};
            v4f aZ = {bZ[u],bZ[u],bZ[u],bZ[u]};
            v4f aNI= {bNI[u],bNI[u],bNI[u],bNI[u]};
            v4f aNH= {bNH[u],bNH[u],bNH[u],bNH[u]};
            v8s b;
            b = FIH[(g   )*64 + l];   aR = MFMA16(eh,b,aR);  aR = MFMA16(el,b,aR);
            b = FHH[((g)*2+0)*64+l];  aR = MFMA16(h0h,b,aR); aR = MFMA16(h0l,b,aR);
            b = FHH[((g)*2+1)*64+l];  aR = MFMA16(h1h,b,aR); aR = MFMA16(h1l,b,aR);
            b = FIH[(4+g )*64 + l];   aZ = MFMA16(eh,b,aZ);  aZ = MFMA16(el,b,aZ);
            b = FHH[((4+g)*2+0)*64+l];aZ = MFMA16(h0h,b,aZ); aZ = MFMA16(h0l,b,aZ);
            b = FHH[((4+g)*2+1)*64+l];aZ = MFMA16(h1h,b,aZ); aZ = MFMA16(h1l,b,aZ);
            b = FIH[(8+g )*64 + l];   aNI= MFMA16(eh,b,aNI); aNI= MFMA16(el,b,aNI);
            b = FHH[((8+g)*2+0)*64+l];aNH= MFMA16(h0h,b,aNH);aNH= MFMA16(h0l,b,aNH);
            b = FHH[((8+g)*2+1)*64+l];aNH= MFMA16(h1h,b,aNH);aNH= MFMA16(h1l,b,aNH);
#pragma unroll
            for (int i=0;i<4;i++){
                float r_ = fsig(aR[i]);
                float z_ = fsig(aZ[i]);
                float nn_ = ftanh(aNI[i] + r_*aNH[i]);
                int row = q*4 + i, col = g*16 + ln;
                float old = sh[row*ESTR + col];
                sh[row*ESTR + col] = (1.f - z_)*nn_ + z_*old;
            }
        }
    }
    __syncthreads();
    {
        v8s a0h,a0l,a1h,a1l;
        cvt8_lrelu(&sh[ln*ESTR +      q*8], a0h, a0l);
        cvt8_lrelu(&sh[ln*ESTR + 32 + q*8], a1h, a1l);
#pragma unroll
        for (int u=0;u<2;u++){
            int nt = 2*w + u;
            float bb = bdyn[nt*16 + ln];
            v4f acc = {bb,bb,bb,bb};
            v8s b;
            b = FDY[(nt*2+0)*64 + l]; acc = MFMA16(a0h,b,acc); acc = MFMA16(a0l,b,acc);
            b = FDY[(nt*2+1)*64 + l]; acc = MFMA16(a1h,b,acc); acc = MFMA16(a1l,b,acc);
#pragma unroll
            for (int i=0;i<4;i++){
                hist[(size_t)(blk*16 + q*4 + i)*64 + nt*16 + ln] = lrelu(acc[i]);
            }
        }
    }
}

// ---------------- CGConv node projections (unchanged) ----------------
#define PROJ_NODES 32
__global__ __launch_bounds__(256) void proj_kernel(
    const float* __restrict__ xin,
    const float* __restrict__ Wf, const float* __restrict__ Ws,
    float* __restrict__ Af, float* __restrict__ Bf,
    float* __restrict__ As, float* __restrict__ Bs)
{
    __shared__ float sW[2][ENC*ENC];
    __shared__ float sx[PROJ_NODES*ENC];
    const int tid = threadIdx.x;
    const int n0 = blockIdx.x*PROJ_NODES;
    for (int idx=tid; idx<PROJ_NODES*ENC; idx+=256){
        int nn = idx>>6, k = idx&63;
        int n = n0+nn;
        sx[idx] = (n<NN) ? xin[(size_t)n*ENC+k] : 0.f;
    }
    const int c = tid&63, q = tid>>6;
#pragma unroll
    for (int p=0;p<2;p++){
        const float* W = p ? Ws : Wf;
        float* oD = p ? As : Af;
        float* oS = p ? Bs : Bf;
        __syncthreads();
        for (int idx=tid; idx<2*ENC*ENC; idx+=256){
            int m = idx>>12, r = idx&4095;
            int cc = r>>6, k = r&63;
            sW[m][k*64+cc] = W[cc*130 + m*64 + k];
        }
        __syncthreads();
        for (int nn=q; nn<PROJ_NODES; nn+=4){
            int n = n0+nn;
            if (n>=NN) break;
            float aD=0.f, aS=0.f;
#pragma unroll
            for (int k=0;k<ENC;k++){
                float xv = sx[nn*ENC+k];
                aD += sW[0][k*64+c]*xv;
                aS += sW[1][k*64+c]*xv;
            }
            oD[(size_t)n*ENC+c]=aD;
            oS[(size_t)n*ENC+c]=aS;
        }
    }
}

// ---------------- CGConv edge kernel (unchanged) ----------------
__global__ __launch_bounds__(256) void edge_kernel(
    const int* __restrict__ ei, const float* __restrict__ ea,
    const float* __restrict__ Wf, const float* __restrict__ bf,
    const float* __restrict__ Ws, const float* __restrict__ bs,
    const float* __restrict__ Af, const float* __restrict__ Bf,
    const float* __restrict__ As, const float* __restrict__ Bs,
    float* __restrict__ agg)
{
    __shared__ float cf0[64], cf1[64], cfb[64], cs0[64], cs1[64], csb[64];
    const int tid=threadIdx.x;
    if (tid<64){
        cf0[tid]=Wf[tid*130+128]; cf1[tid]=Wf[tid*130+129]; cfb[tid]=bf[tid];
        cs0[tid]=Ws[tid*130+128]; cs1[tid]=Ws[tid*130+129]; csb[tid]=bs[tid];
    }
    __syncthreads();
    const int wid = tid>>6, c = tid&63;
    const int ebase = blockIdx.x*16 + wid*4;
#pragma unroll 1
    for (int i=0;i<4;i++){
        int e = ebase + i;
        if (e >= EE) break;
        int src = ei[e], dst = ei[EE+e];
        float e0 = ea[2*(size_t)e], e1 = ea[2*(size_t)e+1];
        float gf = Af[(size_t)dst*64+c] + Bf[(size_t)src*64+c] + cf0[c]*e0 + cf1[c]*e1 + cfb[c];
        float gs = As[(size_t)dst*64+c] + Bs[(size_t)src*64+c] + cs0[c]*e0 + cs1[c]*e1 + csb[c];
        float m = sigmoidf_(gf)*softplusf_(gs);
        atomicAdd(&agg[(size_t)dst*64+c], m);
    }
}

// ---------------- BN (inference) + residual (unchanged) ----------------
__global__ void bnres_kernel(const float* __restrict__ xin, const float* __restrict__ agg,
    const float* __restrict__ gamma, const float* __restrict__ beta,
    const float* __restrict__ mean, const float* __restrict__ var,
    float* __restrict__ outp)
{
    size_t i = (size_t)blockIdx.x*256 + threadIdx.x;
    if (i >= (size_t)NN*ENC) return;
    int c = (int)(i&63);
    float a = (agg[i]-mean[c])*rsqrtf(var[c]+BN_EPS)*gamma[c] + beta[c];
    outp[i] = xin[i] + a;
}

// ---------------- target gather + nbrs linear + concat (unchanged) ----------------
__global__ __launch_bounds__(256) void target_kernel(
    const float* __restrict__ hist, const float* __restrict__ f2,
    const int* __restrict__ tgt,
    const float* __restrict__ Wn, const float* __restrict__ bn_,
    float* __restrict__ enc)
{
    const int tid=threadIdx.x;
    const int c = tid&63, q = tid>>6;
    const int b = blockIdx.x*4 + q;
    if (b>=BB) return;
    const int n = tgt[b];
    float a = bn_[c];
#pragma unroll
    for (int k=0;k<ENC;k++) a += Wn[c*64+k]*f2[(size_t)n*64+k];
    enc[(size_t)b*128 + 64 + c] = lrelu(a);
    enc[(size_t)b*128 + c]      = hist[(size_t)n*64+c];
}

// ---------------- transpose lstm0_Wih [512][128] -> [128][512] ----------------
__global__ void transpose_w0(const float* __restrict__ W, float* __restrict__ WT){
    int i = blockIdx.x*256+threadIdx.x;
    if (i >= 512*DEC) return;
    int g = i>>7, k = i&127;
    WT[k*512+g] = W[i];
}

// ---------------- gi0 = enc @ Wih0^T + bih0 + bhh0 (time-invariant) ----------------
__global__ __launch_bounds__(512) void gi0_kernel(
    const float* __restrict__ enc, const float* __restrict__ W0T,
    const float* __restrict__ bih0, const float* __restrict__ bhh0,
    float* __restrict__ gi0)
{
    __shared__ float se[128];
    const int b = blockIdx.x, g = threadIdx.x;
    if (g < 128) se[g] = enc[(size_t)b*128+g];
    __syncthreads();
    float a = bih0[g]+bhh0[g];
#pragma unroll 4
    for (int k=0;k<128;k++) a += W0T[k*512+g]*se[k];
    gi0[(size_t)b*512+g] = a;
}

// ---------------- 2-layer LSTM decoder v3: register-resident MFMA ----------------
// R5 post-mortem: weight stream (768KB/block/step, 2.4GB total) was latency/BW
// bound at 1 block/CU: FETCH 775MB, MfmaUtil 4%. v3: each wave's B-frag slice
// (48 v8s = 192 VGPRs, bf16 hi-only) loaded ONCE into registers before the
// t-loop; A (h state) stays hi+lo split (2-term MFMA). t-loop has ZERO global
// loads. gi0 lives in LDS to stay under the 256-VGPR / 2-waves-per-EU cap.
#define LMB 16
__global__ __launch_bounds__(512, 2) void lstm_mfma(
    const float* __restrict__ gi0,
    const unsigned short* __restrict__ B0h,   // NT=32 KB=4, hi
    const unsigned short* __restrict__ B1h,   // NT=32 KB=8, hi
    const float* __restrict__ bih1, const float* __restrict__ bhh1,
    const float* __restrict__ Wop, const float* __restrict__ bop,
    float* __restrict__ outp)
{
    __shared__ unsigned short h0hi[4*512], h0lo[4*512];   // frag order: kb*512 + lane*8 + j
    __shared__ unsigned short h1hi[4*512], h1lo[4*512];
    __shared__ float sgi[LMB*512];                        // 32KB: layer0 input gates
    __shared__ float sh1f[16*132];                        // row-layout h1 for out-proj
    __shared__ float sWop[256];
    const int tid = threadIdx.x;
    const int l = tid & 63;
    const int w = tid >> 6;           // wave 0..7
    const int c = l & 15;             // col within tile
    const int q = l >> 4;             // quad -> rows m = q*4+i
    const int j = w*16 + c;           // owned hidden unit (all 4 gates)
    const int b0 = blockIdx.x*LMB;

    for (int i=tid;i<4*512;i+=512){ h0hi[i]=0; h0lo[i]=0; h1hi[i]=0; h1lo[i]=0; }
    for (int i=tid;i<LMB*512;i+=512) sgi[i] = gi0[(size_t)b0*512 + i];
    if (tid < 256) sWop[tid] = Wop[tid];

    // ---- register-resident weight fragments (hi-only bf16) ----
    const v8s* F0 = (const v8s*)B0h;
    const v8s* F1 = (const v8s*)B1h;
    v8s W0[16];   // [g*4+kb]
    v8s W1[32];   // [g*8+kb]
#pragma unroll
    for (int g=0;g<4;g++)
#pragma unroll
        for (int kb=0;kb<4;kb++) W0[g*4+kb] = F0[((g*8+w)*4 + kb)*64 + l];
#pragma unroll
    for (int g=0;g<4;g++)
#pragma unroll
        for (int kb=0;kb<8;kb++) W1[g*8+kb] = F1[((g*8+w)*8 + kb)*64 + l];

    float b1[4];
#pragma unroll
    for (int g=0;g<4;g++) b1[g] = bih1[g*128+j] + bhh1[g*128+j];
    float c0[4] = {0,0,0,0}, c1[4] = {0,0,0,0};
    const float bo0 = bop[0], bo1 = bop[1];
    const int kbw = j>>5, qw = (j>>3)&3, jw = j&7;   // write-back frag coords for unit j
    __syncthreads();

#pragma unroll 1
    for (int t=0;t<OUTL;t++){
        // ---- layer 0: gates[m][g*128+j] = gi0 + h0_prev @ Whh0^T ----
        v4f acc[4];
#pragma unroll
        for (int g=0;g<4;g++){
            v4f t4 = { sgi[(q*4+0)*512 + g*128 + j], sgi[(q*4+1)*512 + g*128 + j],
                       sgi[(q*4+2)*512 + g*128 + j], sgi[(q*4+3)*512 + g*128 + j] };
            acc[g] = t4;
        }
#pragma unroll
        for (int kb=0;kb<4;kb++){
            v8s ah = *(const v8s*)&h0hi[kb*512 + l*8];
            v8s al = *(const v8s*)&h0lo[kb*512 + l*8];
#pragma unroll
            for (int g=0;g<4;g++){
                acc[g] = MFMA16(ah, W0[g*4+kb], acc[g]);
                acc[g] = MFMA16(al, W0[g*4+kb], acc[g]);
            }
        }
        float hnew[4];
#pragma unroll
        for (int i=0;i<4;i++){
            c0[i] = fsig(acc[1][i])*c0[i] + fsig(acc[0][i])*ftanh(acc[2][i]);
            hnew[i] = fsig(acc[3][i])*ftanh(c0[i]);
        }
        __syncthreads();     // all waves done reading h0_prev
#pragma unroll
        for (int i=0;i<4;i++){
            int off = kbw*512 + (qw*16 + q*4 + i)*8 + jw;
            unsigned short h = f2bf(hnew[i]);
            h0hi[off] = h;
            h0lo[off] = f2bf(hnew[i] - bf2f(h));
        }
        __syncthreads();     // h0_new visible

        // ---- layer 1: gates = b1 + [h0_new | h1_prev] @ [Wih1|Whh1]^T ----
        v4f a1[4];
#pragma unroll
        for (int g=0;g<4;g++){ v4f t4={b1[g],b1[g],b1[g],b1[g]}; a1[g]=t4; }
#pragma unroll
        for (int kb=0;kb<8;kb++){
            const unsigned short* hb = (kb<4) ? h0hi : h1hi;
            const unsigned short* lb = (kb<4) ? h0lo : h1lo;
            int kk = kb & 3;
            v8s ah = *(const v8s*)&hb[kk*512 + l*8];
            v8s al = *(const v8s*)&lb[kk*512 + l*8];
#pragma unroll
            for (int g=0;g<4;g++){
                a1[g] = MFMA16(ah, W1[g*8+kb], a1[g]);
                a1[g] = MFMA16(al, W1[g*8+kb], a1[g]);
            }
        }
        float h1new[4];
#pragma unroll
        for (int i=0;i<4;i++){
            c1[i] = fsig(a1[1][i])*c1[i] + fsig(a1[0][i])*ftanh(a1[2][i]);
            h1new[i] = fsig(a1[3][i])*ftanh(c1[i]);
        }
        __syncthreads();     // all waves done reading h1_prev
#pragma unroll
        for (int i=0;i<4;i++){
            int off = kbw*512 + (qw*16 + q*4 + i)*8 + jw;
            unsigned short h = f2bf(h1new[i]);
            h1hi[off] = h;
            h1lo[off] = f2bf(h1new[i] - bf2f(h));
            sh1f[(q*4+i)*132 + j] = h1new[i];
        }
        __syncthreads();     // h1_new + sh1f visible

        // ---- output projection: fut[b0+m][t][o] ----
        if (tid < 32){
            int m = tid>>1, o = tid&1;
            const float4* hv = (const float4*)&sh1f[m*132];
            const float4* wv = (const float4*)&sWop[o*128];
            float4 s4={0,0,0,0};
#pragma unroll
            for (int k4=0;k4<32;k4++) fma44(s4, wv[k4], hv[k4]);
            outp[(size_t)(b0+m)*(OUTL*2) + t*2 + o] = hsum(s4) + (o ? bo1 : bo0);
        }
        // out-proj readers finish before next write to sh1f (2 barriers away)
    }
}

extern "C" void kernel_launch(void* const* d_in, const int* in_sizes, int n_in,
                              void* d_out, int out_size, void* d_ws, size_t ws_size,
                              hipStream_t stream)
{
    const float* x    = (const float*)d_in[0];
    const int*   ei   = (const int*)d_in[1];
    const float* ea   = (const float*)d_in[2];
    const int*   tgt  = (const int*)d_in[3];
    const float* Wip  = (const float*)d_in[4];
    const float* bip  = (const float*)d_in[5];
    const float* gWih = (const float*)d_in[6];
    const float* gWhh = (const float*)d_in[7];
    const float* gbih = (const float*)d_in[8];
    const float* gbhh = (const float*)d_in[9];
    const float* Wdyn = (const float*)d_in[10];
    const float* bdyn = (const float*)d_in[11];
    const float* c1Wf=(const float*)d_in[12]; const float* c1bf=(const float*)d_in[13];
    const float* c1Ws=(const float*)d_in[14]; const float* c1bs=(const float*)d_in[15];
    const float* c1g =(const float*)d_in[16]; const float* c1b =(const float*)d_in[17];
    const float* c1m =(const float*)d_in[18]; const float* c1v =(const float*)d_in[19];
    const float* c2Wf=(const float*)d_in[20]; const float* c2bf=(const float*)d_in[21];
    const float* c2Ws=(const float*)d_in[22]; const float* c2bs=(const float*)d_in[23];
    const float* c2g =(const float*)d_in[24]; const float* c2b =(const float*)d_in[25];
    const float* c2m =(const float*)d_in[26]; const float* c2v =(const float*)d_in[27];
    const float* Wn  =(const float*)d_in[28]; const float* bn_ =(const float*)d_in[29];
    const float* l0Wih=(const float*)d_in[30]; const float* l0Whh=(const float*)d_in[31];
    const float* l0bih=(const float*)d_in[32]; const float* l0bhh=(const float*)d_in[33];
    const float* l1Wih=(const float*)d_in[34]; const float* l1Whh=(const float*)d_in[35];
    const float* l1bih=(const float*)d_in[36]; const float* l1bhh=(const float*)d_in[37];
    const float* Wop =(const float*)d_in[38]; const float* bop=(const float*)d_in[39];

    float* ws = (float*)d_ws;
    size_t o = 0;
    float* hist = ws + o; o += (size_t)NN*ENC;
    float* f1   = ws + o; o += (size_t)NN*ENC;
    float* f2   = ws + o; o += (size_t)NN*ENC;
    float* Af   = ws + o; o += (size_t)NN*ENC;
    float* Bf   = ws + o; o += (size_t)NN*ENC;
    float* As   = ws + o; o += (size_t)NN*ENC;
    float* Bs   = ws + o; o += (size_t)NN*ENC;
    float* agg  = ws + o; o += (size_t)NN*ENC;
    float* enc  = ws + o; o += (size_t)BB*2*ENC;
    float* gi0  = ws + o; o += (size_t)BB*4*DEC;
    float* W0T  = ws + o; o += (size_t)128*512;
    unsigned short* pWih  = (unsigned short*)(ws + o); o += (size_t)12*64*8/2;
    unsigned short* pWhh  = (unsigned short*)(ws + o); o += (size_t)24*64*8/2;
    unsigned short* pWdyn = (unsigned short*)(ws + o); o += (size_t)8*64*8/2;
    unsigned short* B0h = (unsigned short*)(ws + o); o += (size_t)32*4*64*8/2;   // 64K shorts
    unsigned short* B1h = (unsigned short*)(ws + o); o += (size_t)32*8*64*8/2;   // 128K shorts

    // --- weight packing ---
    pack_frag<<<(12*64+255)/256, 256, 0, stream>>>(gWih, 32, 1, pWih, 12*64);
    pack_frag<<<(24*64+255)/256, 256, 0, stream>>>(gWhh, 64, 2, pWhh, 24*64);
    pack_frag<<<(8*64+255)/256, 256, 0, stream>>>(Wdyn, 64, 2, pWdyn, 8*64);
    pack_frag_cat<<<(32*4*64+255)/256, 256, 0, stream>>>(l0Whh, l0Whh, 128, 128, 4, B0h, 32*4*64);
    pack_frag_cat<<<(32*8*64+255)/256, 256, 0, stream>>>(l1Wih, l1Whh, 128, 256, 8, B1h, 32*8*64);

    // --- history encoder (MFMA) ---
    encoder_mfma<<<NN/16, 128, 0, stream>>>(x, Wip, bip, pWih, pWhh, gbih, gbhh, pWdyn, bdyn, hist);

    // --- CGConv 1 ---
    proj_kernel<<<(NN+PROJ_NODES-1)/PROJ_NODES, 256, 0, stream>>>(hist, c1Wf, c1Ws, Af,Bf,As,Bs);
    (void)hipMemsetAsync(agg, 0, (size_t)NN*ENC*sizeof(float), stream);
    edge_kernel<<<EE/16, 256, 0, stream>>>(ei, ea, c1Wf,c1bf,c1Ws,c1bs, Af,Bf,As,Bs, agg);
    bnres_kernel<<<(NN*ENC)/256, 256, 0, stream>>>(hist, agg, c1g,c1b,c1m,c1v, f1);

    // --- CGConv 2 ---
    proj_kernel<<<(NN+PROJ_NODES-1)/PROJ_NODES, 256, 0, stream>>>(f1, c2Wf, c2Ws, Af,Bf,As,Bs);
    (void)hipMemsetAsync(agg, 0, (size_t)NN*ENC*sizeof(float), stream);
    edge_kernel<<<EE/16, 256, 0, stream>>>(ei, ea, c2Wf,c2bf,c2Ws,c2bs, Af,Bf,As,Bs, agg);
    bnres_kernel<<<(NN*ENC)/256, 256, 0, stream>>>(f1, agg, c2g,c2b,c2m,c2v, f2);

    // --- target encoding ---
    target_kernel<<<(BB+3)/4, 256, 0, stream>>>(hist, f2, tgt, Wn, bn_, enc);

    // --- LSTM decoder prep ---
    transpose_w0<<<(512*DEC+255)/256, 256, 0, stream>>>(l0Wih, W0T);
    gi0_kernel<<<BB, 512, 0, stream>>>(enc, W0T, l0bih, l0bhh, gi0);

    // --- LSTM decoder (register-resident MFMA) ---
    lstm_mfma<<<BB/LMB, 512, 0, stream>>>(gi0, B0h, B1h,
                                          l1bih, l1bhh, Wop, bop, (float*)d_out);
}

// Round 7
// 1102.816 us; speedup vs baseline: 11.7470x; 1.2318x over previous
//
#include <hip/hip_runtime.h>
#include <math.h>

#define NN   50000
#define TT   16
#define EE   800000
#define BB   2000
#define EMBD 32
#define ENC  64
#define DEC  128
#define OUTL 25
#define BN_EPS 1e-5f

typedef short v8s __attribute__((ext_vector_type(8)));
typedef float v4f __attribute__((ext_vector_type(4)));
#define MFMA16(a,b,c) __builtin_amdgcn_mfma_f32_16x16x32_bf16((a),(b),(c),0,0,0)

__device__ __forceinline__ float lrelu(float v){ return v >= 0.f ? v : 0.1f*v; }
__device__ __forceinline__ float fsig(float v){ return __builtin_amdgcn_rcpf(1.f + __expf(-v)); }
__device__ __forceinline__ float ftanh(float v){ return 2.f*__builtin_amdgcn_rcpf(1.f + __expf(-2.f*v)) - 1.f; }
__device__ __forceinline__ float fsoftplus(float v){
    return v > 15.f ? v : __logf(1.f + __expf(v));
}
__device__ __forceinline__ void fma44(float4& a, float4 w, float4 h){
    a.x += w.x*h.x; a.y += w.y*h.y; a.z += w.z*h.z; a.w += w.w*h.w;
}
__device__ __forceinline__ float hsum(float4 a){ return (a.x+a.y)+(a.z+a.w); }

__device__ __forceinline__ unsigned short f2bf(float f){
    unsigned u = __float_as_uint(f);
    u = u + 0x7FFFu + ((u>>16)&1u);
    return (unsigned short)(u>>16);
}
__device__ __forceinline__ float bf2f(unsigned short s){ return __uint_as_float(((unsigned)s)<<16); }

__device__ __forceinline__ void cvt8(const float* p, v8s& hi, v8s& lo){
    float4 a0 = *(const float4*)p;
    float4 a1 = *(const float4*)(p+4);
    float av[8] = {a0.x,a0.y,a0.z,a0.w,a1.x,a1.y,a1.z,a1.w};
#pragma unroll
    for (int j=0;j<8;j++){
        unsigned short h = f2bf(av[j]);
        hi[j] = (short)h;
        lo[j] = (short)f2bf(av[j] - bf2f(h));
    }
}
__device__ __forceinline__ void cvt8_lrelu(const float* p, v8s& hi, v8s& lo){
    float4 a0 = *(const float4*)p;
    float4 a1 = *(const float4*)(p+4);
    float av[8] = {a0.x,a0.y,a0.z,a0.w,a1.x,a1.y,a1.z,a1.w};
#pragma unroll
    for (int j=0;j<8;j++){
        float a = lrelu(av[j]);
        unsigned short h = f2bf(a);
        hi[j] = (short)h;
        lo[j] = (short)f2bf(a - bf2f(h));
    }
}

// ---------------- pack W[N][K] rows into bf16 B-fragment order (hi only) ----------------
__global__ void pack_frag(const float* __restrict__ W, int K, int KB,
                          unsigned short* __restrict__ out, int total){
    int i = blockIdx.x*256 + threadIdx.x;
    if (i >= total) return;
    int l = i & 63, fb = i >> 6;
    int kb = fb % KB, nt = fb / KB;
    int n = nt*16 + (l&15);
    int k0 = kb*32 + ((l>>4)*8);
#pragma unroll
    for (int j=0;j<8;j++) out[i*8+j] = f2bf(W[(size_t)n*K + k0 + j]);
}

// ---------------- pack (Wa | Wb) rows into bf16 B-fragment order (hi only) ----------------
__global__ void pack_frag_cat(const float* __restrict__ Wa, const float* __restrict__ Wb,
                              int K1, int K, int KB,
                              unsigned short* __restrict__ hi, int total){
    int i = blockIdx.x*256 + threadIdx.x;
    if (i >= total) return;
    int l = i & 63, fb = i >> 6;
    int kb = fb % KB, nt = fb / KB;
    int n = nt*16 + (l&15);
    int k0 = kb*32 + ((l>>4)*8);
#pragma unroll
    for (int j=0;j<8;j++){
        int k = k0 + j;
        float v = (k < K1) ? Wa[(size_t)n*K1 + k] : Wb[(size_t)n*(K-K1) + (k-K1)];
        hi[i*8+j] = f2bf(v);
    }
}

// ---------------- GRU encoder v3: MFMA (unchanged) ----------------
#define ESTR 68
__global__ __launch_bounds__(128) void encoder_mfma(
    const float* __restrict__ x,
    const float* __restrict__ Wip, const float* __restrict__ bip,
    const unsigned short* __restrict__ pWih,
    const unsigned short* __restrict__ pWhh,
    const float* __restrict__ bih, const float* __restrict__ bhh,
    const unsigned short* __restrict__ pWdyn,
    const float* __restrict__ bdyn,
    float* __restrict__ hist)
{
    __shared__ float sxl[512];
    __shared__ float femb[16*36];
    __shared__ float sh[16*ESTR];
    const int tid = threadIdx.x;
    const int l   = tid & 63;
    const int w   = tid >> 6;
    const int ln  = l & 15, q = l >> 4;
    const int blk = blockIdx.x;

    ((float4*)sxl)[tid] = ((const float4*)x)[(size_t)blk*128 + tid];
    for (int i=tid;i<16*ESTR;i+=128) sh[i]=0.f;

    const int ek = tid & 31;
    const float w0 = Wip[2*ek], w1 = Wip[2*ek+1], bk = bip[ek];
    const int em0 = tid >> 5;

    float bR[2], bZ[2], bNI[2], bNH[2];
#pragma unroll
    for (int u=0;u<2;u++){
        int g = 2*w + u;
        int c = g*16 + ln;
        bR[u]  = bih[c]       + bhh[c];
        bZ[u]  = bih[64 + c]  + bhh[64 + c];
        bNI[u] = bih[128 + c];
        bNH[u] = bhh[128 + c];
    }
    const v8s* FIH = (const v8s*)pWih;
    const v8s* FHH = (const v8s*)pWhh;
    const v8s* FDY = (const v8s*)pWdyn;
    __syncthreads();

#pragma unroll 1
    for (int t=0;t<TT;t++){
#pragma unroll
        for (int r=0;r<4;r++){
            int m = em0 + r*4;
            float e = w0*sxl[m*32 + 2*t] + w1*sxl[m*32 + 2*t + 1] + bk;
            femb[m*36 + ek] = lrelu(e);
        }
        __syncthreads();
        v8s eh, el; cvt8(&femb[ln*36 + q*8], eh, el);
        v8s h0h, h0l, h1h, h1l;
        cvt8(&sh[ln*ESTR +      q*8], h0h, h0l);
        cvt8(&sh[ln*ESTR + 32 + q*8], h1h, h1l);
        __syncthreads();
#pragma unroll
        for (int u=0;u<2;u++){
            int g = 2*w + u;
            v4f aR = {bR[u],bR[u],bR[u],bR[u]};
            v4f aZ = {bZ[u],bZ[u],bZ[u],bZ[u]};
            v4f aNI= {bNI[u],bNI[u],bNI[u],bNI[u]};
            v4f aNH= {bNH[u],bNH[u],bNH[u],bNH[u]};
            v8s b;
            b = FIH[(g   )*64 + l];   aR = MFMA16(eh,b,aR);  aR = MFMA16(el,b,aR);
            b = FHH[((g)*2+0)*64+l];  aR = MFMA16(h0h,b,aR); aR = MFMA16(h0l,b,aR);
            b = FHH[((g)*2+1)*64+l];  aR = MFMA16(h1h,b,aR); aR = MFMA16(h1l,b,aR);
            b = FIH[(4+g )*64 + l];   aZ = MFMA16(eh,b,aZ);  aZ = MFMA16(el,b,aZ);
            b = FHH[((4+g)*2+0)*64+l];aZ = MFMA16(h0h,b,aZ); aZ = MFMA16(h0l,b,aZ);
            b = FHH[((4+g)*2+1)*64+l];aZ = MFMA16(h1h,b,aZ); aZ = MFMA16(h1l,b,aZ);
            b = FIH[(8+g )*64 + l];   aNI= MFMA16(eh,b,aNI); aNI= MFMA16(el,b,aNI);
            b = FHH[((8+g)*2+0)*64+l];aNH= MFMA16(h0h,b,aNH);aNH= MFMA16(h0l,b,aNH);
            b = FHH[((8+g)*2+1)*64+l];aNH= MFMA16(h1h,b,aNH);aNH= MFMA16(h1l,b,aNH);
#pragma unroll
            for (int i=0;i<4;i++){
                float r_ = fsig(aR[i]);
                float z_ = fsig(aZ[i]);
                float nn_ = ftanh(aNI[i] + r_*aNH[i]);
                int row = q*4 + i, col = g*16 + ln;
                float old = sh[row*ESTR + col];
                sh[row*ESTR + col] = (1.f - z_)*nn_ + z_*old;
            }
        }
    }
    __syncthreads();
    {
        v8s a0h,a0l,a1h,a1l;
        cvt8_lrelu(&sh[ln*ESTR +      q*8], a0h, a0l);
        cvt8_lrelu(&sh[ln*ESTR + 32 + q*8], a1h, a1l);
#pragma unroll
        for (int u=0;u<2;u++){
            int nt = 2*w + u;
            float bb = bdyn[nt*16 + ln];
            v4f acc = {bb,bb,bb,bb};
            v8s b;
            b = FDY[(nt*2+0)*64 + l]; acc = MFMA16(a0h,b,acc); acc = MFMA16(a0l,b,acc);
            b = FDY[(nt*2+1)*64 + l]; acc = MFMA16(a1h,b,acc); acc = MFMA16(a1l,b,acc);
#pragma unroll
            for (int i=0;i<4;i++){
                hist[(size_t)(blk*16 + q*4 + i)*64 + nt*16 + ln] = lrelu(acc[i]);
            }
        }
    }
}

// ---------------- CGConv node projections (R6 + pad 64->65: stride-64 writes
// were all-lanes-one-bank, 24.8M conflict cycles) ----------------
#define PROJ_NODES 32
#define WPAD 65
__global__ __launch_bounds__(256) void proj_kernel(
    const float* __restrict__ xin,
    const float* __restrict__ Wf, const float* __restrict__ Ws,
    float* __restrict__ Af, float* __restrict__ Bf,
    float* __restrict__ As, float* __restrict__ Bs)
{
    __shared__ float sW[2][ENC*WPAD];
    __shared__ float sx[PROJ_NODES*ENC];
    const int tid = threadIdx.x;
    const int n0 = blockIdx.x*PROJ_NODES;
    for (int idx=tid; idx<PROJ_NODES*ENC; idx+=256){
        int nn = idx>>6, k = idx&63;
        int n = n0+nn;
        sx[idx] = (n<NN) ? xin[(size_t)n*ENC+k] : 0.f;
    }
    const int c = tid&63, q = tid>>6;
#pragma unroll
    for (int p=0;p<2;p++){
        const float* W = p ? Ws : Wf;
        float* oD = p ? As : Af;
        float* oS = p ? Bs : Bf;
        __syncthreads();
        for (int idx=tid; idx<2*ENC*ENC; idx+=256){
            int m = idx>>12, r = idx&4095;
            int cc = r>>6, k = r&63;
            sW[m][k*WPAD+cc] = W[cc*130 + m*64 + k];
        }
        __syncthreads();
        for (int nn=q; nn<PROJ_NODES; nn+=4){
            int n = n0+nn;
            if (n>=NN) break;
            float aD=0.f, aS=0.f;
#pragma unroll
            for (int k=0;k<ENC;k++){
                float xv = sx[nn*ENC+k];
                aD += sW[0][k*WPAD+c]*xv;
                aS += sW[1][k*WPAD+c]*xv;
            }
            oD[(size_t)n*ENC+c]=aD;
            oS[(size_t)n*ENC+c]=aS;
        }
    }
}

// ---------------- dst counting sort (built once per launch, reused by both convs) ----------------
__global__ void count_kernel(const int* __restrict__ ei, int* __restrict__ cnt){
    int e = blockIdx.x*256 + threadIdx.x;
    if (e < EE) atomicAdd(&cnt[ei[EE+e]], 1);
}

__global__ __launch_bounds__(1024) void scan_kernel(const int* __restrict__ cnt,
                                                    int* __restrict__ off, int* __restrict__ cur){
    __shared__ int ssum[1024];
    const int t = threadIdx.x;
    const int CH = (NN + 1023)/1024;      // 49
    const int base = t*CH;
    int s = 0;
    for (int i=0;i<CH;i++){ int idx=base+i; if (idx<NN) s += cnt[idx]; }
    ssum[t] = s;
    __syncthreads();
    for (int d=1; d<1024; d<<=1){
        int v = (t>=d) ? ssum[t-d] : 0;
        __syncthreads();
        ssum[t] += v;
        __syncthreads();
    }
    int ex = (t==0) ? 0 : ssum[t-1];
    for (int i=0;i<CH;i++){
        int idx=base+i;
        if (idx<NN){ off[idx]=ex; cur[idx]=ex; ex += cnt[idx]; }
    }
    if (t==1023) off[NN] = ssum[1023];
}

__global__ void scatter_kernel(const int* __restrict__ ei, int* __restrict__ cur,
                               int* __restrict__ sorted){
    int e = blockIdx.x*256 + threadIdx.x;
    if (e >= EE) return;
    int d = ei[EE+e];
    int p = atomicAdd(&cur[d], 1);
    sorted[p] = e;
}

// ---------------- CGConv aggregate: wave per node, no atomics, fused BN+residual ----------------
// R6 post-mortem: atomic scatter wrote 200MB to HBM (device-scope atomics round-
// trip across XCDs) + 4 row-gathers/edge. Here: dst rows hoisted (2 gathers/edge),
// register accumulate, one write, BN+residual fused.
__global__ __launch_bounds__(256) void cg_agg(
    const float* __restrict__ xin,
    const int* __restrict__ ei, const float* __restrict__ ea,
    const int* __restrict__ sorted, const int* __restrict__ off,
    const float* __restrict__ Wf, const float* __restrict__ bf,
    const float* __restrict__ Ws, const float* __restrict__ bs,
    const float* __restrict__ Af, const float* __restrict__ Bf,
    const float* __restrict__ As, const float* __restrict__ Bs,
    const float* __restrict__ gamma, const float* __restrict__ beta,
    const float* __restrict__ mean, const float* __restrict__ var,
    float* __restrict__ outp)
{
    const int tid = threadIdx.x;
    const int c = tid & 63, wid = tid >> 6;
    const int n = blockIdx.x*4 + wid;
    if (n >= NN) return;

    const float wf0 = Wf[c*130+128], wf1 = Wf[c*130+129], bfc = bf[c];
    const float ws0 = Ws[c*130+128], ws1 = Ws[c*130+129], bsc = bs[c];
    const float afd = Af[(size_t)n*64+c], asd = As[(size_t)n*64+c];

    float acc = 0.f;
    const int i1 = off[n+1];
#pragma unroll 1
    for (int i=off[n]; i<i1; ++i){
        int eid = sorted[i];
        int src = ei[eid];
        float e0 = ea[2*(size_t)eid], e1 = ea[2*(size_t)eid+1];
        float gf = afd + Bf[(size_t)src*64+c] + wf0*e0 + wf1*e1 + bfc;
        float gs = asd + Bs[(size_t)src*64+c] + ws0*e0 + ws1*e1 + bsc;
        acc += fsig(gf) * fsoftplus(gs);
    }
    float bn = (acc - mean[c])*rsqrtf(var[c]+BN_EPS)*gamma[c] + beta[c];
    outp[(size_t)n*64+c] = xin[(size_t)n*64+c] + bn;
}

// ---------------- target gather + nbrs linear + concat (unchanged) ----------------
__global__ __launch_bounds__(256) void target_kernel(
    const float* __restrict__ hist, const float* __restrict__ f2,
    const int* __restrict__ tgt,
    const float* __restrict__ Wn, const float* __restrict__ bn_,
    float* __restrict__ enc)
{
    const int tid=threadIdx.x;
    const int c = tid&63, q = tid>>6;
    const int b = blockIdx.x*4 + q;
    if (b>=BB) return;
    const int n = tgt[b];
    float a = bn_[c];
#pragma unroll
    for (int k=0;k<ENC;k++) a += Wn[c*64+k]*f2[(size_t)n*64+k];
    enc[(size_t)b*128 + 64 + c] = lrelu(a);
    enc[(size_t)b*128 + c]      = hist[(size_t)n*64+c];
}

// ---------------- transpose lstm0_Wih [512][128] -> [128][512] ----------------
__global__ void transpose_w0(const float* __restrict__ W, float* __restrict__ WT){
    int i = blockIdx.x*256+threadIdx.x;
    if (i >= 512*DEC) return;
    int g = i>>7, k = i&127;
    WT[k*512+g] = W[i];
}

// ---------------- gi0 = enc @ Wih0^T + bih0 + bhh0 (time-invariant) ----------------
__global__ __launch_bounds__(512) void gi0_kernel(
    const float* __restrict__ enc, const float* __restrict__ W0T,
    const float* __restrict__ bih0, const float* __restrict__ bhh0,
    float* __restrict__ gi0)
{
    __shared__ float se[128];
    const int b = blockIdx.x, g = threadIdx.x;
    if (g < 128) se[g] = enc[(size_t)b*128+g];
    __syncthreads();
    float a = bih0[g]+bhh0[g];
#pragma unroll 4
    for (int k=0;k<128;k++) a += W0T[k*512+g]*se[k];
    gi0[(size_t)b*512+g] = a;
}

// ---------------- 2-layer LSTM decoder v3: register-resident MFMA (unchanged) ----------------
#define LMB 16
__global__ __launch_bounds__(512, 2) void lstm_mfma(
    const float* __restrict__ gi0,
    const unsigned short* __restrict__ B0h,
    const unsigned short* __restrict__ B1h,
    const float* __restrict__ bih1, const float* __restrict__ bhh1,
    const float* __restrict__ Wop, const float* __restrict__ bop,
    float* __restrict__ outp)
{
    __shared__ unsigned short h0hi[4*512], h0lo[4*512];
    __shared__ unsigned short h1hi[4*512], h1lo[4*512];
    __shared__ float sgi[LMB*512];
    __shared__ float sh1f[16*132];
    __shared__ float sWop[256];
    const int tid = threadIdx.x;
    const int l = tid & 63;
    const int w = tid >> 6;
    const int c = l & 15;
    const int q = l >> 4;
    const int j = w*16 + c;
    const int b0 = blockIdx.x*LMB;

    for (int i=tid;i<4*512;i+=512){ h0hi[i]=0; h0lo[i]=0; h1hi[i]=0; h1lo[i]=0; }
    for (int i=tid;i<LMB*512;i+=512) sgi[i] = gi0[(size_t)b0*512 + i];
    if (tid < 256) sWop[tid] = Wop[tid];

    const v8s* F0 = (const v8s*)B0h;
    const v8s* F1 = (const v8s*)B1h;
    v8s W0[16];
    v8s W1[32];
#pragma unroll
    for (int g=0;g<4;g++)
#pragma unroll
        for (int kb=0;kb<4;kb++) W0[g*4+kb] = F0[((g*8+w)*4 + kb)*64 + l];
#pragma unroll
    for (int g=0;g<4;g++)
#pragma unroll
        for (int kb=0;kb<8;kb++) W1[g*8+kb] = F1[((g*8+w)*8 + kb)*64 + l];

    float b1[4];
#pragma unroll
    for (int g=0;g<4;g++) b1[g] = bih1[g*128+j] + bhh1[g*128+j];
    float c0[4] = {0,0,0,0}, c1[4] = {0,0,0,0};
    const float bo0 = bop[0], bo1 = bop[1];
    const int kbw = j>>5, qw = (j>>3)&3, jw = j&7;
    __syncthreads();

#pragma unroll 1
    for (int t=0;t<OUTL;t++){
        v4f acc[4];
#pragma unroll
        for (int g=0;g<4;g++){
            v4f t4 = { sgi[(q*4+0)*512 + g*128 + j], sgi[(q*4+1)*512 + g*128 + j],
                       sgi[(q*4+2)*512 + g*128 + j], sgi[(q*4+3)*512 + g*128 + j] };
            acc[g] = t4;
        }
#pragma unroll
        for (int kb=0;kb<4;kb++){
            v8s ah = *(const v8s*)&h0hi[kb*512 + l*8];
            v8s al = *(const v8s*)&h0lo[kb*512 + l*8];
#pragma unroll
            for (int g=0;g<4;g++){
                acc[g] = MFMA16(ah, W0[g*4+kb], acc[g]);
                acc[g] = MFMA16(al, W0[g*4+kb], acc[g]);
            }
        }
        float hnew[4];
#pragma unroll
        for (int i=0;i<4;i++){
            c0[i] = fsig(acc[1][i])*c0[i] + fsig(acc[0][i])*ftanh(acc[2][i]);
            hnew[i] = fsig(acc[3][i])*ftanh(c0[i]);
        }
        __syncthreads();
#pragma unroll
        for (int i=0;i<4;i++){
            int off = kbw*512 + (qw*16 + q*4 + i)*8 + jw;
            unsigned short h = f2bf(hnew[i]);
            h0hi[off] = h;
            h0lo[off] = f2bf(hnew[i] - bf2f(h));
        }
        __syncthreads();

        v4f a1[4];
#pragma unroll
        for (int g=0;g<4;g++){ v4f t4={b1[g],b1[g],b1[g],b1[g]}; a1[g]=t4; }
#pragma unroll
        for (int kb=0;kb<8;kb++){
            const unsigned short* hb = (kb<4) ? h0hi : h1hi;
            const unsigned short* lb = (kb<4) ? h0lo : h1lo;
            int kk = kb & 3;
            v8s ah = *(const v8s*)&hb[kk*512 + l*8];
            v8s al = *(const v8s*)&lb[kk*512 + l*8];
#pragma unroll
            for (int g=0;g<4;g++){
                a1[g] = MFMA16(ah, W1[g*8+kb], a1[g]);
                a1[g] = MFMA16(al, W1[g*8+kb], a1[g]);
            }
        }
        float h1new[4];
#pragma unroll
        for (int i=0;i<4;i++){
            c1[i] = fsig(a1[1][i])*c1[i] + fsig(a1[0][i])*ftanh(a1[2][i]);
            h1new[i] = fsig(a1[3][i])*ftanh(c1[i]);
        }
        __syncthreads();
#pragma unroll
        for (int i=0;i<4;i++){
            int off = kbw*512 + (qw*16 + q*4 + i)*8 + jw;
            unsigned short h = f2bf(h1new[i]);
            h1hi[off] = h;
            h1lo[off] = f2bf(h1new[i] - bf2f(h));
            sh1f[(q*4+i)*132 + j] = h1new[i];
        }
        __syncthreads();

        if (tid < 32){
            int m = tid>>1, o = tid&1;
            const float4* hv = (const float4*)&sh1f[m*132];
            const float4* wv = (const float4*)&sWop[o*128];
            float4 s4={0,0,0,0};
#pragma unroll
            for (int k4=0;k4<32;k4++) fma44(s4, wv[k4], hv[k4]);
            outp[(size_t)(b0+m)*(OUTL*2) + t*2 + o] = hsum(s4) + (o ? bo1 : bo0);
        }
    }
}

extern "C" void kernel_launch(void* const* d_in, const int* in_sizes, int n_in,
                              void* d_out, int out_size, void* d_ws, size_t ws_size,
                              hipStream_t stream)
{
    const float* x    = (const float*)d_in[0];
    const int*   ei   = (const int*)d_in[1];
    const float* ea   = (const float*)d_in[2];
    const int*   tgt  = (const int*)d_in[3];
    const float* Wip  = (const float*)d_in[4];
    const float* bip  = (const float*)d_in[5];
    const float* gWih = (const float*)d_in[6];
    const float* gWhh = (const float*)d_in[7];
    const float* gbih = (const float*)d_in[8];
    const float* gbhh = (const float*)d_in[9];
    const float* Wdyn = (const float*)d_in[10];
    const float* bdyn = (const float*)d_in[11];
    const float* c1Wf=(const float*)d_in[12]; const float* c1bf=(const float*)d_in[13];
    const float* c1Ws=(const float*)d_in[14]; const float* c1bs=(const float*)d_in[15];
    const float* c1g =(const float*)d_in[16]; const float* c1b =(const float*)d_in[17];
    const float* c1m =(const float*)d_in[18]; const float* c1v =(const float*)d_in[19];
    const float* c2Wf=(const float*)d_in[20]; const float* c2bf=(const float*)d_in[21];
    const float* c2Ws=(const float*)d_in[22]; const float* c2bs=(const float*)d_in[23];
    const float* c2g =(const float*)d_in[24]; const float* c2b =(const float*)d_in[25];
    const float* c2m =(const float*)d_in[26]; const float* c2v =(const float*)d_in[27];
    const float* Wn  =(const float*)d_in[28]; const float* bn_ =(const float*)d_in[29];
    const float* l0Wih=(const float*)d_in[30]; const float* l0Whh=(const float*)d_in[31];
    const float* l0bih=(const float*)d_in[32]; const float* l0bhh=(const float*)d_in[33];
    const float* l1Wih=(const float*)d_in[34]; const float* l1Whh=(const float*)d_in[35];
    const float* l1bih=(const float*)d_in[36]; const float* l1bhh=(const float*)d_in[37];
    const float* Wop =(const float*)d_in[38]; const float* bop=(const float*)d_in[39];

    float* ws = (float*)d_ws;
    size_t o = 0;
    float* hist = ws + o; o += (size_t)NN*ENC;
    float* f1   = ws + o; o += (size_t)NN*ENC;
    float* f2   = ws + o; o += (size_t)NN*ENC;
    float* Af   = ws + o; o += (size_t)NN*ENC;
    float* Bf   = ws + o; o += (size_t)NN*ENC;
    float* As   = ws + o; o += (size_t)NN*ENC;
    float* Bs   = ws + o; o += (size_t)NN*ENC;
    float* enc  = ws + o; o += (size_t)BB*2*ENC;
    float* gi0  = ws + o; o += (size_t)BB*4*DEC;
    float* W0T  = ws + o; o += (size_t)128*512;
    unsigned short* pWih  = (unsigned short*)(ws + o); o += (size_t)12*64*8/2;
    unsigned short* pWhh  = (unsigned short*)(ws + o); o += (size_t)24*64*8/2;
    unsigned short* pWdyn = (unsigned short*)(ws + o); o += (size_t)8*64*8/2;
    unsigned short* B0h = (unsigned short*)(ws + o); o += (size_t)32*4*64*8/2;
    unsigned short* B1h = (unsigned short*)(ws + o); o += (size_t)32*8*64*8/2;
    int* cnt    = (int*)(ws + o); o += NN;
    int* offv   = (int*)(ws + o); o += NN+1;
    int* curv   = (int*)(ws + o); o += NN;
    int* sorted = (int*)(ws + o); o += EE;

    // --- weight packing ---
    pack_frag<<<(12*64+255)/256, 256, 0, stream>>>(gWih, 32, 1, pWih, 12*64);
    pack_frag<<<(24*64+255)/256, 256, 0, stream>>>(gWhh, 64, 2, pWhh, 24*64);
    pack_frag<<<(8*64+255)/256, 256, 0, stream>>>(Wdyn, 64, 2, pWdyn, 8*64);
    pack_frag_cat<<<(32*4*64+255)/256, 256, 0, stream>>>(l0Whh, l0Whh, 128, 128, 4, B0h, 32*4*64);
    pack_frag_cat<<<(32*8*64+255)/256, 256, 0, stream>>>(l1Wih, l1Whh, 128, 256, 8, B1h, 32*8*64);

    // --- dst counting sort (reused by both convs) ---
    (void)hipMemsetAsync(cnt, 0, (size_t)NN*sizeof(int), stream);
    count_kernel<<<(EE+255)/256, 256, 0, stream>>>(ei, cnt);
    scan_kernel<<<1, 1024, 0, stream>>>(cnt, offv, curv);
    scatter_kernel<<<(EE+255)/256, 256, 0, stream>>>(ei, curv, sorted);

    // --- history encoder (MFMA) ---
    encoder_mfma<<<NN/16, 128, 0, stream>>>(x, Wip, bip, pWih, pWhh, gbih, gbhh, pWdyn, bdyn, hist);

    // --- CGConv 1 ---
    proj_kernel<<<(NN+PROJ_NODES-1)/PROJ_NODES, 256, 0, stream>>>(hist, c1Wf, c1Ws, Af,Bf,As,Bs);
    cg_agg<<<(NN+3)/4, 256, 0, stream>>>(hist, ei, ea, sorted, offv,
                                         c1Wf,c1bf,c1Ws,c1bs, Af,Bf,As,Bs,
                                         c1g,c1b,c1m,c1v, f1);

    // --- CGConv 2 ---
    proj_kernel<<<(NN+PROJ_NODES-1)/PROJ_NODES, 256, 0, stream>>>(f1, c2Wf, c2Ws, Af,Bf,As,Bs);
    cg_agg<<<(NN+3)/4, 256, 0, stream>>>(f1, ei, ea, sorted, offv,
                                         c2Wf,c2bf,c2Ws,c2bs, Af,Bf,As,Bs,
                                         c2g,c2b,c2m,c2v, f2);

    // --- target encoding ---
    target_kernel<<<(BB+3)/4, 256, 0, stream>>>(hist, f2, tgt, Wn, bn_, enc);

    // --- LSTM decoder prep ---
    transpose_w0<<<(512*DEC+255)/256, 256, 0, stream>>>(l0Wih, W0T);
    gi0_kernel<<<BB, 512, 0, stream>>>(enc, W0T, l0bih, l0bhh, gi0);

    // --- LSTM decoder (register-resident MFMA) ---
    lstm_mfma<<<BB/LMB, 512, 0, stream>>>(gi0, B0h, B1h,
                                          l1bih, l1bhh, Wop, bop, (float*)d_out);
}

// Round 8
// 1007.080 us; speedup vs baseline: 12.8637x; 1.0951x over previous
//
#include <hip/hip_runtime.h>
#include <math.h>

#define NN   50000
#define TT   16
#define EE   800000
#define BB   2000
#define EMBD 32
#define ENC  64
#define DEC  128
#define OUTL 25
#define BN_EPS 1e-5f

typedef short v8s __attribute__((ext_vector_type(8)));
typedef float v4f __attribute__((ext_vector_type(4)));
#define MFMA16(a,b,c) __builtin_amdgcn_mfma_f32_16x16x32_bf16((a),(b),(c),0,0,0)

__device__ __forceinline__ float lrelu(float v){ return v >= 0.f ? v : 0.1f*v; }
__device__ __forceinline__ float fsig(float v){ return __builtin_amdgcn_rcpf(1.f + __expf(-v)); }
__device__ __forceinline__ float ftanh(float v){ return 2.f*__builtin_amdgcn_rcpf(1.f + __expf(-2.f*v)) - 1.f; }
__device__ __forceinline__ float fsoftplus(float v){
    return v > 15.f ? v : __logf(1.f + __expf(v));
}
__device__ __forceinline__ void fma44(float4& a, float4 w, float4 h){
    a.x += w.x*h.x; a.y += w.y*h.y; a.z += w.z*h.z; a.w += w.w*h.w;
}
__device__ __forceinline__ float hsum(float4 a){ return (a.x+a.y)+(a.z+a.w); }

__device__ __forceinline__ unsigned short f2bf(float f){
    unsigned u = __float_as_uint(f);
    u = u + 0x7FFFu + ((u>>16)&1u);
    return (unsigned short)(u>>16);
}
__device__ __forceinline__ float bf2f(unsigned short s){ return __uint_as_float(((unsigned)s)<<16); }

__device__ __forceinline__ v8s as_v8s(int4 v){
    union { int4 i; v8s s; } u; u.i = v; return u.s;
}

__device__ __forceinline__ void cvt8(const float* p, v8s& hi, v8s& lo){
    float4 a0 = *(const float4*)p;
    float4 a1 = *(const float4*)(p+4);
    float av[8] = {a0.x,a0.y,a0.z,a0.w,a1.x,a1.y,a1.z,a1.w};
#pragma unroll
    for (int j=0;j<8;j++){
        unsigned short h = f2bf(av[j]);
        hi[j] = (short)h;
        lo[j] = (short)f2bf(av[j] - bf2f(h));
    }
}
__device__ __forceinline__ void cvt8_lrelu(const float* p, v8s& hi, v8s& lo){
    float4 a0 = *(const float4*)p;
    float4 a1 = *(const float4*)(p+4);
    float av[8] = {a0.x,a0.y,a0.z,a0.w,a1.x,a1.y,a1.z,a1.w};
#pragma unroll
    for (int j=0;j<8;j++){
        float a = lrelu(av[j]);
        unsigned short h = f2bf(a);
        hi[j] = (short)h;
        lo[j] = (short)f2bf(a - bf2f(h));
    }
}

// ---------------- pack W[N][K] rows into bf16 B-fragment order (hi only) ----------------
__global__ void pack_frag(const float* __restrict__ W, int K, int KB,
                          unsigned short* __restrict__ out, int total){
    int i = blockIdx.x*256 + threadIdx.x;
    if (i >= total) return;
    int l = i & 63, fb = i >> 6;
    int kb = fb % KB, nt = fb / KB;
    int n = nt*16 + (l&15);
    int k0 = kb*32 + ((l>>4)*8);
#pragma unroll
    for (int j=0;j<8;j++) out[i*8+j] = f2bf(W[(size_t)n*K + k0 + j]);
}

// ---------------- pack (Wa | Wb) rows into bf16 B-fragment order (hi only) ----------------
__global__ void pack_frag_cat(const float* __restrict__ Wa, const float* __restrict__ Wb,
                              int K1, int K, int KB,
                              unsigned short* __restrict__ hi, int total){
    int i = blockIdx.x*256 + threadIdx.x;
    if (i >= total) return;
    int l = i & 63, fb = i >> 6;
    int kb = fb % KB, nt = fb / KB;
    int n = nt*16 + (l&15);
    int k0 = kb*32 + ((l>>4)*8);
#pragma unroll
    for (int j=0;j<8;j++){
        int k = k0 + j;
        float v = (k < K1) ? Wa[(size_t)n*K1 + k] : Wb[(size_t)n*(K-K1) + (k-K1)];
        hi[i*8+j] = f2bf(v);
    }
}

// ---------------- pack CGConv proj weights: B[256][64] hi+lo B-frags, NT=16 KB=2 ----
// row n: d=n>>6 (0:Af=Wf[:, :64] 1:Bf=Wf[:,64:128] 2:As 3:Bs), c=n&63
__global__ void pack_proj(const float* __restrict__ Wf, const float* __restrict__ Ws,
                          unsigned short* __restrict__ hi, unsigned short* __restrict__ lo){
    int i = blockIdx.x*256 + threadIdx.x;   // 16*2*64 = 2048
    if (i >= 2048) return;
    int l = i & 63, fb = i >> 6;
    int kb = fb & 1, nt = fb >> 1;
    int n = nt*16 + (l&15);
    int d = n >> 6, c = n & 63;
    const float* W = (d < 2) ? Wf : Ws;
    int k0 = (d&1)*64 + kb*32 + ((l>>4)*8);
#pragma unroll
    for (int j=0;j<8;j++){
        float v = W[c*130 + k0 + j];
        unsigned short h = f2bf(v);
        hi[i*8+j] = h;
        lo[i*8+j] = f2bf(v - bf2f(h));
    }
}

// ---------------- GRU encoder v3: MFMA (unchanged) ----------------
#define ESTR 68
__global__ __launch_bounds__(128) void encoder_mfma(
    const float* __restrict__ x,
    const float* __restrict__ Wip, const float* __restrict__ bip,
    const unsigned short* __restrict__ pWih,
    const unsigned short* __restrict__ pWhh,
    const float* __restrict__ bih, const float* __restrict__ bhh,
    const unsigned short* __restrict__ pWdyn,
    const float* __restrict__ bdyn,
    float* __restrict__ hist)
{
    __shared__ float sxl[512];
    __shared__ float femb[16*36];
    __shared__ float sh[16*ESTR];
    const int tid = threadIdx.x;
    const int l   = tid & 63;
    const int w   = tid >> 6;
    const int ln  = l & 15, q = l >> 4;
    const int blk = blockIdx.x;

    ((float4*)sxl)[tid] = ((const float4*)x)[(size_t)blk*128 + tid];
    for (int i=tid;i<16*ESTR;i+=128) sh[i]=0.f;

    const int ek = tid & 31;
    const float w0 = Wip[2*ek], w1 = Wip[2*ek+1], bk = bip[ek];
    const int em0 = tid >> 5;

    float bR[2], bZ[2], bNI[2], bNH[2];
#pragma unroll
    for (int u=0;u<2;u++){
        int g = 2*w + u;
        int c = g*16 + ln;
        bR[u]  = bih[c]       + bhh[c];
        bZ[u]  = bih[64 + c]  + bhh[64 + c];
        bNI[u] = bih[128 + c];
        bNH[u] = bhh[128 + c];
    }
    const v8s* FIH = (const v8s*)pWih;
    const v8s* FHH = (const v8s*)pWhh;
    const v8s* FDY = (const v8s*)pWdyn;
    __syncthreads();

#pragma unroll 1
    for (int t=0;t<TT;t++){
#pragma unroll
        for (int r=0;r<4;r++){
            int m = em0 + r*4;
            float e = w0*sxl[m*32 + 2*t] + w1*sxl[m*32 + 2*t + 1] + bk;
            femb[m*36 + ek] = lrelu(e);
        }
        __syncthreads();
        v8s eh, el; cvt8(&femb[ln*36 + q*8], eh, el);
        v8s h0h, h0l, h1h, h1l;
        cvt8(&sh[ln*ESTR +      q*8], h0h, h0l);
        cvt8(&sh[ln*ESTR + 32 + q*8], h1h, h1l);
        __syncthreads();
#pragma unroll
        for (int u=0;u<2;u++){
            int g = 2*w + u;
            v4f aR = {bR[u],bR[u],bR[u],bR[u]};
            v4f aZ = {bZ[u],bZ[u],bZ[u],bZ[u]};
            v4f aNI= {bNI[u],bNI[u],bNI[u],bNI[u]};
            v4f aNH= {bNH[u],bNH[u],bNH[u],bNH[u]};
            v8s b;
            b = FIH[(g   )*64 + l];   aR = MFMA16(eh,b,aR);  aR = MFMA16(el,b,aR);
            b = FHH[((g)*2+0)*64+l];  aR = MFMA16(h0h,b,aR); aR = MFMA16(h0l,b,aR);
            b = FHH[((g)*2+1)*64+l];  aR = MFMA16(h1h,b,aR); aR = MFMA16(h1l,b,aR);
            b = FIH[(4+g )*64 + l];   aZ = MFMA16(eh,b,aZ);  aZ = MFMA16(el,b,aZ);
            b = FHH[((4+g)*2+0)*64+l];aZ = MFMA16(h0h,b,aZ); aZ = MFMA16(h0l,b,aZ);
            b = FHH[((4+g)*2+1)*64+l];aZ = MFMA16(h1h,b,aZ); aZ = MFMA16(h1l,b,aZ);
            b = FIH[(8+g )*64 + l];   aNI= MFMA16(eh,b,aNI); aNI= MFMA16(el,b,aNI);
            b = FHH[((8+g)*2+0)*64+l];aNH= MFMA16(h0h,b,aNH);aNH= MFMA16(h0l,b,aNH);
            b = FHH[((8+g)*2+1)*64+l];aNH= MFMA16(h1h,b,aNH);aNH= MFMA16(h1l,b,aNH);
#pragma unroll
            for (int i=0;i<4;i++){
                float r_ = fsig(aR[i]);
                float z_ = fsig(aZ[i]);
                float nn_ = ftanh(aNI[i] + r_*aNH[i]);
                int row = q*4 + i, col = g*16 + ln;
                float old = sh[row*ESTR + col];
                sh[row*ESTR + col] = (1.f - z_)*nn_ + z_*old;
            }
        }
    }
    __syncthreads();
    {
        v8s a0h,a0l,a1h,a1l;
        cvt8_lrelu(&sh[ln*ESTR +      q*8], a0h, a0l);
        cvt8_lrelu(&sh[ln*ESTR + 32 + q*8], a1h, a1l);
#pragma unroll
        for (int u=0;u<2;u++){
            int nt = 2*w + u;
            float bb = bdyn[nt*16 + ln];
            v4f acc = {bb,bb,bb,bb};
            v8s b;
            b = FDY[(nt*2+0)*64 + l]; acc = MFMA16(a0h,b,acc); acc = MFMA16(a0l,b,acc);
            b = FDY[(nt*2+1)*64 + l]; acc = MFMA16(a1h,b,acc); acc = MFMA16(a1l,b,acc);
#pragma unroll
            for (int i=0;i<4;i++){
                hist[(size_t)(blk*16 + q*4 + i)*64 + nt*16 + ln] = lrelu(acc[i]);
            }
        }
    }
}

// ---------------- CGConv projections v2: MFMA ----------------
// R7 post-mortem: fp32 proj re-staged 32KB weights/LDS per 32-node block.
// v2: 64 nodes/block, wave = one 16-node M-tile, 16 N-tiles (Af|Bf|As|Bs),
// 3-term split-bf16 MFMA (~fp32 accuracy), weights streamed from L2.
__global__ __launch_bounds__(256) void proj_mfma(
    const float* __restrict__ xin,
    const unsigned short* __restrict__ Bh, const unsigned short* __restrict__ Bl,
    float* __restrict__ Af, float* __restrict__ Bf,
    float* __restrict__ As, float* __restrict__ Bs)
{
    __shared__ float sx[64*68];
    const int tid = threadIdx.x;
    const int l = tid & 63;
    const int w = tid >> 6;
    const int ln = l & 15, q = l >> 4;
    const int n0 = blockIdx.x*64;

    for (int i=tid;i<64*16;i+=256){
        int nn = i>>4, f4 = i&15;
        float4 v = {0.f,0.f,0.f,0.f};
        if (n0+nn < NN) v = ((const float4*)(xin + (size_t)(n0+nn)*64))[f4];
        *(float4*)&sx[nn*68 + f4*4] = v;
    }
    __syncthreads();

    v8s ah0,al0,ah1,al1;
    cvt8(&sx[(w*16+ln)*68 +      q*8], ah0, al0);
    cvt8(&sx[(w*16+ln)*68 + 32 + q*8], ah1, al1);

    const v8s* FH = (const v8s*)Bh;
    const v8s* FL = (const v8s*)Bl;
#pragma unroll 1
    for (int nt=0; nt<16; nt++){
        v8s bh0 = FH[(nt*2+0)*64 + l], bl0 = FL[(nt*2+0)*64 + l];
        v8s bh1 = FH[(nt*2+1)*64 + l], bl1 = FL[(nt*2+1)*64 + l];
        v4f acc = {0.f,0.f,0.f,0.f};
        acc = MFMA16(ah0,bh0,acc); acc = MFMA16(al0,bh0,acc); acc = MFMA16(ah0,bl0,acc);
        acc = MFMA16(ah1,bh1,acc); acc = MFMA16(al1,bh1,acc); acc = MFMA16(ah1,bl1,acc);
        int d = nt >> 2, col = (nt&3)*16 + ln;
        float* op = (d==0) ? Af : (d==1) ? Bf : (d==2) ? As : Bs;
#pragma unroll
        for (int i=0;i<4;i++){
            int node = n0 + w*16 + q*4 + i;
            if (node < NN) op[(size_t)node*64 + col] = acc[i];
        }
    }
}

// ---------------- dst counting sort (unchanged) ----------------
__global__ void count_kernel(const int* __restrict__ ei, int* __restrict__ cnt){
    int e = blockIdx.x*256 + threadIdx.x;
    if (e < EE) atomicAdd(&cnt[ei[EE+e]], 1);
}

__global__ __launch_bounds__(1024) void scan_kernel(const int* __restrict__ cnt,
                                                    int* __restrict__ off, int* __restrict__ cur){
    __shared__ int ssum[1024];
    const int t = threadIdx.x;
    const int CH = (NN + 1023)/1024;
    const int base = t*CH;
    int s = 0;
    for (int i=0;i<CH;i++){ int idx=base+i; if (idx<NN) s += cnt[idx]; }
    ssum[t] = s;
    __syncthreads();
    for (int d=1; d<1024; d<<=1){
        int v = (t>=d) ? ssum[t-d] : 0;
        __syncthreads();
        ssum[t] += v;
        __syncthreads();
    }
    int ex = (t==0) ? 0 : ssum[t-1];
    for (int i=0;i<CH;i++){
        int idx=base+i;
        if (idx<NN){ off[idx]=ex; cur[idx]=ex; ex += cnt[idx]; }
    }
    if (t==1023) off[NN] = ssum[1023];
}

__global__ void scatter_kernel(const int* __restrict__ ei, int* __restrict__ cur,
                               int* __restrict__ sorted){
    int e = blockIdx.x*256 + threadIdx.x;
    if (e >= EE) return;
    int d = ei[EE+e];
    int p = atomicAdd(&cur[d], 1);
    sorted[p] = e;
}

// ---------------- CGConv aggregate (unchanged) ----------------
__global__ __launch_bounds__(256) void cg_agg(
    const float* __restrict__ xin,
    const int* __restrict__ ei, const float* __restrict__ ea,
    const int* __restrict__ sorted, const int* __restrict__ off,
    const float* __restrict__ Wf, const float* __restrict__ bf,
    const float* __restrict__ Ws, const float* __restrict__ bs,
    const float* __restrict__ Af, const float* __restrict__ Bf,
    const float* __restrict__ As, const float* __restrict__ Bs,
    const float* __restrict__ gamma, const float* __restrict__ beta,
    const float* __restrict__ mean, const float* __restrict__ var,
    float* __restrict__ outp)
{
    const int tid = threadIdx.x;
    const int c = tid & 63, wid = tid >> 6;
    const int n = blockIdx.x*4 + wid;
    if (n >= NN) return;

    const float wf0 = Wf[c*130+128], wf1 = Wf[c*130+129], bfc = bf[c];
    const float ws0 = Ws[c*130+128], ws1 = Ws[c*130+129], bsc = bs[c];
    const float afd = Af[(size_t)n*64+c], asd = As[(size_t)n*64+c];

    float acc = 0.f;
    const int i1 = off[n+1];
#pragma unroll 1
    for (int i=off[n]; i<i1; ++i){
        int eid = sorted[i];
        int src = ei[eid];
        float e0 = ea[2*(size_t)eid], e1 = ea[2*(size_t)eid+1];
        float gf = afd + Bf[(size_t)src*64+c] + wf0*e0 + wf1*e1 + bfc;
        float gs = asd + Bs[(size_t)src*64+c] + ws0*e0 + ws1*e1 + bsc;
        acc += fsig(gf) * fsoftplus(gs);
    }
    float bn = (acc - mean[c])*rsqrtf(var[c]+BN_EPS)*gamma[c] + beta[c];
    outp[(size_t)n*64+c] = xin[(size_t)n*64+c] + bn;
}

// ---------------- target gather + nbrs linear + concat (unchanged) ----------------
__global__ __launch_bounds__(256) void target_kernel(
    const float* __restrict__ hist, const float* __restrict__ f2,
    const int* __restrict__ tgt,
    const float* __restrict__ Wn, const float* __restrict__ bn_,
    float* __restrict__ enc)
{
    const int tid=threadIdx.x;
    const int c = tid&63, q = tid>>6;
    const int b = blockIdx.x*4 + q;
    if (b>=BB) return;
    const int n = tgt[b];
    float a = bn_[c];
#pragma unroll
    for (int k=0;k<ENC;k++) a += Wn[c*64+k]*f2[(size_t)n*64+k];
    enc[(size_t)b*128 + 64 + c] = lrelu(a);
    enc[(size_t)b*128 + c]      = hist[(size_t)n*64+c];
}

// ---------------- transpose lstm0_Wih [512][128] -> [128][512] ----------------
__global__ void transpose_w0(const float* __restrict__ W, float* __restrict__ WT){
    int i = blockIdx.x*256+threadIdx.x;
    if (i >= 512*DEC) return;
    int g = i>>7, k = i&127;
    WT[k*512+g] = W[i];
}

// ---------------- gi0 = enc @ Wih0^T + bih0 + bhh0 (unchanged) ----------------
__global__ __launch_bounds__(512) void gi0_kernel(
    const float* __restrict__ enc, const float* __restrict__ W0T,
    const float* __restrict__ bih0, const float* __restrict__ bhh0,
    float* __restrict__ gi0)
{
    __shared__ float se[128];
    const int b = blockIdx.x, g = threadIdx.x;
    if (g < 128) se[g] = enc[(size_t)b*128+g];
    __syncthreads();
    float a = bih0[g]+bhh0[g];
#pragma unroll 4
    for (int k=0;k<128;k++) a += W0T[k*512+g]*se[k];
    gi0[(size_t)b*512+g] = a;
}

// ---------------- 2-layer LSTM decoder v4 ----------------
// R7 post-mortem: VGPR=128 proved the compiler REMATERIALIZED the weight loads
// inside the t-loop (per-step L2 reloads, 6.9us/step) and 125 blocks left half
// the CUs idle. v4: (1) asm-pin weights into 192 VGPRs (can't rematerialize);
// (2) LMB=8 -> 250 blocks (M rows 8-15 zero-pad, garbage confined to unused C
// rows); (3) double-buffered h -> 2 barriers/step; (4) gi0 pre-transposed in
// LDS -> 4 aligned ds_read_b128 for acc init.
#define LMB 8
__global__ __launch_bounds__(512, 2) void lstm_mfma(
    const float* __restrict__ gi0,
    const unsigned short* __restrict__ B0h,
    const unsigned short* __restrict__ B1h,
    const float* __restrict__ bih1, const float* __restrict__ bhh1,
    const float* __restrict__ Wop, const float* __restrict__ bop,
    float* __restrict__ outp)
{
    __shared__ unsigned short h0hi[2][4*512], h0lo[2][4*512];
    __shared__ unsigned short h1hi[2][4*512], h1lo[2][4*512];
    __shared__ float sgiT[128*36];    // [j]*36 + g*8 + m  (m<8)
    __shared__ float sh1f[8*132];
    __shared__ float sWop[256];
    const int tid = threadIdx.x;
    const int l = tid & 63;
    const int w = tid >> 6;
    const int c = l & 15;
    const int q = l >> 4;
    const int j = w*16 + c;
    const int b0 = blockIdx.x*LMB;

    for (int i=tid;i<4*512;i+=512){
        h0hi[0][i]=0; h0lo[0][i]=0; h1hi[0][i]=0; h1lo[0][i]=0;
        h0hi[1][i]=0; h0lo[1][i]=0; h1hi[1][i]=0; h1lo[1][i]=0;
    }
    // stage gi0 transposed (coalesced read, spread write)
    for (int i=tid;i<8*512;i+=512){
        int m = i>>9, gj = i&511;
        int g = gj>>7, jj = gj&127;
        sgiT[jj*36 + g*8 + m] = gi0[(size_t)(b0+m)*512 + gj];
    }
    if (tid < 256) sWop[tid] = Wop[tid];

    // ---- load + PIN weight fragments in registers ----
    int4 W0r[16], W1r[32];
    {
        const int4* F0 = (const int4*)B0h;
        const int4* F1 = (const int4*)B1h;
#pragma unroll
        for (int g=0;g<4;g++)
#pragma unroll
            for (int kb=0;kb<4;kb++) W0r[g*4+kb] = F0[((g*8+w)*4 + kb)*64 + l];
#pragma unroll
        for (int g=0;g<4;g++)
#pragma unroll
            for (int kb=0;kb<8;kb++) W1r[g*8+kb] = F1[((g*8+w)*8 + kb)*64 + l];
#pragma unroll
        for (int i=0;i<16;i++)
            asm volatile("" : "+v"(W0r[i].x), "+v"(W0r[i].y), "+v"(W0r[i].z), "+v"(W0r[i].w));
#pragma unroll
        for (int i=0;i<32;i++)
            asm volatile("" : "+v"(W1r[i].x), "+v"(W1r[i].y), "+v"(W1r[i].z), "+v"(W1r[i].w));
    }

    float b1[4];
#pragma unroll
    for (int g=0;g<4;g++) b1[g] = bih1[g*128+j] + bhh1[g*128+j];
    float c0[4] = {0,0,0,0}, c1[4] = {0,0,0,0};
    const float bo0 = bop[0], bo1 = bop[1];
    const int kbw = j>>5, qw = (j>>3)&3, jw = j&7;
    __syncthreads();

    int p = 0;
#pragma unroll 1
    for (int t=0;t<OUTL;t++){
        // ---- layer 0: read h0[p], write h0[1-p] ----
        v4f acc[4];
#pragma unroll
        for (int g=0;g<4;g++){
            if (q < 2) acc[g] = *(const v4f*)&sgiT[j*36 + g*8 + q*4];
            else { v4f z = {0.f,0.f,0.f,0.f}; acc[g] = z; }
        }
#pragma unroll
        for (int kb=0;kb<4;kb++){
            v8s ah = *(const v8s*)&h0hi[p][kb*512 + l*8];
            v8s al = *(const v8s*)&h0lo[p][kb*512 + l*8];
#pragma unroll
            for (int g=0;g<4;g++){
                acc[g] = MFMA16(ah, as_v8s(W0r[g*4+kb]), acc[g]);
                acc[g] = MFMA16(al, as_v8s(W0r[g*4+kb]), acc[g]);
            }
        }
        float hnew[4];
#pragma unroll
        for (int i=0;i<4;i++){
            c0[i] = fsig(acc[1][i])*c0[i] + fsig(acc[0][i])*ftanh(acc[2][i]);
            hnew[i] = fsig(acc[3][i])*ftanh(c0[i]);
        }
#pragma unroll
        for (int i=0;i<4;i++){
            int off = kbw*512 + (qw*16 + q*4 + i)*8 + jw;
            unsigned short h = f2bf(hnew[i]);
            h0hi[1-p][off] = h;
            h0lo[1-p][off] = f2bf(hnew[i] - bf2f(h));
        }
        __syncthreads();   // B1: h0[1-p] visible

        // ---- layer 1: read h0[1-p] + h1[p], write h1[1-p] ----
        v4f a1[4];
#pragma unroll
        for (int g=0;g<4;g++){ v4f t4={b1[g],b1[g],b1[g],b1[g]}; a1[g]=t4; }
#pragma unroll
        for (int kb=0;kb<8;kb++){
            const unsigned short* hb = (kb<4) ? h0hi[1-p] : h1hi[p];
            const unsigned short* lb = (kb<4) ? h0lo[1-p] : h1lo[p];
            int kk = kb & 3;
            v8s ah = *(const v8s*)&hb[kk*512 + l*8];
            v8s al = *(const v8s*)&lb[kk*512 + l*8];
#pragma unroll
            for (int g=0;g<4;g++){
                a1[g] = MFMA16(ah, as_v8s(W1r[g*8+kb]), a1[g]);
                a1[g] = MFMA16(al, as_v8s(W1r[g*8+kb]), a1[g]);
            }
        }
        float h1new[4];
#pragma unroll
        for (int i=0;i<4;i++){
            c1[i] = fsig(a1[1][i])*c1[i] + fsig(a1[0][i])*ftanh(a1[2][i]);
            h1new[i] = fsig(a1[3][i])*ftanh(c1[i]);
        }
#pragma unroll
        for (int i=0;i<4;i++){
            int off = kbw*512 + (qw*16 + q*4 + i)*8 + jw;
            unsigned short h = f2bf(h1new[i]);
            h1hi[1-p][off] = h;
            h1lo[1-p][off] = f2bf(h1new[i] - bf2f(h));
            if (q < 2) sh1f[(q*4+i)*132 + j] = h1new[i];
        }
        __syncthreads();   // B2: h1[1-p] + sh1f visible

        // ---- output projection (8 samples x 2 outputs) ----
        if (tid < 16){
            int m = tid>>1, o = tid&1;
            const float4* hv = (const float4*)&sh1f[m*132];
            const float4* wv = (const float4*)&sWop[o*128];
            float4 s4={0,0,0,0};
#pragma unroll
            for (int k4=0;k4<32;k4++) fma44(s4, wv[k4], hv[k4]);
            outp[(size_t)(b0+m)*(OUTL*2) + t*2 + o] = hsum(s4) + (o ? bo1 : bo0);
        }
        // out-proj wave finishes its sh1f reads before it reaches next B1;
        // other waves' first sh1f write of step t+1 is after next B1 -> safe.
        p ^= 1;
    }
}

extern "C" void kernel_launch(void* const* d_in, const int* in_sizes, int n_in,
                              void* d_out, int out_size, void* d_ws, size_t ws_size,
                              hipStream_t stream)
{
    const float* x    = (const float*)d_in[0];
    const int*   ei   = (const int*)d_in[1];
    const float* ea   = (const float*)d_in[2];
    const int*   tgt  = (const int*)d_in[3];
    const float* Wip  = (const float*)d_in[4];
    const float* bip  = (const float*)d_in[5];
    const float* gWih = (const float*)d_in[6];
    const float* gWhh = (const float*)d_in[7];
    const float* gbih = (const float*)d_in[8];
    const float* gbhh = (const float*)d_in[9];
    const float* Wdyn = (const float*)d_in[10];
    const float* bdyn = (const float*)d_in[11];
    const float* c1Wf=(const float*)d_in[12]; const float* c1bf=(const float*)d_in[13];
    const float* c1Ws=(const float*)d_in[14]; const float* c1bs=(const float*)d_in[15];
    const float* c1g =(const float*)d_in[16]; const float* c1b =(const float*)d_in[17];
    const float* c1m =(const float*)d_in[18]; const float* c1v =(const float*)d_in[19];
    const float* c2Wf=(const float*)d_in[20]; const float* c2bf=(const float*)d_in[21];
    const float* c2Ws=(const float*)d_in[22]; const float* c2bs=(const float*)d_in[23];
    const float* c2g =(const float*)d_in[24]; const float* c2b =(const float*)d_in[25];
    const float* c2m =(const float*)d_in[26]; const float* c2v =(const float*)d_in[27];
    const float* Wn  =(const float*)d_in[28]; const float* bn_ =(const float*)d_in[29];
    const float* l0Wih=(const float*)d_in[30]; const float* l0Whh=(const float*)d_in[31];
    const float* l0bih=(const float*)d_in[32]; const float* l0bhh=(const float*)d_in[33];
    const float* l1Wih=(const float*)d_in[34]; const float* l1Whh=(const float*)d_in[35];
    const float* l1bih=(const float*)d_in[36]; const float* l1bhh=(const float*)d_in[37];
    const float* Wop =(const float*)d_in[38]; const float* bop=(const float*)d_in[39];

    float* ws = (float*)d_ws;
    size_t o = 0;
    float* hist = ws + o; o += (size_t)NN*ENC;
    float* f1   = ws + o; o += (size_t)NN*ENC;
    float* f2   = ws + o; o += (size_t)NN*ENC;
    float* Af   = ws + o; o += (size_t)NN*ENC;
    float* Bf   = ws + o; o += (size_t)NN*ENC;
    float* As   = ws + o; o += (size_t)NN*ENC;
    float* Bs   = ws + o; o += (size_t)NN*ENC;
    float* enc  = ws + o; o += (size_t)BB*2*ENC;
    float* gi0  = ws + o; o += (size_t)BB*4*DEC;
    float* W0T  = ws + o; o += (size_t)128*512;
    unsigned short* pWih  = (unsigned short*)(ws + o); o += (size_t)12*64*8/2;
    unsigned short* pWhh  = (unsigned short*)(ws + o); o += (size_t)24*64*8/2;
    unsigned short* pWdyn = (unsigned short*)(ws + o); o += (size_t)8*64*8/2;
    unsigned short* B0h = (unsigned short*)(ws + o); o += (size_t)32*4*64*8/2;
    unsigned short* B1h = (unsigned short*)(ws + o); o += (size_t)32*8*64*8/2;
    unsigned short* P1h = (unsigned short*)(ws + o); o += (size_t)2048*8/2;
    unsigned short* P1l = (unsigned short*)(ws + o); o += (size_t)2048*8/2;
    unsigned short* P2h = (unsigned short*)(ws + o); o += (size_t)2048*8/2;
    unsigned short* P2l = (unsigned short*)(ws + o); o += (size_t)2048*8/2;
    int* cnt    = (int*)(ws + o); o += NN;
    int* offv   = (int*)(ws + o); o += NN+1;
    int* curv   = (int*)(ws + o); o += NN;
    int* sorted = (int*)(ws + o); o += EE;

    // --- weight packing ---
    pack_frag<<<(12*64+255)/256, 256, 0, stream>>>(gWih, 32, 1, pWih, 12*64);
    pack_frag<<<(24*64+255)/256, 256, 0, stream>>>(gWhh, 64, 2, pWhh, 24*64);
    pack_frag<<<(8*64+255)/256, 256, 0, stream>>>(Wdyn, 64, 2, pWdyn, 8*64);
    pack_frag_cat<<<(32*4*64+255)/256, 256, 0, stream>>>(l0Whh, l0Whh, 128, 128, 4, B0h, 32*4*64);
    pack_frag_cat<<<(32*8*64+255)/256, 256, 0, stream>>>(l1Wih, l1Whh, 128, 256, 8, B1h, 32*8*64);
    pack_proj<<<8, 256, 0, stream>>>(c1Wf, c1Ws, P1h, P1l);
    pack_proj<<<8, 256, 0, stream>>>(c2Wf, c2Ws, P2h, P2l);

    // --- dst counting sort (reused by both convs) ---
    (void)hipMemsetAsync(cnt, 0, (size_t)NN*sizeof(int), stream);
    count_kernel<<<(EE+255)/256, 256, 0, stream>>>(ei, cnt);
    scan_kernel<<<1, 1024, 0, stream>>>(cnt, offv, curv);
    scatter_kernel<<<(EE+255)/256, 256, 0, stream>>>(ei, curv, sorted);

    // --- history encoder (MFMA) ---
    encoder_mfma<<<NN/16, 128, 0, stream>>>(x, Wip, bip, pWih, pWhh, gbih, gbhh, pWdyn, bdyn, hist);

    // --- CGConv 1 ---
    proj_mfma<<<(NN+63)/64, 256, 0, stream>>>(hist, P1h, P1l, Af,Bf,As,Bs);
    cg_agg<<<(NN+3)/4, 256, 0, stream>>>(hist, ei, ea, sorted, offv,
                                         c1Wf,c1bf,c1Ws,c1bs, Af,Bf,As,Bs,
                                         c1g,c1b,c1m,c1v, f1);

    // --- CGConv 2 ---
    proj_mfma<<<(NN+63)/64, 256, 0, stream>>>(f1, P2h, P2l, Af,Bf,As,Bs);
    cg_agg<<<(NN+3)/4, 256, 0, stream>>>(f1, ei, ea, sorted, offv,
                                         c2Wf,c2bf,c2Ws,c2bs, Af,Bf,As,Bs,
                                         c2g,c2b,c2m,c2v, f2);

    // --- target encoding ---
    target_kernel<<<(BB+3)/4, 256, 0, stream>>>(hist, f2, tgt, Wn, bn_, enc);

    // --- LSTM decoder prep ---
    transpose_w0<<<(512*DEC+255)/256, 256, 0, stream>>>(l0Wih, W0T);
    gi0_kernel<<<BB, 512, 0, stream>>>(enc, W0T, l0bih, l0bhh, gi0);

    // --- LSTM decoder (pinned-register MFMA) ---
    lstm_mfma<<<BB/LMB, 512, 0, stream>>>(gi0, B0h, B1h,
                                          l1bih, l1bhh, Wop, bop, (float*)d_out);
}

// Round 9
// 846.552 us; speedup vs baseline: 15.3029x; 1.1896x over previous
//
#include <hip/hip_runtime.h>
#include <math.h>

#define NN   50000
#define TT   16
#define EE   800000
#define BB   2000
#define EMBD 32
#define ENC  64
#define DEC  128
#define OUTL 25
#define BN_EPS 1e-5f

typedef short v8s __attribute__((ext_vector_type(8)));
typedef float v4f __attribute__((ext_vector_type(4)));
#define MFMA16(a,b,c) __builtin_amdgcn_mfma_f32_16x16x32_bf16((a),(b),(c),0,0,0)

__device__ __forceinline__ float lrelu(float v){ return v >= 0.f ? v : 0.1f*v; }
__device__ __forceinline__ float fsig(float v){ return __builtin_amdgcn_rcpf(1.f + __expf(-v)); }
__device__ __forceinline__ float ftanh(float v){ return 2.f*__builtin_amdgcn_rcpf(1.f + __expf(-2.f*v)) - 1.f; }
__device__ __forceinline__ float fsoftplus(float v){
    return v > 15.f ? v : __logf(1.f + __expf(v));
}
__device__ __forceinline__ void fma44(float4& a, float4 w, float4 h){
    a.x += w.x*h.x; a.y += w.y*h.y; a.z += w.z*h.z; a.w += w.w*h.w;
}
__device__ __forceinline__ float hsum(float4 a){ return (a.x+a.y)+(a.z+a.w); }

__device__ __forceinline__ unsigned short f2bf(float f){
    unsigned u = __float_as_uint(f);
    u = u + 0x7FFFu + ((u>>16)&1u);
    return (unsigned short)(u>>16);
}
__device__ __forceinline__ float bf2f(unsigned short s){ return __uint_as_float(((unsigned)s)<<16); }

__device__ __forceinline__ v8s as_v8s(int4 v){
    union { int4 i; v8s s; } u; u.i = v; return u.s;
}

__device__ __forceinline__ void cvt8(const float* p, v8s& hi, v8s& lo){
    float4 a0 = *(const float4*)p;
    float4 a1 = *(const float4*)(p+4);
    float av[8] = {a0.x,a0.y,a0.z,a0.w,a1.x,a1.y,a1.z,a1.w};
#pragma unroll
    for (int j=0;j<8;j++){
        unsigned short h = f2bf(av[j]);
        hi[j] = (short)h;
        lo[j] = (short)f2bf(av[j] - bf2f(h));
    }
}
__device__ __forceinline__ void cvt8_lrelu(const float* p, v8s& hi, v8s& lo){
    float4 a0 = *(const float4*)p;
    float4 a1 = *(const float4*)(p+4);
    float av[8] = {a0.x,a0.y,a0.z,a0.w,a1.x,a1.y,a1.z,a1.w};
#pragma unroll
    for (int j=0;j<8;j++){
        float a = lrelu(av[j]);
        unsigned short h = f2bf(a);
        hi[j] = (short)h;
        lo[j] = (short)f2bf(a - bf2f(h));
    }
}

// ---------------- fused packing helpers ----------------
__device__ __forceinline__ void pf_item(const float* W, int K, int KB, int i,
                                        unsigned short* out){
    int l = i & 63, fb = i >> 6;
    int kb = fb % KB, nt = fb / KB;
    int n = nt*16 + (l&15);
    int k0 = kb*32 + ((l>>4)*8);
#pragma unroll
    for (int j=0;j<8;j++) out[i*8+j] = f2bf(W[(size_t)n*K + k0 + j]);
}
__device__ __forceinline__ void pcat_item(const float* Wa, const float* Wb,
                                          int K1, int K, int KB, int i,
                                          unsigned short* out){
    int l = i & 63, fb = i >> 6;
    int kb = fb % KB, nt = fb / KB;
    int n = nt*16 + (l&15);
    int k0 = kb*32 + ((l>>4)*8);
#pragma unroll
    for (int j=0;j<8;j++){
        int k = k0 + j;
        float v = (k < K1) ? Wa[(size_t)n*K1 + k] : Wb[(size_t)n*(K-K1) + (k-K1)];
        out[i*8+j] = f2bf(v);
    }
}
__device__ __forceinline__ void pproj_item(const float* Wf, const float* Ws, int i,
                                           unsigned short* hi, unsigned short* lo){
    int l = i & 63, fb = i >> 6;
    int kb = fb & 1, nt = fb >> 1;
    int n = nt*16 + (l&15);
    int d = n >> 6, c = n & 63;
    const float* W = (d < 2) ? Wf : Ws;
    int k0 = (d&1)*64 + kb*32 + ((l>>4)*8);
#pragma unroll
    for (int j=0;j<8;j++){
        float v = W[c*130 + k0 + j];
        unsigned short h = f2bf(v);
        hi[i*8+j] = h;
        lo[i*8+j] = f2bf(v - bf2f(h));
    }
}

// ---------------- all weight prep in ONE dispatch (was 8) ----------------
__global__ void pack_all(
    const float* __restrict__ gWih, const float* __restrict__ gWhh,
    const float* __restrict__ Wdyn,
    const float* __restrict__ l0Whh, const float* __restrict__ l1Wih,
    const float* __restrict__ l1Whh, const float* __restrict__ l0Wih,
    const float* __restrict__ c1Wf, const float* __restrict__ c1Ws,
    const float* __restrict__ c2Wf, const float* __restrict__ c2Ws,
    unsigned short* __restrict__ pWih, unsigned short* __restrict__ pWhh,
    unsigned short* __restrict__ pWdyn,
    unsigned short* __restrict__ B0h, unsigned short* __restrict__ B1h,
    unsigned short* __restrict__ P1h, unsigned short* __restrict__ P1l,
    unsigned short* __restrict__ P2h, unsigned short* __restrict__ P2l,
    float* __restrict__ W0T, int* __restrict__ cnt)
{
    int i = blockIdx.x*256 + threadIdx.x;
    if (i < 768){ pf_item(gWih, 32, 1, i, pWih); return; }   i -= 768;
    if (i < 1536){ pf_item(gWhh, 64, 2, i, pWhh); return; }  i -= 1536;
    if (i < 512){ pf_item(Wdyn, 64, 2, i, pWdyn); return; }  i -= 512;
    if (i < 8192){ pcat_item(l0Whh, l0Whh, 128, 128, 4, i, B0h); return; } i -= 8192;
    if (i < 16384){ pcat_item(l1Wih, l1Whh, 128, 256, 8, i, B1h); return; } i -= 16384;
    if (i < 2048){ pproj_item(c1Wf, c1Ws, i, P1h, P1l); return; } i -= 2048;
    if (i < 2048){ pproj_item(c2Wf, c2Ws, i, P2h, P2l); return; } i -= 2048;
    if (i < 65536){ int g = i>>7, k = i&127; W0T[k*512+g] = l0Wih[i]; return; } i -= 65536;
    if (i < NN){ cnt[i] = 0; return; }
}
#define PACK_TOTAL (768+1536+512+8192+16384+2048+2048+65536+NN)

// ---------------- GRU encoder v3: MFMA (unchanged) ----------------
#define ESTR 68
__global__ __launch_bounds__(128) void encoder_mfma(
    const float* __restrict__ x,
    const float* __restrict__ Wip, const float* __restrict__ bip,
    const unsigned short* __restrict__ pWih,
    const unsigned short* __restrict__ pWhh,
    const float* __restrict__ bih, const float* __restrict__ bhh,
    const unsigned short* __restrict__ pWdyn,
    const float* __restrict__ bdyn,
    float* __restrict__ hist)
{
    __shared__ float sxl[512];
    __shared__ float femb[16*36];
    __shared__ float sh[16*ESTR];
    const int tid = threadIdx.x;
    const int l   = tid & 63;
    const int w   = tid >> 6;
    const int ln  = l & 15, q = l >> 4;
    const int blk = blockIdx.x;

    ((float4*)sxl)[tid] = ((const float4*)x)[(size_t)blk*128 + tid];
    for (int i=tid;i<16*ESTR;i+=128) sh[i]=0.f;

    const int ek = tid & 31;
    const float w0 = Wip[2*ek], w1 = Wip[2*ek+1], bk = bip[ek];
    const int em0 = tid >> 5;

    float bR[2], bZ[2], bNI[2], bNH[2];
#pragma unroll
    for (int u=0;u<2;u++){
        int g = 2*w + u;
        int c = g*16 + ln;
        bR[u]  = bih[c]       + bhh[c];
        bZ[u]  = bih[64 + c]  + bhh[64 + c];
        bNI[u] = bih[128 + c];
        bNH[u] = bhh[128 + c];
    }
    const v8s* FIH = (const v8s*)pWih;
    const v8s* FHH = (const v8s*)pWhh;
    const v8s* FDY = (const v8s*)pWdyn;
    __syncthreads();

#pragma unroll 1
    for (int t=0;t<TT;t++){
#pragma unroll
        for (int r=0;r<4;r++){
            int m = em0 + r*4;
            float e = w0*sxl[m*32 + 2*t] + w1*sxl[m*32 + 2*t + 1] + bk;
            femb[m*36 + ek] = lrelu(e);
        }
        __syncthreads();
        v8s eh, el; cvt8(&femb[ln*36 + q*8], eh, el);
        v8s h0h, h0l, h1h, h1l;
        cvt8(&sh[ln*ESTR +      q*8], h0h, h0l);
        cvt8(&sh[ln*ESTR + 32 + q*8], h1h, h1l);
        __syncthreads();
#pragma unroll
        for (int u=0;u<2;u++){
            int g = 2*w + u;
            v4f aR = {bR[u],bR[u],bR[u],bR[u]};
            v4f aZ = {bZ[u],bZ[u],bZ[u],bZ[u]};
            v4f aNI= {bNI[u],bNI[u],bNI[u],bNI[u]};
            v4f aNH= {bNH[u],bNH[u],bNH[u],bNH[u]};
            v8s b;
            b = FIH[(g   )*64 + l];   aR = MFMA16(eh,b,aR);  aR = MFMA16(el,b,aR);
            b = FHH[((g)*2+0)*64+l];  aR = MFMA16(h0h,b,aR); aR = MFMA16(h0l,b,aR);
            b = FHH[((g)*2+1)*64+l];  aR = MFMA16(h1h,b,aR); aR = MFMA16(h1l,b,aR);
            b = FIH[(4+g )*64 + l];   aZ = MFMA16(eh,b,aZ);  aZ = MFMA16(el,b,aZ);
            b = FHH[((4+g)*2+0)*64+l];aZ = MFMA16(h0h,b,aZ); aZ = MFMA16(h0l,b,aZ);
            b = FHH[((4+g)*2+1)*64+l];aZ = MFMA16(h1h,b,aZ); aZ = MFMA16(h1l,b,aZ);
            b = FIH[(8+g )*64 + l];   aNI= MFMA16(eh,b,aNI); aNI= MFMA16(el,b,aNI);
            b = FHH[((8+g)*2+0)*64+l];aNH= MFMA16(h0h,b,aNH);aNH= MFMA16(h0l,b,aNH);
            b = FHH[((8+g)*2+1)*64+l];aNH= MFMA16(h1h,b,aNH);aNH= MFMA16(h1l,b,aNH);
#pragma unroll
            for (int i=0;i<4;i++){
                float r_ = fsig(aR[i]);
                float z_ = fsig(aZ[i]);
                float nn_ = ftanh(aNI[i] + r_*aNH[i]);
                int row = q*4 + i, col = g*16 + ln;
                float old = sh[row*ESTR + col];
                sh[row*ESTR + col] = (1.f - z_)*nn_ + z_*old;
            }
        }
    }
    __syncthreads();
    {
        v8s a0h,a0l,a1h,a1l;
        cvt8_lrelu(&sh[ln*ESTR +      q*8], a0h, a0l);
        cvt8_lrelu(&sh[ln*ESTR + 32 + q*8], a1h, a1l);
#pragma unroll
        for (int u=0;u<2;u++){
            int nt = 2*w + u;
            float bb = bdyn[nt*16 + ln];
            v4f acc = {bb,bb,bb,bb};
            v8s b;
            b = FDY[(nt*2+0)*64 + l]; acc = MFMA16(a0h,b,acc); acc = MFMA16(a0l,b,acc);
            b = FDY[(nt*2+1)*64 + l]; acc = MFMA16(a1h,b,acc); acc = MFMA16(a1l,b,acc);
#pragma unroll
            for (int i=0;i<4;i++){
                hist[(size_t)(blk*16 + q*4 + i)*64 + nt*16 + ln] = lrelu(acc[i]);
            }
        }
    }
}

// ---------------- CGConv projections: MFMA (unchanged) ----------------
__global__ __launch_bounds__(256) void proj_mfma(
    const float* __restrict__ xin,
    const unsigned short* __restrict__ Bh, const unsigned short* __restrict__ Bl,
    float* __restrict__ Af, float* __restrict__ Bf,
    float* __restrict__ As, float* __restrict__ Bs)
{
    __shared__ float sx[64*68];
    const int tid = threadIdx.x;
    const int l = tid & 63;
    const int w = tid >> 6;
    const int ln = l & 15, q = l >> 4;
    const int n0 = blockIdx.x*64;

    for (int i=tid;i<64*16;i+=256){
        int nn = i>>4, f4 = i&15;
        float4 v = {0.f,0.f,0.f,0.f};
        if (n0+nn < NN) v = ((const float4*)(xin + (size_t)(n0+nn)*64))[f4];
        *(float4*)&sx[nn*68 + f4*4] = v;
    }
    __syncthreads();

    v8s ah0,al0,ah1,al1;
    cvt8(&sx[(w*16+ln)*68 +      q*8], ah0, al0);
    cvt8(&sx[(w*16+ln)*68 + 32 + q*8], ah1, al1);

    const v8s* FH = (const v8s*)Bh;
    const v8s* FL = (const v8s*)Bl;
#pragma unroll 1
    for (int nt=0; nt<16; nt++){
        v8s bh0 = FH[(nt*2+0)*64 + l], bl0 = FL[(nt*2+0)*64 + l];
        v8s bh1 = FH[(nt*2+1)*64 + l], bl1 = FL[(nt*2+1)*64 + l];
        v4f acc = {0.f,0.f,0.f,0.f};
        acc = MFMA16(ah0,bh0,acc); acc = MFMA16(al0,bh0,acc); acc = MFMA16(ah0,bl0,acc);
        acc = MFMA16(ah1,bh1,acc); acc = MFMA16(al1,bh1,acc); acc = MFMA16(ah1,bl1,acc);
        int d = nt >> 2, col = (nt&3)*16 + ln;
        float* op = (d==0) ? Af : (d==1) ? Bf : (d==2) ? As : Bs;
#pragma unroll
        for (int i=0;i<4;i++){
            int node = n0 + w*16 + q*4 + i;
            if (node < NN) op[(size_t)node*64 + col] = acc[i];
        }
    }
}

// ---------------- dst counting sort (unchanged; cnt zeroed by pack_all) ----------------
__global__ void count_kernel(const int* __restrict__ ei, int* __restrict__ cnt){
    int e = blockIdx.x*256 + threadIdx.x;
    if (e < EE) atomicAdd(&cnt[ei[EE+e]], 1);
}

__global__ __launch_bounds__(1024) void scan_kernel(const int* __restrict__ cnt,
                                                    int* __restrict__ off, int* __restrict__ cur){
    __shared__ int ssum[1024];
    const int t = threadIdx.x;
    const int CH = (NN + 1023)/1024;
    const int base = t*CH;
    int s = 0;
    for (int i=0;i<CH;i++){ int idx=base+i; if (idx<NN) s += cnt[idx]; }
    ssum[t] = s;
    __syncthreads();
    for (int d=1; d<1024; d<<=1){
        int v = (t>=d) ? ssum[t-d] : 0;
        __syncthreads();
        ssum[t] += v;
        __syncthreads();
    }
    int ex = (t==0) ? 0 : ssum[t-1];
    for (int i=0;i<CH;i++){
        int idx=base+i;
        if (idx<NN){ off[idx]=ex; cur[idx]=ex; ex += cnt[idx]; }
    }
    if (t==1023) off[NN] = ssum[1023];
}

__global__ void scatter_kernel(const int* __restrict__ ei, int* __restrict__ cur,
                               int* __restrict__ sorted){
    int e = blockIdx.x*256 + threadIdx.x;
    if (e >= EE) return;
    int d = ei[EE+e];
    int p = atomicAdd(&cur[d], 1);
    sorted[p] = e;
}

// ---------------- CGConv aggregate (R8 + 2x unroll for MLP) ----------------
__global__ __launch_bounds__(256) void cg_agg(
    const float* __restrict__ xin,
    const int* __restrict__ ei, const float* __restrict__ ea,
    const int* __restrict__ sorted, const int* __restrict__ off,
    const float* __restrict__ Wf, const float* __restrict__ bf,
    const float* __restrict__ Ws, const float* __restrict__ bs,
    const float* __restrict__ Af, const float* __restrict__ Bf,
    const float* __restrict__ As, const float* __restrict__ Bs,
    const float* __restrict__ gamma, const float* __restrict__ beta,
    const float* __restrict__ mean, const float* __restrict__ var,
    float* __restrict__ outp)
{
    const int tid = threadIdx.x;
    const int c = tid & 63, wid = tid >> 6;
    const int n = blockIdx.x*4 + wid;
    if (n >= NN) return;

    const float wf0 = Wf[c*130+128], wf1 = Wf[c*130+129], bfc = bf[c];
    const float ws0 = Ws[c*130+128], ws1 = Ws[c*130+129], bsc = bs[c];
    const float afd = Af[(size_t)n*64+c] + bfc, asd = As[(size_t)n*64+c] + bsc;
    const float* Bfc = Bf + c;
    const float* Bsc = Bs + c;

    float acc = 0.f;
    int i = off[n];
    const int i1 = off[n+1];
#pragma unroll 1
    for (; i+1 < i1; i += 2){
        int e0i = sorted[i], e1i = sorted[i+1];
        int s0 = ei[e0i], s1 = ei[e1i];
        float ea00 = ea[2*(size_t)e0i], ea01 = ea[2*(size_t)e0i+1];
        float ea10 = ea[2*(size_t)e1i], ea11 = ea[2*(size_t)e1i+1];
        float bf0v = Bfc[(size_t)s0*64], bs0v = Bsc[(size_t)s0*64];
        float bf1v = Bfc[(size_t)s1*64], bs1v = Bsc[(size_t)s1*64];
        float gf0 = afd + bf0v + wf0*ea00 + wf1*ea01;
        float gs0 = asd + bs0v + ws0*ea00 + ws1*ea01;
        float gf1 = afd + bf1v + wf0*ea10 + wf1*ea11;
        float gs1 = asd + bs1v + ws0*ea10 + ws1*ea11;
        acc += fsig(gf0)*fsoftplus(gs0);
        acc += fsig(gf1)*fsoftplus(gs1);
    }
    if (i < i1){
        int eid = sorted[i];
        int src = ei[eid];
        float e0 = ea[2*(size_t)eid], e1 = ea[2*(size_t)eid+1];
        float gf = afd + Bfc[(size_t)src*64] + wf0*e0 + wf1*e1;
        float gs = asd + Bsc[(size_t)src*64] + ws0*e0 + ws1*e1;
        acc += fsig(gf)*fsoftplus(gs);
    }
    float bn = (acc - mean[c])*rsqrtf(var[c]+BN_EPS)*gamma[c] + beta[c];
    outp[(size_t)n*64+c] = xin[(size_t)n*64+c] + bn;
}

// ---------------- target gather + nbrs linear + concat (unchanged) ----------------
__global__ __launch_bounds__(256) void target_kernel(
    const float* __restrict__ hist, const float* __restrict__ f2,
    const int* __restrict__ tgt,
    const float* __restrict__ Wn, const float* __restrict__ bn_,
    float* __restrict__ enc)
{
    const int tid=threadIdx.x;
    const int c = tid&63, q = tid>>6;
    const int b = blockIdx.x*4 + q;
    if (b>=BB) return;
    const int n = tgt[b];
    float a = bn_[c];
#pragma unroll
    for (int k=0;k<ENC;k++) a += Wn[c*64+k]*f2[(size_t)n*64+k];
    enc[(size_t)b*128 + 64 + c] = lrelu(a);
    enc[(size_t)b*128 + c]      = hist[(size_t)n*64+c];
}

// ---------------- gi0 = enc @ Wih0^T + bih0 + bhh0 (unchanged) ----------------
__global__ __launch_bounds__(512) void gi0_kernel(
    const float* __restrict__ enc, const float* __restrict__ W0T,
    const float* __restrict__ bih0, const float* __restrict__ bhh0,
    float* __restrict__ gi0)
{
    __shared__ float se[128];
    const int b = blockIdx.x, g = threadIdx.x;
    if (g < 128) se[g] = enc[(size_t)b*128+g];
    __syncthreads();
    float a = bih0[g]+bhh0[g];
#pragma unroll 4
    for (int k=0;k<128;k++) a += W0T[k*512+g]*se[k];
    gi0[(size_t)b*512+g] = a;
}

// ---------------- 2-layer LSTM decoder v5 ----------------
// R8 post-mortem: RA kept VGPR=128 and spilled/remat'd the 192-reg pin (FETCH
// 359MB). v5 makes residency structurally cheap: layer0 weights (128KB) live in
// LDS (flat copy of the packed frags, per-step ds_read_b128); layer1 weights are
// only 32 frags = 128 VGPRs pinned, with amdgpu_waves_per_eu(2,2) so the RA has
// no occupancy incentive below 256 regs. LMB=16 (125 blocks) halves any residual
// stream. Single-buffered h (4 barriers/step) to fit the 160KB LDS budget:
// 128K W0 + 16K h + 8.4K sh1f + 1K Wop = 157K.
#define LMB 16
__global__ __launch_bounds__(512)
__attribute__((amdgpu_waves_per_eu(2,2)))
void lstm_mfma(
    const float* __restrict__ gi0,
    const unsigned short* __restrict__ B0h,   // layer0 frags, NT=32 KB=4
    const unsigned short* __restrict__ B1h,   // layer1 frags, NT=32 KB=8
    const float* __restrict__ bih1, const float* __restrict__ bhh1,
    const float* __restrict__ Wop, const float* __restrict__ bop,
    float* __restrict__ outp)
{
    __shared__ int4 sW0[32*4*64];             // 128 KB: full layer0 weight frag set
    __shared__ unsigned short h0hi[4*512], h0lo[4*512];
    __shared__ unsigned short h1hi[4*512], h1lo[4*512];
    __shared__ float sh1f[16*132];
    __shared__ float sWop[256];
    const int tid = threadIdx.x;
    const int l = tid & 63;
    const int w = tid >> 6;           // wave 0..7
    const int c = l & 15;
    const int q = l >> 4;
    const int j = w*16 + c;           // owned hidden unit (all 4 gates)
    const int b0 = blockIdx.x*LMB;

    // stage layer0 weights to LDS (flat copy; packed order == use order)
    {
        const int4* F0 = (const int4*)B0h;
        for (int i=tid;i<32*4*64;i+=512) sW0[i] = F0[i];
    }
    for (int i=tid;i<4*512;i+=512){ h0hi[i]=0; h0lo[i]=0; h1hi[i]=0; h1lo[i]=0; }
    if (tid < 256) sWop[tid] = Wop[tid];

    // layer1 weights: 32 frags = 128 VGPRs, pinned
    int4 W1r[32];
    {
        const int4* F1 = (const int4*)B1h;
#pragma unroll
        for (int g=0;g<4;g++)
#pragma unroll
            for (int kb=0;kb<8;kb++) W1r[g*8+kb] = F1[((g*8+w)*8 + kb)*64 + l];
#pragma unroll
        for (int i=0;i<32;i++)
            asm volatile("" : "+v"(W1r[i].x), "+v"(W1r[i].y), "+v"(W1r[i].z), "+v"(W1r[i].w));
    }

    // gi0 (time-invariant layer0 input gates) in registers
    float rgi[4][4];
#pragma unroll
    for (int g=0;g<4;g++)
#pragma unroll
        for (int i=0;i<4;i++)
            rgi[g][i] = gi0[(size_t)(b0 + q*4 + i)*512 + g*128 + j];

    float b1[4];
#pragma unroll
    for (int g=0;g<4;g++) b1[g] = bih1[g*128+j] + bhh1[g*128+j];
    float c0[4] = {0,0,0,0}, c1[4] = {0,0,0,0};
    const float bo0 = bop[0], bo1 = bop[1];
    const int kbw = j>>5, qw = (j>>3)&3, jw = j&7;
    __syncthreads();

#pragma unroll 1
    for (int t=0;t<OUTL;t++){
        // ---- layer 0: W0 from LDS ----
        v4f acc[4];
#pragma unroll
        for (int g=0;g<4;g++){
            v4f t4 = {rgi[g][0], rgi[g][1], rgi[g][2], rgi[g][3]};
            acc[g] = t4;
        }
#pragma unroll
        for (int kb=0;kb<4;kb++){
            v8s ah = *(const v8s*)&h0hi[kb*512 + l*8];
            v8s al = *(const v8s*)&h0lo[kb*512 + l*8];
#pragma unroll
            for (int g=0;g<4;g++){
                v8s bfr = as_v8s(sW0[((g*8+w)*4 + kb)*64 + l]);
                acc[g] = MFMA16(ah, bfr, acc[g]);
                acc[g] = MFMA16(al, bfr, acc[g]);
            }
        }
        float hnew[4];
#pragma unroll
        for (int i=0;i<4;i++){
            c0[i] = fsig(acc[1][i])*c0[i] + fsig(acc[0][i])*ftanh(acc[2][i]);
            hnew[i] = fsig(acc[3][i])*ftanh(c0[i]);
        }
        __syncthreads();   // B1: all waves done reading h0_prev
#pragma unroll
        for (int i=0;i<4;i++){
            int off = kbw*512 + (qw*16 + q*4 + i)*8 + jw;
            unsigned short h = f2bf(hnew[i]);
            h0hi[off] = h;
            h0lo[off] = f2bf(hnew[i] - bf2f(h));
        }
        __syncthreads();   // B2: h0_new visible

        // ---- layer 1: W1 from pinned registers ----
        v4f a1[4];
#pragma unroll
        for (int g=0;g<4;g++){ v4f t4={b1[g],b1[g],b1[g],b1[g]}; a1[g]=t4; }
#pragma unroll
        for (int kb=0;kb<8;kb++){
            const unsigned short* hb = (kb<4) ? h0hi : h1hi;
            const unsigned short* lb = (kb<4) ? h0lo : h1lo;
            int kk = kb & 3;
            v8s ah = *(const v8s*)&hb[kk*512 + l*8];
            v8s al = *(const v8s*)&lb[kk*512 + l*8];
#pragma unroll
            for (int g=0;g<4;g++){
                a1[g] = MFMA16(ah, as_v8s(W1r[g*8+kb]), a1[g]);
                a1[g] = MFMA16(al, as_v8s(W1r[g*8+kb]), a1[g]);
            }
        }
        float h1new[4];
#pragma unroll
        for (int i=0;i<4;i++){
            c1[i] = fsig(a1[1][i])*c1[i] + fsig(a1[0][i])*ftanh(a1[2][i]);
            h1new[i] = fsig(a1[3][i])*ftanh(c1[i]);
        }
        __syncthreads();   // B3: all waves done reading h1_prev
#pragma unroll
        for (int i=0;i<4;i++){
            int off = kbw*512 + (qw*16 + q*4 + i)*8 + jw;
            unsigned short h = f2bf(h1new[i]);
            h1hi[off] = h;
            h1lo[off] = f2bf(h1new[i] - bf2f(h));
            sh1f[(q*4+i)*132 + j] = h1new[i];
        }
        __syncthreads();   // B4: h1_new + sh1f visible

        // ---- output projection (16 samples x 2 outputs) ----
        if (tid < 32){
            int m = tid>>1, o = tid&1;
            const float4* hv = (const float4*)&sh1f[m*132];
            const float4* wv = (const float4*)&sWop[o*128];
            float4 s4={0,0,0,0};
#pragma unroll
            for (int k4=0;k4<32;k4++) fma44(s4, wv[k4], hv[k4]);
            outp[(size_t)(b0+m)*(OUTL*2) + t*2 + o] = hsum(s4) + (o ? bo1 : bo0);
        }
        // out-proj wave (wave 0) must re-join B1 before any wave can pass B3 of
        // the next step (first sh1f overwrite) -> reads complete in time. Safe.
    }
}

extern "C" void kernel_launch(void* const* d_in, const int* in_sizes, int n_in,
                              void* d_out, int out_size, void* d_ws, size_t ws_size,
                              hipStream_t stream)
{
    const float* x    = (const float*)d_in[0];
    const int*   ei   = (const int*)d_in[1];
    const float* ea   = (const float*)d_in[2];
    const int*   tgt  = (const int*)d_in[3];
    const float* Wip  = (const float*)d_in[4];
    const float* bip  = (const float*)d_in[5];
    const float* gWih = (const float*)d_in[6];
    const float* gWhh = (const float*)d_in[7];
    const float* gbih = (const float*)d_in[8];
    const float* gbhh = (const float*)d_in[9];
    const float* Wdyn = (const float*)d_in[10];
    const float* bdyn = (const float*)d_in[11];
    const float* c1Wf=(const float*)d_in[12]; const float* c1bf=(const float*)d_in[13];
    const float* c1Ws=(const float*)d_in[14]; const float* c1bs=(const float*)d_in[15];
    const float* c1g =(const float*)d_in[16]; const float* c1b =(const float*)d_in[17];
    const float* c1m =(const float*)d_in[18]; const float* c1v =(const float*)d_in[19];
    const float* c2Wf=(const float*)d_in[20]; const float* c2bf=(const float*)d_in[21];
    const float* c2Ws=(const float*)d_in[22]; const float* c2bs=(const float*)d_in[23];
    const float* c2g =(const float*)d_in[24]; const float* c2b =(const float*)d_in[25];
    const float* c2m =(const float*)d_in[26]; const float* c2v =(const float*)d_in[27];
    const float* Wn  =(const float*)d_in[28]; const float* bn_ =(const float*)d_in[29];
    const float* l0Wih=(const float*)d_in[30]; const float* l0Whh=(const float*)d_in[31];
    const float* l0bih=(const float*)d_in[32]; const float* l0bhh=(const float*)d_in[33];
    const float* l1Wih=(const float*)d_in[34]; const float* l1Whh=(const float*)d_in[35];
    const float* l1bih=(const float*)d_in[36]; const float* l1bhh=(const float*)d_in[37];
    const float* Wop =(const float*)d_in[38]; const float* bop=(const float*)d_in[39];

    float* ws = (float*)d_ws;
    size_t o = 0;
    float* hist = ws + o; o += (size_t)NN*ENC;
    float* f1   = ws + o; o += (size_t)NN*ENC;
    float* f2   = ws + o; o += (size_t)NN*ENC;
    float* Af   = ws + o; o += (size_t)NN*ENC;
    float* Bf   = ws + o; o += (size_t)NN*ENC;
    float* As   = ws + o; o += (size_t)NN*ENC;
    float* Bs   = ws + o; o += (size_t)NN*ENC;
    float* enc  = ws + o; o += (size_t)BB*2*ENC;
    float* gi0  = ws + o; o += (size_t)BB*4*DEC;
    float* W0T  = ws + o; o += (size_t)128*512;
    unsigned short* pWih  = (unsigned short*)(ws + o); o += (size_t)12*64*8/2;
    unsigned short* pWhh  = (unsigned short*)(ws + o); o += (size_t)24*64*8/2;
    unsigned short* pWdyn = (unsigned short*)(ws + o); o += (size_t)8*64*8/2;
    unsigned short* B0h = (unsigned short*)(ws + o); o += (size_t)32*4*64*8/2;
    unsigned short* B1h = (unsigned short*)(ws + o); o += (size_t)32*8*64*8/2;
    unsigned short* P1h = (unsigned short*)(ws + o); o += (size_t)2048*8/2;
    unsigned short* P1l = (unsigned short*)(ws + o); o += (size_t)2048*8/2;
    unsigned short* P2h = (unsigned short*)(ws + o); o += (size_t)2048*8/2;
    unsigned short* P2l = (unsigned short*)(ws + o); o += (size_t)2048*8/2;
    int* cnt    = (int*)(ws + o); o += NN;
    int* offv   = (int*)(ws + o); o += NN+1;
    int* curv   = (int*)(ws + o); o += NN;
    int* sorted = (int*)(ws + o); o += EE;

    // --- all weight prep + cnt zero in one dispatch ---
    pack_all<<<(PACK_TOTAL+255)/256, 256, 0, stream>>>(
        gWih, gWhh, Wdyn, l0Whh, l1Wih, l1Whh, l0Wih,
        c1Wf, c1Ws, c2Wf, c2Ws,
        pWih, pWhh, pWdyn, B0h, B1h, P1h, P1l, P2h, P2l, W0T, cnt);

    // --- dst counting sort (reused by both convs) ---
    count_kernel<<<(EE+255)/256, 256, 0, stream>>>(ei, cnt);
    scan_kernel<<<1, 1024, 0, stream>>>(cnt, offv, curv);
    scatter_kernel<<<(EE+255)/256, 256, 0, stream>>>(ei, curv, sorted);

    // --- history encoder (MFMA) ---
    encoder_mfma<<<NN/16, 128, 0, stream>>>(x, Wip, bip, pWih, pWhh, gbih, gbhh, pWdyn, bdyn, hist);

    // --- CGConv 1 ---
    proj_mfma<<<(NN+63)/64, 256, 0, stream>>>(hist, P1h, P1l, Af,Bf,As,Bs);
    cg_agg<<<(NN+3)/4, 256, 0, stream>>>(hist, ei, ea, sorted, offv,
                                         c1Wf,c1bf,c1Ws,c1bs, Af,Bf,As,Bs,
                                         c1g,c1b,c1m,c1v, f1);

    // --- CGConv 2 ---
    proj_mfma<<<(NN+63)/64, 256, 0, stream>>>(f1, P2h, P2l, Af,Bf,As,Bs);
    cg_agg<<<(NN+3)/4, 256, 0, stream>>>(f1, ei, ea, sorted, offv,
                                         c2Wf,c2bf,c2Ws,c2bs, Af,Bf,As,Bs,
                                         c2g,c2b,c2m,c2v, f2);

    // --- target encoding ---
    target_kernel<<<(BB+3)/4, 256, 0, stream>>>(hist, f2, tgt, Wn, bn_, enc);

    // --- LSTM decoder prep ---
    gi0_kernel<<<BB, 512, 0, stream>>>(enc, W0T, l0bih, l0bhh, gi0);

    // --- LSTM decoder (LDS-W0 + pinned-W1 MFMA) ---
    lstm_mfma<<<BB/LMB, 512, 0, stream>>>(gi0, B0h, B1h,
                                          l1bih, l1bhh, Wop, bop, (float*)d_out);
}

// Round 10
// 754.303 us; speedup vs baseline: 17.1744x; 1.1223x over previous
//
#include <hip/hip_runtime.h>
#include <math.h>

#define NN   50000
#define TT   16
#define EE   800000
#define BB   2000
#define EMBD 32
#define ENC  64
#define DEC  128
#define OUTL 25
#define BN_EPS 1e-5f

typedef short v8s __attribute__((ext_vector_type(8)));
typedef float v4f __attribute__((ext_vector_type(4)));
#define MFMA16(a,b,c) __builtin_amdgcn_mfma_f32_16x16x32_bf16((a),(b),(c),0,0,0)

__device__ __forceinline__ float lrelu(float v){ return v >= 0.f ? v : 0.1f*v; }
__device__ __forceinline__ float fsig(float v){ return __builtin_amdgcn_rcpf(1.f + __expf(-v)); }
__device__ __forceinline__ float ftanh(float v){ return 2.f*__builtin_amdgcn_rcpf(1.f + __expf(-2.f*v)) - 1.f; }
__device__ __forceinline__ float fsoftplus(float v){
    return v > 15.f ? v : __logf(1.f + __expf(v));
}
__device__ __forceinline__ void fma44(float4& a, float4 w, float4 h){
    a.x += w.x*h.x; a.y += w.y*h.y; a.z += w.z*h.z; a.w += w.w*h.w;
}
__device__ __forceinline__ float hsum(float4 a){ return (a.x+a.y)+(a.z+a.w); }

__device__ __forceinline__ unsigned short f2bf(float f){
    unsigned u = __float_as_uint(f);
    u = u + 0x7FFFu + ((u>>16)&1u);
    return (unsigned short)(u>>16);
}
__device__ __forceinline__ float bf2f(unsigned short s){ return __uint_as_float(((unsigned)s)<<16); }

__device__ __forceinline__ v8s as_v8s(int4 v){
    union { int4 i; v8s s; } u; u.i = v; return u.s;
}

__device__ __forceinline__ void cvt8(const float* p, v8s& hi, v8s& lo){
    float4 a0 = *(const float4*)p;
    float4 a1 = *(const float4*)(p+4);
    float av[8] = {a0.x,a0.y,a0.z,a0.w,a1.x,a1.y,a1.z,a1.w};
#pragma unroll
    for (int j=0;j<8;j++){
        unsigned short h = f2bf(av[j]);
        hi[j] = (short)h;
        lo[j] = (short)f2bf(av[j] - bf2f(h));
    }
}
// reconstruct hi+lo, lrelu, re-split
__device__ __forceinline__ void lrelu_resplit(v8s hh, v8s hl, v8s& oh, v8s& ol){
#pragma unroll
    for (int j=0;j<8;j++){
        float v = bf2f((unsigned short)hh[j]) + bf2f((unsigned short)hl[j]);
        float a = lrelu(v);
        unsigned short h = f2bf(a);
        oh[j] = (short)h;
        ol[j] = (short)f2bf(a - bf2f(h));
    }
}

// ---------------- fused packing helpers ----------------
__device__ __forceinline__ void pf_item(const float* W, int K, int KB, int i,
                                        unsigned short* out){
    int l = i & 63, fb = i >> 6;
    int kb = fb % KB, nt = fb / KB;
    int n = nt*16 + (l&15);
    int k0 = kb*32 + ((l>>4)*8);
#pragma unroll
    for (int j=0;j<8;j++) out[i*8+j] = f2bf(W[(size_t)n*K + k0 + j]);
}
__device__ __forceinline__ void phl_item(const float* W, int K, int KB, int i,
                                         unsigned short* hi, unsigned short* lo){
    int l = i & 63, fb = i >> 6;
    int kb = fb % KB, nt = fb / KB;
    int n = nt*16 + (l&15);
    int k0 = kb*32 + ((l>>4)*8);
#pragma unroll
    for (int j=0;j<8;j++){
        float v = W[(size_t)n*K + k0 + j];
        unsigned short h = f2bf(v);
        hi[i*8+j] = h;
        lo[i*8+j] = f2bf(v - bf2f(h));
    }
}
__device__ __forceinline__ void pcat_item(const float* Wa, const float* Wb,
                                          int K1, int K, int KB, int i,
                                          unsigned short* out){
    int l = i & 63, fb = i >> 6;
    int kb = fb % KB, nt = fb / KB;
    int n = nt*16 + (l&15);
    int k0 = kb*32 + ((l>>4)*8);
#pragma unroll
    for (int j=0;j<8;j++){
        int k = k0 + j;
        float v = (k < K1) ? Wa[(size_t)n*K1 + k] : Wb[(size_t)n*(K-K1) + (k-K1)];
        out[i*8+j] = f2bf(v);
    }
}
__device__ __forceinline__ void pproj_item(const float* Wf, const float* Ws, int i,
                                           unsigned short* hi, unsigned short* lo){
    int l = i & 63, fb = i >> 6;
    int kb = fb & 1, nt = fb >> 1;
    int n = nt*16 + (l&15);
    int d = n >> 6, c = n & 63;
    const float* W = (d < 2) ? Wf : Ws;
    int k0 = (d&1)*64 + kb*32 + ((l>>4)*8);
#pragma unroll
    for (int j=0;j<8;j++){
        float v = W[c*130 + k0 + j];
        unsigned short h = f2bf(v);
        hi[i*8+j] = h;
        lo[i*8+j] = f2bf(v - bf2f(h));
    }
}

// ---------------- all weight prep in ONE dispatch ----------------
__global__ void pack_all(
    const float* __restrict__ gWih, const float* __restrict__ gWhh,
    const float* __restrict__ Wdyn,
    const float* __restrict__ l0Whh, const float* __restrict__ l1Wih,
    const float* __restrict__ l1Whh, const float* __restrict__ l0Wih,
    const float* __restrict__ c1Wf, const float* __restrict__ c1Ws,
    const float* __restrict__ c2Wf, const float* __restrict__ c2Ws,
    unsigned short* __restrict__ pWih, unsigned short* __restrict__ pWhh,
    unsigned short* __restrict__ pWdyn,
    unsigned short* __restrict__ B0h, unsigned short* __restrict__ B1h,
    unsigned short* __restrict__ P1h, unsigned short* __restrict__ P1l,
    unsigned short* __restrict__ P2h, unsigned short* __restrict__ P2l,
    unsigned short* __restrict__ GIh, unsigned short* __restrict__ GIl,
    int* __restrict__ cnt)
{
    int i = blockIdx.x*256 + threadIdx.x;
    if (i < 768){ pf_item(gWih, 32, 1, i, pWih); return; }   i -= 768;
    if (i < 1536){ pf_item(gWhh, 64, 2, i, pWhh); return; }  i -= 1536;
    if (i < 512){ pf_item(Wdyn, 64, 2, i, pWdyn); return; }  i -= 512;
    if (i < 8192){ pcat_item(l0Whh, l0Whh, 128, 128, 4, i, B0h); return; } i -= 8192;
    if (i < 16384){ pcat_item(l1Wih, l1Whh, 128, 256, 8, i, B1h); return; } i -= 16384;
    if (i < 2048){ pproj_item(c1Wf, c1Ws, i, P1h, P1l); return; } i -= 2048;
    if (i < 2048){ pproj_item(c2Wf, c2Ws, i, P2h, P2l); return; } i -= 2048;
    if (i < 8192){ phl_item(l0Wih, 128, 4, i, GIh, GIl); return; } i -= 8192;
    if (i < NN){ cnt[i] = 0; return; }
}
#define PACK_TOTAL (768+1536+512+8192+16384+2048+2048+8192+NN)

// ---------------- GRU encoder v4: MFMA + frag-resident state ----------------
// R9 note: read-side cvt8 x3/step (~240 VALU) -> emb & h stored directly in
// A-frag hi/lo layout (writer splits once), old-h kept in registers.
__global__ __launch_bounds__(128) void encoder_mfma(
    const float* __restrict__ x,
    const float* __restrict__ Wip, const float* __restrict__ bip,
    const unsigned short* __restrict__ pWih,
    const unsigned short* __restrict__ pWhh,
    const float* __restrict__ bih, const float* __restrict__ bhh,
    const unsigned short* __restrict__ pWdyn,
    const float* __restrict__ bdyn,
    float* __restrict__ hist)
{
    __shared__ float sxl[512];
    __shared__ unsigned short efh[512], efl[512];      // emb A-frags (kb=0)
    __shared__ unsigned short hfh[2*512], hfl[2*512];  // h A-frags (kb=0,1)
    const int tid = threadIdx.x;
    const int l   = tid & 63;
    const int w   = tid >> 6;
    const int ln  = l & 15, q = l >> 4;
    const int blk = blockIdx.x;

    ((float4*)sxl)[tid] = ((const float4*)x)[(size_t)blk*128 + tid];
    for (int i=tid;i<2*512;i+=128){ hfh[i]=0; hfl[i]=0; }

    const int ek = tid & 31;
    const float w0 = Wip[2*ek], w1 = Wip[2*ek+1], bk = bip[ek];
    const int em0 = tid >> 5;
    const int eoffb = (16*(ek>>3))*8 + (ek&7);   // frag offset base for k=ek

    float bR[2], bZ[2], bNI[2], bNH[2];
    float hprev[2][4];
#pragma unroll
    for (int u=0;u<2;u++){
        int g = 2*w + u;
        int c = g*16 + ln;
        bR[u]  = bih[c]       + bhh[c];
        bZ[u]  = bih[64 + c]  + bhh[64 + c];
        bNI[u] = bih[128 + c];
        bNH[u] = bhh[128 + c];
        hprev[u][0]=0.f; hprev[u][1]=0.f; hprev[u][2]=0.f; hprev[u][3]=0.f;
    }
    const v8s* FIH = (const v8s*)pWih;
    const v8s* FHH = (const v8s*)pWhh;
    const v8s* FDY = (const v8s*)pWdyn;
    __syncthreads();

#pragma unroll 1
    for (int t=0;t<TT;t++){
        // ---- emb = lrelu(x W_ip^T + b), split-written into A-frag layout ----
#pragma unroll
        for (int r=0;r<4;r++){
            int m = em0 + r*4;
            float e = lrelu(w0*sxl[m*32 + 2*t] + w1*sxl[m*32 + 2*t + 1] + bk);
            unsigned short h_ = f2bf(e);
            int off = eoffb + m*8;
            efh[off] = h_;
            efl[off] = f2bf(e - bf2f(h_));
        }
        __syncthreads();                       // BA: frags ready
        v8s eh = *(const v8s*)&efh[l*8];
        v8s el = *(const v8s*)&efl[l*8];
        v8s h0h = *(const v8s*)&hfh[l*8];
        v8s h0l = *(const v8s*)&hfl[l*8];
        v8s h1h = *(const v8s*)&hfh[512 + l*8];
        v8s h1l = *(const v8s*)&hfl[512 + l*8];
        __syncthreads();                       // BB: reads done, writes may begin
#pragma unroll
        for (int u=0;u<2;u++){
            int g = 2*w + u;
            v4f aR = {bR[u],bR[u],bR[u],bR[u]};
            v4f aZ = {bZ[u],bZ[u],bZ[u],bZ[u]};
            v4f aNI= {bNI[u],bNI[u],bNI[u],bNI[u]};
            v4f aNH= {bNH[u],bNH[u],bNH[u],bNH[u]};
            v8s b;
            b = FIH[(g   )*64 + l];   aR = MFMA16(eh,b,aR);  aR = MFMA16(el,b,aR);
            b = FHH[((g)*2+0)*64+l];  aR = MFMA16(h0h,b,aR); aR = MFMA16(h0l,b,aR);
            b = FHH[((g)*2+1)*64+l];  aR = MFMA16(h1h,b,aR); aR = MFMA16(h1l,b,aR);
            b = FIH[(4+g )*64 + l];   aZ = MFMA16(eh,b,aZ);  aZ = MFMA16(el,b,aZ);
            b = FHH[((4+g)*2+0)*64+l];aZ = MFMA16(h0h,b,aZ); aZ = MFMA16(h0l,b,aZ);
            b = FHH[((4+g)*2+1)*64+l];aZ = MFMA16(h1h,b,aZ); aZ = MFMA16(h1l,b,aZ);
            b = FIH[(8+g )*64 + l];   aNI= MFMA16(eh,b,aNI); aNI= MFMA16(el,b,aNI);
            b = FHH[((8+g)*2+0)*64+l];aNH= MFMA16(h0h,b,aNH);aNH= MFMA16(h0l,b,aNH);
            b = FHH[((8+g)*2+1)*64+l];aNH= MFMA16(h1h,b,aNH);aNH= MFMA16(h1l,b,aNH);
#pragma unroll
            for (int i=0;i<4;i++){
                float r_ = fsig(aR[i]);
                float z_ = fsig(aZ[i]);
                float nn_ = ftanh(aNI[i] + r_*aNH[i]);
                float hn = (1.f - z_)*nn_ + z_*hprev[u][i];
                hprev[u][i] = hn;
                int row = q*4 + i, col = g*16 + ln;
                int off = (col>>5)*512 + (16*((col&31)>>3) + row)*8 + (col&7);
                unsigned short hh_ = f2bf(hn);
                hfh[off] = hh_;
                hfl[off] = f2bf(hn - bf2f(hh_));
            }
        }
    }
    __syncthreads();
    // ---- hist = lrelu(lrelu(h) @ Wdyn^T + b) ----
    {
        v8s a0h,a0l,a1h,a1l;
        lrelu_resplit(*(const v8s*)&hfh[l*8],       *(const v8s*)&hfl[l*8],       a0h, a0l);
        lrelu_resplit(*(const v8s*)&hfh[512 + l*8], *(const v8s*)&hfl[512 + l*8], a1h, a1l);
#pragma unroll
        for (int u=0;u<2;u++){
            int nt = 2*w + u;
            float bb = bdyn[nt*16 + ln];
            v4f acc = {bb,bb,bb,bb};
            v8s b;
            b = FDY[(nt*2+0)*64 + l]; acc = MFMA16(a0h,b,acc); acc = MFMA16(a0l,b,acc);
            b = FDY[(nt*2+1)*64 + l]; acc = MFMA16(a1h,b,acc); acc = MFMA16(a1l,b,acc);
#pragma unroll
            for (int i=0;i<4;i++){
                hist[(size_t)(blk*16 + q*4 + i)*64 + nt*16 + ln] = lrelu(acc[i]);
            }
        }
    }
}

// ---------------- CGConv projections: MFMA (unchanged) ----------------
__global__ __launch_bounds__(256) void proj_mfma(
    const float* __restrict__ xin,
    const unsigned short* __restrict__ Bh, const unsigned short* __restrict__ Bl,
    float* __restrict__ Af, float* __restrict__ Bf,
    float* __restrict__ As, float* __restrict__ Bs)
{
    __shared__ float sx[64*68];
    const int tid = threadIdx.x;
    const int l = tid & 63;
    const int w = tid >> 6;
    const int ln = l & 15, q = l >> 4;
    const int n0 = blockIdx.x*64;

    for (int i=tid;i<64*16;i+=256){
        int nn = i>>4, f4 = i&15;
        float4 v = {0.f,0.f,0.f,0.f};
        if (n0+nn < NN) v = ((const float4*)(xin + (size_t)(n0+nn)*64))[f4];
        *(float4*)&sx[nn*68 + f4*4] = v;
    }
    __syncthreads();

    v8s ah0,al0,ah1,al1;
    cvt8(&sx[(w*16+ln)*68 +      q*8], ah0, al0);
    cvt8(&sx[(w*16+ln)*68 + 32 + q*8], ah1, al1);

    const v8s* FH = (const v8s*)Bh;
    const v8s* FL = (const v8s*)Bl;
#pragma unroll 1
    for (int nt=0; nt<16; nt++){
        v8s bh0 = FH[(nt*2+0)*64 + l], bl0 = FL[(nt*2+0)*64 + l];
        v8s bh1 = FH[(nt*2+1)*64 + l], bl1 = FL[(nt*2+1)*64 + l];
        v4f acc = {0.f,0.f,0.f,0.f};
        acc = MFMA16(ah0,bh0,acc); acc = MFMA16(al0,bh0,acc); acc = MFMA16(ah0,bl0,acc);
        acc = MFMA16(ah1,bh1,acc); acc = MFMA16(al1,bh1,acc); acc = MFMA16(ah1,bl1,acc);
        int d = nt >> 2, col = (nt&3)*16 + ln;
        float* op = (d==0) ? Af : (d==1) ? Bf : (d==2) ? As : Bs;
#pragma unroll
        for (int i=0;i<4;i++){
            int node = n0 + w*16 + q*4 + i;
            if (node < NN) op[(size_t)node*64 + col] = acc[i];
        }
    }
}

// ---------------- dst counting sort + edge pre-gather ----------------
__global__ void count_kernel(const int* __restrict__ ei, int* __restrict__ cnt){
    int e = blockIdx.x*256 + threadIdx.x;
    if (e < EE) atomicAdd(&cnt[ei[EE+e]], 1);
}

__global__ __launch_bounds__(1024) void scan_kernel(const int* __restrict__ cnt,
                                                    int* __restrict__ off, int* __restrict__ cur){
    __shared__ int ssum[1024];
    const int t = threadIdx.x;
    const int CH = (NN + 1023)/1024;
    const int base = t*CH;
    int s = 0;
    for (int i=0;i<CH;i++){ int idx=base+i; if (idx<NN) s += cnt[idx]; }
    ssum[t] = s;
    __syncthreads();
    for (int d=1; d<1024; d<<=1){
        int v = (t>=d) ? ssum[t-d] : 0;
        __syncthreads();
        ssum[t] += v;
        __syncthreads();
    }
    int ex = (t==0) ? 0 : ssum[t-1];
    for (int i=0;i<CH;i++){
        int idx=base+i;
        if (idx<NN){ off[idx]=ex; cur[idx]=ex; ex += cnt[idx]; }
    }
    if (t==1023) off[NN] = ssum[1023];
}

// scatter + pre-gather src & edge_attr into dst-sorted order
__global__ void scatter_kernel(const int* __restrict__ ei, const float* __restrict__ ea,
                               int* __restrict__ cur,
                               int* __restrict__ srcS, float2* __restrict__ eaS){
    int e = blockIdx.x*256 + threadIdx.x;
    if (e >= EE) return;
    int d = ei[EE+e];
    int p = atomicAdd(&cur[d], 1);
    srcS[p] = ei[e];
    float2 v; v.x = ea[2*(size_t)e]; v.y = ea[2*(size_t)e+1];
    eaS[p] = v;
}

// ---------------- CGConv aggregate (sorted-sequential src/ea reads) ----------------
__global__ __launch_bounds__(256) void cg_agg(
    const float* __restrict__ xin,
    const int* __restrict__ srcS, const float2* __restrict__ eaS,
    const int* __restrict__ off,
    const float* __restrict__ Wf, const float* __restrict__ bf,
    const float* __restrict__ Ws, const float* __restrict__ bs,
    const float* __restrict__ Af, const float* __restrict__ Bf,
    const float* __restrict__ As, const float* __restrict__ Bs,
    const float* __restrict__ gamma, const float* __restrict__ beta,
    const float* __restrict__ mean, const float* __restrict__ var,
    float* __restrict__ outp)
{
    const int tid = threadIdx.x;
    const int c = tid & 63, wid = tid >> 6;
    const int n = blockIdx.x*4 + wid;
    if (n >= NN) return;

    const float wf0 = Wf[c*130+128], wf1 = Wf[c*130+129], bfc = bf[c];
    const float ws0 = Ws[c*130+128], ws1 = Ws[c*130+129], bsc = bs[c];
    const float afd = Af[(size_t)n*64+c] + bfc, asd = As[(size_t)n*64+c] + bsc;
    const float* Bfc = Bf + c;
    const float* Bsc = Bs + c;

    float acc = 0.f;
    int i = off[n];
    const int i1 = off[n+1];
#pragma unroll 1
    for (; i+1 < i1; i += 2){
        int s0 = srcS[i], s1 = srcS[i+1];
        float2 e0 = eaS[i], e1 = eaS[i+1];
        float bf0v = Bfc[(size_t)s0*64], bs0v = Bsc[(size_t)s0*64];
        float bf1v = Bfc[(size_t)s1*64], bs1v = Bsc[(size_t)s1*64];
        float gf0 = afd + bf0v + wf0*e0.x + wf1*e0.y;
        float gs0 = asd + bs0v + ws0*e0.x + ws1*e0.y;
        float gf1 = afd + bf1v + wf0*e1.x + wf1*e1.y;
        float gs1 = asd + bs1v + ws0*e1.x + ws1*e1.y;
        acc += fsig(gf0)*fsoftplus(gs0);
        acc += fsig(gf1)*fsoftplus(gs1);
    }
    if (i < i1){
        int s0 = srcS[i];
        float2 e0 = eaS[i];
        float gf = afd + Bfc[(size_t)s0*64] + wf0*e0.x + wf1*e0.y;
        float gs = asd + Bsc[(size_t)s0*64] + ws0*e0.x + ws1*e0.y;
        acc += fsig(gf)*fsoftplus(gs);
    }
    float bn = (acc - mean[c])*rsqrtf(var[c]+BN_EPS)*gamma[c] + beta[c];
    outp[(size_t)n*64+c] = xin[(size_t)n*64+c] + bn;
}

// ---------------- target gather + nbrs linear + concat (unchanged) ----------------
__global__ __launch_bounds__(256) void target_kernel(
    const float* __restrict__ hist, const float* __restrict__ f2,
    const int* __restrict__ tgt,
    const float* __restrict__ Wn, const float* __restrict__ bn_,
    float* __restrict__ enc)
{
    const int tid=threadIdx.x;
    const int c = tid&63, q = tid>>6;
    const int b = blockIdx.x*4 + q;
    if (b>=BB) return;
    const int n = tgt[b];
    float a = bn_[c];
#pragma unroll
    for (int k=0;k<ENC;k++) a += Wn[c*64+k]*f2[(size_t)n*64+k];
    enc[(size_t)b*128 + 64 + c] = lrelu(a);
    enc[(size_t)b*128 + c]      = hist[(size_t)n*64+c];
}

// ---------------- gi0 via MFMA: [2000x128]@[128->512] + biases ----------------
// R9 post-mortem: gi0_kernel re-read W0T per block = 512MB L2 traffic.
__global__ __launch_bounds__(512) void gi0_mfma(
    const float* __restrict__ enc,
    const unsigned short* __restrict__ GIh, const unsigned short* __restrict__ GIl,
    const float* __restrict__ bih0, const float* __restrict__ bhh0,
    float* __restrict__ gi0)
{
    __shared__ float senc[16*132];
    const int tid = threadIdx.x;
    const int l = tid & 63;
    const int w = tid >> 6;
    const int ln = l & 15, q = l >> 4;
    const int b0 = blockIdx.x*16;

    for (int i=tid;i<16*32;i+=512){
        int row = i>>5, f4 = i&31;
        *(float4*)&senc[row*132 + f4*4] = ((const float4*)(enc + (size_t)(b0+row)*128))[f4];
    }
    __syncthreads();

    v8s ah[4], al[4];
#pragma unroll
    for (int kb=0;kb<4;kb++) cvt8(&senc[ln*132 + kb*32 + q*8], ah[kb], al[kb]);

    const v8s* FH = (const v8s*)GIh;
    const v8s* FL = (const v8s*)GIl;
#pragma unroll
    for (int u=0;u<4;u++){
        int nt = w*4 + u;
        int col = nt*16 + ln;
        float bb = bih0[col] + bhh0[col];
        v4f acc = {bb,bb,bb,bb};
#pragma unroll
        for (int kb=0;kb<4;kb++){
            v8s bh = FH[(nt*4+kb)*64 + l];
            v8s bl = FL[(nt*4+kb)*64 + l];
            acc = MFMA16(ah[kb],bh,acc); acc = MFMA16(al[kb],bh,acc); acc = MFMA16(ah[kb],bl,acc);
        }
#pragma unroll
        for (int i=0;i<4;i++)
            gi0[(size_t)(b0 + q*4 + i)*512 + col] = acc[i];
    }
}

// ---------------- 2-layer LSTM decoder v6 ----------------
// R9: t-loop barrier/latency bound (4 barriers/step, 13k cyc/step vs ~1k work).
// v6: h0 double-buffered -> 3 barriers/step; sh1f stored bf16 (out-proj only);
// Wop read from global. LDS = 131072(W0) + 16384(h0 dbuf) + 8192(h1) +
// 4352(sh1b) = 160000 <= 163840.
#define LMB 16
__global__ __launch_bounds__(512)
__attribute__((amdgpu_waves_per_eu(2,2)))
void lstm_mfma(
    const float* __restrict__ gi0,
    const unsigned short* __restrict__ B0h,
    const unsigned short* __restrict__ B1h,
    const float* __restrict__ bih1, const float* __restrict__ bhh1,
    const float* __restrict__ Wop, const float* __restrict__ bop,
    float* __restrict__ outp)
{
    __shared__ int4 sW0[32*4*64];                       // 128 KB
    __shared__ unsigned short h0hi[2][4*512], h0lo[2][4*512];   // 16 KB
    __shared__ unsigned short h1hi[4*512], h1lo[4*512];         // 8 KB
    __shared__ unsigned short sh1b[16*136];                     // 4.25 KB bf16 h1
    const int tid = threadIdx.x;
    const int l = tid & 63;
    const int w = tid >> 6;
    const int c = l & 15;
    const int q = l >> 4;
    const int j = w*16 + c;
    const int b0 = blockIdx.x*LMB;

    {
        const int4* F0 = (const int4*)B0h;
        for (int i=tid;i<32*4*64;i+=512) sW0[i] = F0[i];
    }
    for (int i=tid;i<4*512;i+=512){
        h0hi[0][i]=0; h0lo[0][i]=0; h0hi[1][i]=0; h0lo[1][i]=0;
        h1hi[i]=0; h1lo[i]=0;
    }

    int4 W1r[32];
    {
        const int4* F1 = (const int4*)B1h;
#pragma unroll
        for (int g=0;g<4;g++)
#pragma unroll
            for (int kb=0;kb<8;kb++) W1r[g*8+kb] = F1[((g*8+w)*8 + kb)*64 + l];
#pragma unroll
        for (int i=0;i<32;i++)
            asm volatile("" : "+v"(W1r[i].x), "+v"(W1r[i].y), "+v"(W1r[i].z), "+v"(W1r[i].w));
    }

    float rgi[4][4];
#pragma unroll
    for (int g=0;g<4;g++)
#pragma unroll
        for (int i=0;i<4;i++)
            rgi[g][i] = gi0[(size_t)(b0 + q*4 + i)*512 + g*128 + j];

    float b1[4];
#pragma unroll
    for (int g=0;g<4;g++) b1[g] = bih1[g*128+j] + bhh1[g*128+j];
    float c0[4] = {0,0,0,0}, c1[4] = {0,0,0,0};
    const float bo0 = bop[0], bo1 = bop[1];
    const int kbw = j>>5, qw = (j>>3)&3, jw = j&7;
    __syncthreads();

    int p = 0;
#pragma unroll 1
    for (int t=0;t<OUTL;t++){
        // ---- layer 0: read h0[p], write h0[1-p] (no pre-barrier) ----
        v4f acc[4];
#pragma unroll
        for (int g=0;g<4;g++){
            v4f t4 = {rgi[g][0], rgi[g][1], rgi[g][2], rgi[g][3]};
            acc[g] = t4;
        }
#pragma unroll
        for (int kb=0;kb<4;kb++){
            v8s ah = *(const v8s*)&h0hi[p][kb*512 + l*8];
            v8s al = *(const v8s*)&h0lo[p][kb*512 + l*8];
#pragma unroll
            for (int g=0;g<4;g++){
                v8s bfr = as_v8s(sW0[((g*8+w)*4 + kb)*64 + l]);
                acc[g] = MFMA16(ah, bfr, acc[g]);
                acc[g] = MFMA16(al, bfr, acc[g]);
            }
        }
#pragma unroll
        for (int i=0;i<4;i++){
            c0[i] = fsig(acc[1][i])*c0[i] + fsig(acc[0][i])*ftanh(acc[2][i]);
            float hn = fsig(acc[3][i])*ftanh(c0[i]);
            int off = kbw*512 + (qw*16 + q*4 + i)*8 + jw;
            unsigned short h = f2bf(hn);
            h0hi[1-p][off] = h;
            h0lo[1-p][off] = f2bf(hn - bf2f(h));
        }
        __syncthreads();   // B1: h0[1-p] visible

        // ---- layer 1: read h0[1-p] + h1 ----
        v4f a1[4];
#pragma unroll
        for (int g=0;g<4;g++){ v4f t4={b1[g],b1[g],b1[g],b1[g]}; a1[g]=t4; }
#pragma unroll
        for (int kb=0;kb<8;kb++){
            const unsigned short* hb = (kb<4) ? h0hi[1-p] : h1hi;
            const unsigned short* lb = (kb<4) ? h0lo[1-p] : h1lo;
            int kk = kb & 3;
            v8s ah = *(const v8s*)&hb[kk*512 + l*8];
            v8s al = *(const v8s*)&lb[kk*512 + l*8];
#pragma unroll
            for (int g=0;g<4;g++){
                a1[g] = MFMA16(ah, as_v8s(W1r[g*8+kb]), a1[g]);
                a1[g] = MFMA16(al, as_v8s(W1r[g*8+kb]), a1[g]);
            }
        }
        float h1new[4];
#pragma unroll
        for (int i=0;i<4;i++){
            c1[i] = fsig(a1[1][i])*c1[i] + fsig(a1[0][i])*ftanh(a1[2][i]);
            h1new[i] = fsig(a1[3][i])*ftanh(c1[i]);
        }
        __syncthreads();   // B2: all h1 reads done
#pragma unroll
        for (int i=0;i<4;i++){
            int off = kbw*512 + (qw*16 + q*4 + i)*8 + jw;
            unsigned short h = f2bf(h1new[i]);
            h1hi[off] = h;
            h1lo[off] = f2bf(h1new[i] - bf2f(h));
            sh1b[(q*4+i)*136 + j] = h;
        }
        __syncthreads();   // B3: h1 + sh1b visible

        // ---- output projection (bf16 h1, Wop from global/L2) ----
        if (tid < 32){
            int m = tid>>1, o = tid&1;
            const float* wv = Wop + o*128;
            float s = 0.f;
#pragma unroll 8
            for (int k=0;k<128;k+=4){
                short4 hv = *(const short4*)&sh1b[m*136 + k];
                s += bf2f((unsigned short)hv.x)*wv[k]   + bf2f((unsigned short)hv.y)*wv[k+1]
                   + bf2f((unsigned short)hv.z)*wv[k+2] + bf2f((unsigned short)hv.w)*wv[k+3];
            }
            outp[(size_t)(b0+m)*(OUTL*2) + t*2 + o] = s + (o ? bo1 : bo0);
        }
        p ^= 1;
    }
}

extern "C" void kernel_launch(void* const* d_in, const int* in_sizes, int n_in,
                              void* d_out, int out_size, void* d_ws, size_t ws_size,
                              hipStream_t stream)
{
    const float* x    = (const float*)d_in[0];
    const int*   ei   = (const int*)d_in[1];
    const float* ea   = (const float*)d_in[2];
    const int*   tgt  = (const int*)d_in[3];
    const float* Wip  = (const float*)d_in[4];
    const float* bip  = (const float*)d_in[5];
    const float* gWih = (const float*)d_in[6];
    const float* gWhh = (const float*)d_in[7];
    const float* gbih = (const float*)d_in[8];
    const float* gbhh = (const float*)d_in[9];
    const float* Wdyn = (const float*)d_in[10];
    const float* bdyn = (const float*)d_in[11];
    const float* c1Wf=(const float*)d_in[12]; const float* c1bf=(const float*)d_in[13];
    const float* c1Ws=(const float*)d_in[14]; const float* c1bs=(const float*)d_in[15];
    const float* c1g =(const float*)d_in[16]; const float* c1b =(const float*)d_in[17];
    const float* c1m =(const float*)d_in[18]; const float* c1v =(const float*)d_in[19];
    const float* c2Wf=(const float*)d_in[20]; const float* c2bf=(const float*)d_in[21];
    const float* c2Ws=(const float*)d_in[22]; const float* c2bs=(const float*)d_in[23];
    const float* c2g =(const float*)d_in[24]; const float* c2b =(const float*)d_in[25];
    const float* c2m =(const float*)d_in[26]; const float* c2v =(const float*)d_in[27];
    const float* Wn  =(const float*)d_in[28]; const float* bn_ =(const float*)d_in[29];
    const float* l0Wih=(const float*)d_in[30]; const float* l0Whh=(const float*)d_in[31];
    const float* l0bih=(const float*)d_in[32]; const float* l0bhh=(const float*)d_in[33];
    const float* l1Wih=(const float*)d_in[34]; const float* l1Whh=(const float*)d_in[35];
    const float* l1bih=(const float*)d_in[36]; const float* l1bhh=(const float*)d_in[37];
    const float* Wop =(const float*)d_in[38]; const float* bop=(const float*)d_in[39];

    float* ws = (float*)d_ws;
    size_t o = 0;
    float* hist = ws + o; o += (size_t)NN*ENC;
    float* f1   = ws + o; o += (size_t)NN*ENC;
    float* f2   = ws + o; o += (size_t)NN*ENC;
    float* Af   = ws + o; o += (size_t)NN*ENC;
    float* Bf   = ws + o; o += (size_t)NN*ENC;
    float* As   = ws + o; o += (size_t)NN*ENC;
    float* Bs   = ws + o; o += (size_t)NN*ENC;
    float* enc  = ws + o; o += (size_t)BB*2*ENC;
    float* gi0  = ws + o; o += (size_t)BB*4*DEC;
    unsigned short* pWih  = (unsigned short*)(ws + o); o += (size_t)12*64*8/2;
    unsigned short* pWhh  = (unsigned short*)(ws + o); o += (size_t)24*64*8/2;
    unsigned short* pWdyn = (unsigned short*)(ws + o); o += (size_t)8*64*8/2;
    unsigned short* B0h = (unsigned short*)(ws + o); o += (size_t)32*4*64*8/2;
    unsigned short* B1h = (unsigned short*)(ws + o); o += (size_t)32*8*64*8/2;
    unsigned short* P1h = (unsigned short*)(ws + o); o += (size_t)2048*8/2;
    unsigned short* P1l = (unsigned short*)(ws + o); o += (size_t)2048*8/2;
    unsigned short* P2h = (unsigned short*)(ws + o); o += (size_t)2048*8/2;
    unsigned short* P2l = (unsigned short*)(ws + o); o += (size_t)2048*8/2;
    unsigned short* GIh = (unsigned short*)(ws + o); o += (size_t)8192*8/2;
    unsigned short* GIl = (unsigned short*)(ws + o); o += (size_t)8192*8/2;
    int* cnt    = (int*)(ws + o); o += NN;
    int* offv   = (int*)(ws + o); o += NN+1;
    int* curv   = (int*)(ws + o); o += NN;
    int* srcS   = (int*)(ws + o); o += EE;
    float2* eaS = (float2*)(ws + o); o += (size_t)2*EE;

    // --- all weight prep + cnt zero in one dispatch ---
    pack_all<<<(PACK_TOTAL+255)/256, 256, 0, stream>>>(
        gWih, gWhh, Wdyn, l0Whh, l1Wih, l1Whh, l0Wih,
        c1Wf, c1Ws, c2Wf, c2Ws,
        pWih, pWhh, pWdyn, B0h, B1h, P1h, P1l, P2h, P2l, GIh, GIl, cnt);

    // --- dst counting sort + edge pre-gather (reused by both convs) ---
    count_kernel<<<(EE+255)/256, 256, 0, stream>>>(ei, cnt);
    scan_kernel<<<1, 1024, 0, stream>>>(cnt, offv, curv);
    scatter_kernel<<<(EE+255)/256, 256, 0, stream>>>(ei, ea, curv, srcS, eaS);

    // --- history encoder (MFMA) ---
    encoder_mfma<<<NN/16, 128, 0, stream>>>(x, Wip, bip, pWih, pWhh, gbih, gbhh, pWdyn, bdyn, hist);

    // --- CGConv 1 ---
    proj_mfma<<<(NN+63)/64, 256, 0, stream>>>(hist, P1h, P1l, Af,Bf,As,Bs);
    cg_agg<<<(NN+3)/4, 256, 0, stream>>>(hist, srcS, eaS, offv,
                                         c1Wf,c1bf,c1Ws,c1bs, Af,Bf,As,Bs,
                                         c1g,c1b,c1m,c1v, f1);

    // --- CGConv 2 ---
    proj_mfma<<<(NN+63)/64, 256, 0, stream>>>(f1, P2h, P2l, Af,Bf,As,Bs);
    cg_agg<<<(NN+3)/4, 256, 0, stream>>>(f1, srcS, eaS, offv,
                                         c2Wf,c2bf,c2Ws,c2bs, Af,Bf,As,Bs,
                                         c2g,c2b,c2m,c2v, f2);

    // --- target encoding ---
    target_kernel<<<(BB+3)/4, 256, 0, stream>>>(hist, f2, tgt, Wn, bn_, enc);

    // --- LSTM decoder prep (MFMA gi0) ---
    gi0_mfma<<<BB/16, 512, 0, stream>>>(enc, GIh, GIl, l0bih, l0bhh, gi0);

    // --- LSTM decoder ---
    lstm_mfma<<<BB/LMB, 512, 0, stream>>>(gi0, B0h, B1h,
                                          l1bih, l1bhh, Wop, bop, (float*)d_out);
}

// Round 11
// 648.970 us; speedup vs baseline: 19.9620x; 1.1623x over previous
//
#include <hip/hip_runtime.h>
#include <math.h>

#define NN   50000
#define TT   16
#define EE   800000
#define BB   2000
#define EMBD 32
#define ENC  64
#define DEC  128
#define OUTL 25
#define BN_EPS 1e-5f

typedef short v8s __attribute__((ext_vector_type(8)));
typedef float v4f __attribute__((ext_vector_type(4)));
#define MFMA16(a,b,c) __builtin_amdgcn_mfma_f32_16x16x32_bf16((a),(b),(c),0,0,0)

__device__ __forceinline__ float lrelu(float v){ return v >= 0.f ? v : 0.1f*v; }
__device__ __forceinline__ float fsig(float v){ return __builtin_amdgcn_rcpf(1.f + __expf(-v)); }
__device__ __forceinline__ float ftanh(float v){ return 2.f*__builtin_amdgcn_rcpf(1.f + __expf(-2.f*v)) - 1.f; }
__device__ __forceinline__ float fsoftplus(float v){
    return v > 15.f ? v : __logf(1.f + __expf(v));
}
__device__ __forceinline__ void fma44(float4& a, float4 w, float4 h){
    a.x += w.x*h.x; a.y += w.y*h.y; a.z += w.z*h.z; a.w += w.w*h.w;
}
__device__ __forceinline__ float hsum(float4 a){ return (a.x+a.y)+(a.z+a.w); }

__device__ __forceinline__ unsigned short f2bf(float f){
    unsigned u = __float_as_uint(f);
    u = u + 0x7FFFu + ((u>>16)&1u);
    return (unsigned short)(u>>16);
}
__device__ __forceinline__ float bf2f(unsigned short s){ return __uint_as_float(((unsigned)s)<<16); }

__device__ __forceinline__ v8s as_v8s(int4 v){
    union { int4 i; v8s s; } u; u.i = v; return u.s;
}

__device__ __forceinline__ void cvt8(const float* p, v8s& hi, v8s& lo){
    float4 a0 = *(const float4*)p;
    float4 a1 = *(const float4*)(p+4);
    float av[8] = {a0.x,a0.y,a0.z,a0.w,a1.x,a1.y,a1.z,a1.w};
#pragma unroll
    for (int j=0;j<8;j++){
        unsigned short h = f2bf(av[j]);
        hi[j] = (short)h;
        lo[j] = (short)f2bf(av[j] - bf2f(h));
    }
}
// reconstruct hi+lo, lrelu, re-split
__device__ __forceinline__ void lrelu_resplit(v8s hh, v8s hl, v8s& oh, v8s& ol){
#pragma unroll
    for (int j=0;j<8;j++){
        float v = bf2f((unsigned short)hh[j]) + bf2f((unsigned short)hl[j]);
        float a = lrelu(v);
        unsigned short h = f2bf(a);
        oh[j] = (short)h;
        ol[j] = (short)f2bf(a - bf2f(h));
    }
}

// ---------------- fused packing helpers ----------------
__device__ __forceinline__ void pf_item(const float* W, int K, int KB, int i,
                                        unsigned short* out){
    int l = i & 63, fb = i >> 6;
    int kb = fb % KB, nt = fb / KB;
    int n = nt*16 + (l&15);
    int k0 = kb*32 + ((l>>4)*8);
#pragma unroll
    for (int j=0;j<8;j++) out[i*8+j] = f2bf(W[(size_t)n*K + k0 + j]);
}
__device__ __forceinline__ void phl_item(const float* W, int K, int KB, int i,
                                         unsigned short* hi, unsigned short* lo){
    int l = i & 63, fb = i >> 6;
    int kb = fb % KB, nt = fb / KB;
    int n = nt*16 + (l&15);
    int k0 = kb*32 + ((l>>4)*8);
#pragma unroll
    for (int j=0;j<8;j++){
        float v = W[(size_t)n*K + k0 + j];
        unsigned short h = f2bf(v);
        hi[i*8+j] = h;
        lo[i*8+j] = f2bf(v - bf2f(h));
    }
}
__device__ __forceinline__ void pcat_item(const float* Wa, const float* Wb,
                                          int K1, int K, int KB, int i,
                                          unsigned short* out){
    int l = i & 63, fb = i >> 6;
    int kb = fb % KB, nt = fb / KB;
    int n = nt*16 + (l&15);
    int k0 = kb*32 + ((l>>4)*8);
#pragma unroll
    for (int j=0;j<8;j++){
        int k = k0 + j;
        float v = (k < K1) ? Wa[(size_t)n*K1 + k] : Wb[(size_t)n*(K-K1) + (k-K1)];
        out[i*8+j] = f2bf(v);
    }
}
__device__ __forceinline__ void pproj_item(const float* Wf, const float* Ws, int i,
                                           unsigned short* hi, unsigned short* lo){
    int l = i & 63, fb = i >> 6;
    int kb = fb & 1, nt = fb >> 1;
    int n = nt*16 + (l&15);
    int d = n >> 6, c = n & 63;
    const float* W = (d < 2) ? Wf : Ws;
    int k0 = (d&1)*64 + kb*32 + ((l>>4)*8);
#pragma unroll
    for (int j=0;j<8;j++){
        float v = W[c*130 + k0 + j];
        unsigned short h = f2bf(v);
        hi[i*8+j] = h;
        lo[i*8+j] = f2bf(v - bf2f(h));
    }
}

// ---------------- all weight prep in ONE dispatch ----------------
__global__ void pack_all(
    const float* __restrict__ gWih, const float* __restrict__ gWhh,
    const float* __restrict__ Wdyn,
    const float* __restrict__ l0Whh, const float* __restrict__ l1Wih,
    const float* __restrict__ l1Whh, const float* __restrict__ l0Wih,
    const float* __restrict__ c1Wf, const float* __restrict__ c1Ws,
    const float* __restrict__ c2Wf, const float* __restrict__ c2Ws,
    unsigned short* __restrict__ pWih, unsigned short* __restrict__ pWhh,
    unsigned short* __restrict__ pWdyn,
    unsigned short* __restrict__ B0h, unsigned short* __restrict__ B1h,
    unsigned short* __restrict__ P1h, unsigned short* __restrict__ P1l,
    unsigned short* __restrict__ P2h, unsigned short* __restrict__ P2l,
    unsigned short* __restrict__ GIh, unsigned short* __restrict__ GIl,
    int* __restrict__ cnt, int* __restrict__ gtot)
{
    int i = blockIdx.x*256 + threadIdx.x;
    if (i < 768){ pf_item(gWih, 32, 1, i, pWih); return; }   i -= 768;
    if (i < 1536){ pf_item(gWhh, 64, 2, i, pWhh); return; }  i -= 1536;
    if (i < 512){ pf_item(Wdyn, 64, 2, i, pWdyn); return; }  i -= 512;
    if (i < 8192){ pcat_item(l0Whh, l0Whh, 128, 128, 4, i, B0h); return; } i -= 8192;
    if (i < 16384){ pcat_item(l1Wih, l1Whh, 128, 256, 8, i, B1h); return; } i -= 16384;
    if (i < 2048){ pproj_item(c1Wf, c1Ws, i, P1h, P1l); return; } i -= 2048;
    if (i < 2048){ pproj_item(c2Wf, c2Ws, i, P2h, P2l); return; } i -= 2048;
    if (i < 8192){ phl_item(l0Wih, 128, 4, i, GIh, GIl); return; } i -= 8192;
    if (i < NN){ cnt[i] = 0; return; } i -= NN;
    if (i < 1){ gtot[0] = 0; return; }
}
#define PACK_TOTAL (768+1536+512+8192+16384+2048+2048+8192+NN+1)

// ---------------- GRU encoder v4: MFMA + frag-resident state (unchanged) ----------------
__global__ __launch_bounds__(128) void encoder_mfma(
    const float* __restrict__ x,
    const float* __restrict__ Wip, const float* __restrict__ bip,
    const unsigned short* __restrict__ pWih,
    const unsigned short* __restrict__ pWhh,
    const float* __restrict__ bih, const float* __restrict__ bhh,
    const unsigned short* __restrict__ pWdyn,
    const float* __restrict__ bdyn,
    float* __restrict__ hist)
{
    __shared__ float sxl[512];
    __shared__ unsigned short efh[512], efl[512];      // emb A-frags (kb=0)
    __shared__ unsigned short hfh[2*512], hfl[2*512];  // h A-frags (kb=0,1)
    const int tid = threadIdx.x;
    const int l   = tid & 63;
    const int w   = tid >> 6;
    const int ln  = l & 15, q = l >> 4;
    const int blk = blockIdx.x;

    ((float4*)sxl)[tid] = ((const float4*)x)[(size_t)blk*128 + tid];
    for (int i=tid;i<2*512;i+=128){ hfh[i]=0; hfl[i]=0; }

    const int ek = tid & 31;
    const float w0 = Wip[2*ek], w1 = Wip[2*ek+1], bk = bip[ek];
    const int em0 = tid >> 5;
    const int eoffb = (16*(ek>>3))*8 + (ek&7);

    float bR[2], bZ[2], bNI[2], bNH[2];
    float hprev[2][4];
#pragma unroll
    for (int u=0;u<2;u++){
        int g = 2*w + u;
        int c = g*16 + ln;
        bR[u]  = bih[c]       + bhh[c];
        bZ[u]  = bih[64 + c]  + bhh[64 + c];
        bNI[u] = bih[128 + c];
        bNH[u] = bhh[128 + c];
        hprev[u][0]=0.f; hprev[u][1]=0.f; hprev[u][2]=0.f; hprev[u][3]=0.f;
    }
    const v8s* FIH = (const v8s*)pWih;
    const v8s* FHH = (const v8s*)pWhh;
    const v8s* FDY = (const v8s*)pWdyn;
    __syncthreads();

#pragma unroll 1
    for (int t=0;t<TT;t++){
#pragma unroll
        for (int r=0;r<4;r++){
            int m = em0 + r*4;
            float e = lrelu(w0*sxl[m*32 + 2*t] + w1*sxl[m*32 + 2*t + 1] + bk);
            unsigned short h_ = f2bf(e);
            int off = eoffb + m*8;
            efh[off] = h_;
            efl[off] = f2bf(e - bf2f(h_));
        }
        __syncthreads();                       // BA: frags ready
        v8s eh = *(const v8s*)&efh[l*8];
        v8s el = *(const v8s*)&efl[l*8];
        v8s h0h = *(const v8s*)&hfh[l*8];
        v8s h0l = *(const v8s*)&hfl[l*8];
        v8s h1h = *(const v8s*)&hfh[512 + l*8];
        v8s h1l = *(const v8s*)&hfl[512 + l*8];
        __syncthreads();                       // BB: reads done, writes may begin
#pragma unroll
        for (int u=0;u<2;u++){
            int g = 2*w + u;
            v4f aR = {bR[u],bR[u],bR[u],bR[u]};
            v4f aZ = {bZ[u],bZ[u],bZ[u],bZ[u]};
            v4f aNI= {bNI[u],bNI[u],bNI[u],bNI[u]};
            v4f aNH= {bNH[u],bNH[u],bNH[u],bNH[u]};
            v8s b;
            b = FIH[(g   )*64 + l];   aR = MFMA16(eh,b,aR);  aR = MFMA16(el,b,aR);
            b = FHH[((g)*2+0)*64+l];  aR = MFMA16(h0h,b,aR); aR = MFMA16(h0l,b,aR);
            b = FHH[((g)*2+1)*64+l];  aR = MFMA16(h1h,b,aR); aR = MFMA16(h1l,b,aR);
            b = FIH[(4+g )*64 + l];   aZ = MFMA16(eh,b,aZ);  aZ = MFMA16(el,b,aZ);
            b = FHH[((4+g)*2+0)*64+l];aZ = MFMA16(h0h,b,aZ); aZ = MFMA16(h0l,b,aZ);
            b = FHH[((4+g)*2+1)*64+l];aZ = MFMA16(h1h,b,aZ); aZ = MFMA16(h1l,b,aZ);
            b = FIH[(8+g )*64 + l];   aNI= MFMA16(eh,b,aNI); aNI= MFMA16(el,b,aNI);
            b = FHH[((8+g)*2+0)*64+l];aNH= MFMA16(h0h,b,aNH);aNH= MFMA16(h0l,b,aNH);
            b = FHH[((8+g)*2+1)*64+l];aNH= MFMA16(h1h,b,aNH);aNH= MFMA16(h1l,b,aNH);
#pragma unroll
            for (int i=0;i<4;i++){
                float r_ = fsig(aR[i]);
                float z_ = fsig(aZ[i]);
                float nn_ = ftanh(aNI[i] + r_*aNH[i]);
                float hn = (1.f - z_)*nn_ + z_*hprev[u][i];
                hprev[u][i] = hn;
                int row = q*4 + i, col = g*16 + ln;
                int off = (col>>5)*512 + (16*((col&31)>>3) + row)*8 + (col&7);
                unsigned short hh_ = f2bf(hn);
                hfh[off] = hh_;
                hfl[off] = f2bf(hn - bf2f(hh_));
            }
        }
    }
    __syncthreads();
    {
        v8s a0h,a0l,a1h,a1l;
        lrelu_resplit(*(const v8s*)&hfh[l*8],       *(const v8s*)&hfl[l*8],       a0h, a0l);
        lrelu_resplit(*(const v8s*)&hfh[512 + l*8], *(const v8s*)&hfl[512 + l*8], a1h, a1l);
#pragma unroll
        for (int u=0;u<2;u++){
            int nt = 2*w + u;
            float bb = bdyn[nt*16 + ln];
            v4f acc = {bb,bb,bb,bb};
            v8s b;
            b = FDY[(nt*2+0)*64 + l]; acc = MFMA16(a0h,b,acc); acc = MFMA16(a0l,b,acc);
            b = FDY[(nt*2+1)*64 + l]; acc = MFMA16(a1h,b,acc); acc = MFMA16(a1l,b,acc);
#pragma unroll
            for (int i=0;i<4;i++){
                hist[(size_t)(blk*16 + q*4 + i)*64 + nt*16 + ln] = lrelu(acc[i]);
            }
        }
    }
}

// ---------------- CGConv projections: MFMA (unchanged) ----------------
__global__ __launch_bounds__(256) void proj_mfma(
    const float* __restrict__ xin,
    const unsigned short* __restrict__ Bh, const unsigned short* __restrict__ Bl,
    float* __restrict__ Af, float* __restrict__ Bf,
    float* __restrict__ As, float* __restrict__ Bs)
{
    __shared__ float sx[64*68];
    const int tid = threadIdx.x;
    const int l = tid & 63;
    const int w = tid >> 6;
    const int ln = l & 15, q = l >> 4;
    const int n0 = blockIdx.x*64;

    for (int i=tid;i<64*16;i+=256){
        int nn = i>>4, f4 = i&15;
        float4 v = {0.f,0.f,0.f,0.f};
        if (n0+nn < NN) v = ((const float4*)(xin + (size_t)(n0+nn)*64))[f4];
        *(float4*)&sx[nn*68 + f4*4] = v;
    }
    __syncthreads();

    v8s ah0,al0,ah1,al1;
    cvt8(&sx[(w*16+ln)*68 +      q*8], ah0, al0);
    cvt8(&sx[(w*16+ln)*68 + 32 + q*8], ah1, al1);

    const v8s* FH = (const v8s*)Bh;
    const v8s* FL = (const v8s*)Bl;
#pragma unroll 1
    for (int nt=0; nt<16; nt++){
        v8s bh0 = FH[(nt*2+0)*64 + l], bl0 = FL[(nt*2+0)*64 + l];
        v8s bh1 = FH[(nt*2+1)*64 + l], bl1 = FL[(nt*2+1)*64 + l];
        v4f acc = {0.f,0.f,0.f,0.f};
        acc = MFMA16(ah0,bh0,acc); acc = MFMA16(al0,bh0,acc); acc = MFMA16(ah0,bl0,acc);
        acc = MFMA16(ah1,bh1,acc); acc = MFMA16(al1,bh1,acc); acc = MFMA16(ah1,bl1,acc);
        int d = nt >> 2, col = (nt&3)*16 + ln;
        float* op = (d==0) ? Af : (d==1) ? Bf : (d==2) ? As : Bs;
#pragma unroll
        for (int i=0;i<4;i++){
            int node = n0 + w*16 + q*4 + i;
            if (node < NN) op[(size_t)node*64 + col] = acc[i];
        }
    }
}

// ---------------- dst segment build: histogram + atomic alloc + scatter ----------------
// R10 post-mortem: single-block prefix scan was the LARGEST dispatch (125us,
// 0.15% occupancy). cg_agg only needs per-node contiguous segments — order
// across nodes is irrelevant — so allocate segment starts with one global
// atomicAdd per node (fully parallel, ~4us).
__global__ void count_kernel(const int* __restrict__ ei, int* __restrict__ cnt){
    int e = blockIdx.x*256 + threadIdx.x;
    if (e < EE) atomicAdd(&cnt[ei[EE+e]], 1);
}

__global__ void alloc_kernel(const int* __restrict__ cnt, int* __restrict__ gtot,
                             int* __restrict__ off, int* __restrict__ cur){
    int n = blockIdx.x*256 + threadIdx.x;
    if (n >= NN) return;
    int c = cnt[n];
    int s = atomicAdd(gtot, c);
    off[n] = s;
    cur[n] = s;
}

// scatter + pre-gather src & edge_attr into dst-sorted order
__global__ void scatter_kernel(const int* __restrict__ ei, const float* __restrict__ ea,
                               int* __restrict__ cur,
                               int* __restrict__ srcS, float2* __restrict__ eaS){
    int e = blockIdx.x*256 + threadIdx.x;
    if (e >= EE) return;
    int d = ei[EE+e];
    int p = atomicAdd(&cur[d], 1);
    srcS[p] = ei[e];
    float2 v; v.x = ea[2*(size_t)e]; v.y = ea[2*(size_t)e+1];
    eaS[p] = v;
}

// ---------------- CGConv aggregate (segment = off[n] .. off[n]+cnt[n]) ----------------
__global__ __launch_bounds__(256) void cg_agg(
    const float* __restrict__ xin,
    const int* __restrict__ srcS, const float2* __restrict__ eaS,
    const int* __restrict__ off, const int* __restrict__ cnt,
    const float* __restrict__ Wf, const float* __restrict__ bf,
    const float* __restrict__ Ws, const float* __restrict__ bs,
    const float* __restrict__ Af, const float* __restrict__ Bf,
    const float* __restrict__ As, const float* __restrict__ Bs,
    const float* __restrict__ gamma, const float* __restrict__ beta,
    const float* __restrict__ mean, const float* __restrict__ var,
    float* __restrict__ outp)
{
    const int tid = threadIdx.x;
    const int c = tid & 63, wid = tid >> 6;
    const int n = blockIdx.x*4 + wid;
    if (n >= NN) return;

    const float wf0 = Wf[c*130+128], wf1 = Wf[c*130+129], bfc = bf[c];
    const float ws0 = Ws[c*130+128], ws1 = Ws[c*130+129], bsc = bs[c];
    const float afd = Af[(size_t)n*64+c] + bfc, asd = As[(size_t)n*64+c] + bsc;
    const float* Bfc = Bf + c;
    const float* Bsc = Bs + c;

    float acc = 0.f;
    int i = off[n];
    const int i1 = i + cnt[n];
#pragma unroll 1
    for (; i+1 < i1; i += 2){
        int s0 = srcS[i], s1 = srcS[i+1];
        float2 e0 = eaS[i], e1 = eaS[i+1];
        float bf0v = Bfc[(size_t)s0*64], bs0v = Bsc[(size_t)s0*64];
        float bf1v = Bfc[(size_t)s1*64], bs1v = Bsc[(size_t)s1*64];
        float gf0 = afd + bf0v + wf0*e0.x + wf1*e0.y;
        float gs0 = asd + bs0v + ws0*e0.x + ws1*e0.y;
        float gf1 = afd + bf1v + wf0*e1.x + wf1*e1.y;
        float gs1 = asd + bs1v + ws0*e1.x + ws1*e1.y;
        acc += fsig(gf0)*fsoftplus(gs0);
        acc += fsig(gf1)*fsoftplus(gs1);
    }
    if (i < i1){
        int s0 = srcS[i];
        float2 e0 = eaS[i];
        float gf = afd + Bfc[(size_t)s0*64] + wf0*e0.x + wf1*e0.y;
        float gs = asd + Bsc[(size_t)s0*64] + ws0*e0.x + ws1*e0.y;
        acc += fsig(gf)*fsoftplus(gs);
    }
    float bn = (acc - mean[c])*rsqrtf(var[c]+BN_EPS)*gamma[c] + beta[c];
    outp[(size_t)n*64+c] = xin[(size_t)n*64+c] + bn;
}

// ---------------- target gather + nbrs linear + concat (unchanged) ----------------
__global__ __launch_bounds__(256) void target_kernel(
    const float* __restrict__ hist, const float* __restrict__ f2,
    const int* __restrict__ tgt,
    const float* __restrict__ Wn, const float* __restrict__ bn_,
    float* __restrict__ enc)
{
    const int tid=threadIdx.x;
    const int c = tid&63, q = tid>>6;
    const int b = blockIdx.x*4 + q;
    if (b>=BB) return;
    const int n = tgt[b];
    float a = bn_[c];
#pragma unroll
    for (int k=0;k<ENC;k++) a += Wn[c*64+k]*f2[(size_t)n*64+k];
    enc[(size_t)b*128 + 64 + c] = lrelu(a);
    enc[(size_t)b*128 + c]      = hist[(size_t)n*64+c];
}

// ---------------- gi0 via MFMA (unchanged) ----------------
__global__ __launch_bounds__(512) void gi0_mfma(
    const float* __restrict__ enc,
    const unsigned short* __restrict__ GIh, const unsigned short* __restrict__ GIl,
    const float* __restrict__ bih0, const float* __restrict__ bhh0,
    float* __restrict__ gi0)
{
    __shared__ float senc[16*132];
    const int tid = threadIdx.x;
    const int l = tid & 63;
    const int w = tid >> 6;
    const int ln = l & 15, q = l >> 4;
    const int b0 = blockIdx.x*16;

    for (int i=tid;i<16*32;i+=512){
        int row = i>>5, f4 = i&31;
        *(float4*)&senc[row*132 + f4*4] = ((const float4*)(enc + (size_t)(b0+row)*128))[f4];
    }
    __syncthreads();

    v8s ah[4], al[4];
#pragma unroll
    for (int kb=0;kb<4;kb++) cvt8(&senc[ln*132 + kb*32 + q*8], ah[kb], al[kb]);

    const v8s* FH = (const v8s*)GIh;
    const v8s* FL = (const v8s*)GIl;
#pragma unroll
    for (int u=0;u<4;u++){
        int nt = w*4 + u;
        int col = nt*16 + ln;
        float bb = bih0[col] + bhh0[col];
        v4f acc = {bb,bb,bb,bb};
#pragma unroll
        for (int kb=0;kb<4;kb++){
            v8s bh = FH[(nt*4+kb)*64 + l];
            v8s bl = FL[(nt*4+kb)*64 + l];
            acc = MFMA16(ah[kb],bh,acc); acc = MFMA16(al[kb],bh,acc); acc = MFMA16(ah[kb],bl,acc);
        }
#pragma unroll
        for (int i=0;i<4;i++)
            gi0[(size_t)(b0 + q*4 + i)*512 + col] = acc[i];
    }
}

// ---------------- 2-layer LSTM decoder v6 (unchanged) ----------------
#define LMB 16
__global__ __launch_bounds__(512)
__attribute__((amdgpu_waves_per_eu(2,2)))
void lstm_mfma(
    const float* __restrict__ gi0,
    const unsigned short* __restrict__ B0h,
    const unsigned short* __restrict__ B1h,
    const float* __restrict__ bih1, const float* __restrict__ bhh1,
    const float* __restrict__ Wop, const float* __restrict__ bop,
    float* __restrict__ outp)
{
    __shared__ int4 sW0[32*4*64];                       // 128 KB
    __shared__ unsigned short h0hi[2][4*512], h0lo[2][4*512];   // 16 KB
    __shared__ unsigned short h1hi[4*512], h1lo[4*512];         // 8 KB
    __shared__ unsigned short sh1b[16*136];                     // 4.25 KB bf16 h1
    const int tid = threadIdx.x;
    const int l = tid & 63;
    const int w = tid >> 6;
    const int c = l & 15;
    const int q = l >> 4;
    const int j = w*16 + c;
    const int b0 = blockIdx.x*LMB;

    {
        const int4* F0 = (const int4*)B0h;
        for (int i=tid;i<32*4*64;i+=512) sW0[i] = F0[i];
    }
    for (int i=tid;i<4*512;i+=512){
        h0hi[0][i]=0; h0lo[0][i]=0; h0hi[1][i]=0; h0lo[1][i]=0;
        h1hi[i]=0; h1lo[i]=0;
    }

    int4 W1r[32];
    {
        const int4* F1 = (const int4*)B1h;
#pragma unroll
        for (int g=0;g<4;g++)
#pragma unroll
            for (int kb=0;kb<8;kb++) W1r[g*8+kb] = F1[((g*8+w)*8 + kb)*64 + l];
#pragma unroll
        for (int i=0;i<32;i++)
            asm volatile("" : "+v"(W1r[i].x), "+v"(W1r[i].y), "+v"(W1r[i].z), "+v"(W1r[i].w));
    }

    float rgi[4][4];
#pragma unroll
    for (int g=0;g<4;g++)
#pragma unroll
        for (int i=0;i<4;i++)
            rgi[g][i] = gi0[(size_t)(b0 + q*4 + i)*512 + g*128 + j];

    float b1[4];
#pragma unroll
    for (int g=0;g<4;g++) b1[g] = bih1[g*128+j] + bhh1[g*128+j];
    float c0[4] = {0,0,0,0}, c1[4] = {0,0,0,0};
    const float bo0 = bop[0], bo1 = bop[1];
    const int kbw = j>>5, qw = (j>>3)&3, jw = j&7;
    __syncthreads();

    int p = 0;
#pragma unroll 1
    for (int t=0;t<OUTL;t++){
        // ---- layer 0: read h0[p], write h0[1-p] (no pre-barrier) ----
        v4f acc[4];
#pragma unroll
        for (int g=0;g<4;g++){
            v4f t4 = {rgi[g][0], rgi[g][1], rgi[g][2], rgi[g][3]};
            acc[g] = t4;
        }
#pragma unroll
        for (int kb=0;kb<4;kb++){
            v8s ah = *(const v8s*)&h0hi[p][kb*512 + l*8];
            v8s al = *(const v8s*)&h0lo[p][kb*512 + l*8];
#pragma unroll
            for (int g=0;g<4;g++){
                v8s bfr = as_v8s(sW0[((g*8+w)*4 + kb)*64 + l]);
                acc[g] = MFMA16(ah, bfr, acc[g]);
                acc[g] = MFMA16(al, bfr, acc[g]);
            }
        }
#pragma unroll
        for (int i=0;i<4;i++){
            c0[i] = fsig(acc[1][i])*c0[i] + fsig(acc[0][i])*ftanh(acc[2][i]);
            float hn = fsig(acc[3][i])*ftanh(c0[i]);
            int off = kbw*512 + (qw*16 + q*4 + i)*8 + jw;
            unsigned short h = f2bf(hn);
            h0hi[1-p][off] = h;
            h0lo[1-p][off] = f2bf(hn - bf2f(h));
        }
        __syncthreads();   // B1: h0[1-p] visible

        // ---- layer 1: read h0[1-p] + h1 ----
        v4f a1[4];
#pragma unroll
        for (int g=0;g<4;g++){ v4f t4={b1[g],b1[g],b1[g],b1[g]}; a1[g]=t4; }
#pragma unroll
        for (int kb=0;kb<8;kb++){
            const unsigned short* hb = (kb<4) ? h0hi[1-p] : h1hi;
            const unsigned short* lb = (kb<4) ? h0lo[1-p] : h1lo;
            int kk = kb & 3;
            v8s ah = *(const v8s*)&hb[kk*512 + l*8];
            v8s al = *(const v8s*)&lb[kk*512 + l*8];
#pragma unroll
            for (int g=0;g<4;g++){
                a1[g] = MFMA16(ah, as_v8s(W1r[g*8+kb]), a1[g]);
                a1[g] = MFMA16(al, as_v8s(W1r[g*8+kb]), a1[g]);
            }
        }
        float h1new[4];
#pragma unroll
        for (int i=0;i<4;i++){
            c1[i] = fsig(a1[1][i])*c1[i] + fsig(a1[0][i])*ftanh(a1[2][i]);
            h1new[i] = fsig(a1[3][i])*ftanh(c1[i]);
        }
        __syncthreads();   // B2: all h1 reads done
#pragma unroll
        for (int i=0;i<4;i++){
            int off = kbw*512 + (qw*16 + q*4 + i)*8 + jw;
            unsigned short h = f2bf(h1new[i]);
            h1hi[off] = h;
            h1lo[off] = f2bf(h1new[i] - bf2f(h));
            sh1b[(q*4+i)*136 + j] = h;
        }
        __syncthreads();   // B3: h1 + sh1b visible

        // ---- output projection (bf16 h1, Wop from global/L2) ----
        if (tid < 32){
            int m = tid>>1, o = tid&1;
            const float* wv = Wop + o*128;
            float s = 0.f;
#pragma unroll 8
            for (int k=0;k<128;k+=4){
                short4 hv = *(const short4*)&sh1b[m*136 + k];
                s += bf2f((unsigned short)hv.x)*wv[k]   + bf2f((unsigned short)hv.y)*wv[k+1]
                   + bf2f((unsigned short)hv.z)*wv[k+2] + bf2f((unsigned short)hv.w)*wv[k+3];
            }
            outp[(size_t)(b0+m)*(OUTL*2) + t*2 + o] = s + (o ? bo1 : bo0);
        }
        p ^= 1;
    }
}

extern "C" void kernel_launch(void* const* d_in, const int* in_sizes, int n_in,
                              void* d_out, int out_size, void* d_ws, size_t ws_size,
                              hipStream_t stream)
{
    const float* x    = (const float*)d_in[0];
    const int*   ei   = (const int*)d_in[1];
    const float* ea   = (const float*)d_in[2];
    const int*   tgt  = (const int*)d_in[3];
    const float* Wip  = (const float*)d_in[4];
    const float* bip  = (const float*)d_in[5];
    const float* gWih = (const float*)d_in[6];
    const float* gWhh = (const float*)d_in[7];
    const float* gbih = (const float*)d_in[8];
    const float* gbhh = (const float*)d_in[9];
    const float* Wdyn = (const float*)d_in[10];
    const float* bdyn = (const float*)d_in[11];
    const float* c1Wf=(const float*)d_in[12]; const float* c1bf=(const float*)d_in[13];
    const float* c1Ws=(const float*)d_in[14]; const float* c1bs=(const float*)d_in[15];
    const float* c1g =(const float*)d_in[16]; const float* c1b =(const float*)d_in[17];
    const float* c1m =(const float*)d_in[18]; const float* c1v =(const float*)d_in[19];
    const float* c2Wf=(const float*)d_in[20]; const float* c2bf=(const float*)d_in[21];
    const float* c2Ws=(const float*)d_in[22]; const float* c2bs=(const float*)d_in[23];
    const float* c2g =(const float*)d_in[24]; const float* c2b =(const float*)d_in[25];
    const float* c2m =(const float*)d_in[26]; const float* c2v =(const float*)d_in[27];
    const float* Wn  =(const float*)d_in[28]; const float* bn_ =(const float*)d_in[29];
    const float* l0Wih=(const float*)d_in[30]; const float* l0Whh=(const float*)d_in[31];
    const float* l0bih=(const float*)d_in[32]; const float* l0bhh=(const float*)d_in[33];
    const float* l1Wih=(const float*)d_in[34]; const float* l1Whh=(const float*)d_in[35];
    const float* l1bih=(const float*)d_in[36]; const float* l1bhh=(const float*)d_in[37];
    const float* Wop =(const float*)d_in[38]; const float* bop=(const float*)d_in[39];

    float* ws = (float*)d_ws;
    size_t o = 0;
    float* hist = ws + o; o += (size_t)NN*ENC;
    float* f1   = ws + o; o += (size_t)NN*ENC;
    float* f2   = ws + o; o += (size_t)NN*ENC;
    float* Af   = ws + o; o += (size_t)NN*ENC;
    float* Bf   = ws + o; o += (size_t)NN*ENC;
    float* As   = ws + o; o += (size_t)NN*ENC;
    float* Bs   = ws + o; o += (size_t)NN*ENC;
    float* enc  = ws + o; o += (size_t)BB*2*ENC;
    float* gi0  = ws + o; o += (size_t)BB*4*DEC;
    unsigned short* pWih  = (unsigned short*)(ws + o); o += (size_t)12*64*8/2;
    unsigned short* pWhh  = (unsigned short*)(ws + o); o += (size_t)24*64*8/2;
    unsigned short* pWdyn = (unsigned short*)(ws + o); o += (size_t)8*64*8/2;
    unsigned short* B0h = (unsigned short*)(ws + o); o += (size_t)32*4*64*8/2;
    unsigned short* B1h = (unsigned short*)(ws + o); o += (size_t)32*8*64*8/2;
    unsigned short* P1h = (unsigned short*)(ws + o); o += (size_t)2048*8/2;
    unsigned short* P1l = (unsigned short*)(ws + o); o += (size_t)2048*8/2;
    unsigned short* P2h = (unsigned short*)(ws + o); o += (size_t)2048*8/2;
    unsigned short* P2l = (unsigned short*)(ws + o); o += (size_t)2048*8/2;
    unsigned short* GIh = (unsigned short*)(ws + o); o += (size_t)8192*8/2;
    unsigned short* GIl = (unsigned short*)(ws + o); o += (size_t)8192*8/2;
    int* cnt    = (int*)(ws + o); o += NN;
    int* offv   = (int*)(ws + o); o += NN+1;
    int* curv   = (int*)(ws + o); o += NN;
    int* gtot   = (int*)(ws + o); o += 1;
    int* srcS   = (int*)(ws + o); o += EE;
    float2* eaS = (float2*)(ws + o); o += (size_t)2*EE;

    // --- all weight prep + cnt/gtot zero in one dispatch ---
    pack_all<<<(PACK_TOTAL+255)/256, 256, 0, stream>>>(
        gWih, gWhh, Wdyn, l0Whh, l1Wih, l1Whh, l0Wih,
        c1Wf, c1Ws, c2Wf, c2Ws,
        pWih, pWhh, pWdyn, B0h, B1h, P1h, P1l, P2h, P2l, GIh, GIl, cnt, gtot);

    // --- dst segment build (order-free atomic allocation) ---
    count_kernel<<<(EE+255)/256, 256, 0, stream>>>(ei, cnt);
    alloc_kernel<<<(NN+255)/256, 256, 0, stream>>>(cnt, gtot, offv, curv);
    scatter_kernel<<<(EE+255)/256, 256, 0, stream>>>(ei, ea, curv, srcS, eaS);

    // --- history encoder (MFMA) ---
    encoder_mfma<<<NN/16, 128, 0, stream>>>(x, Wip, bip, pWih, pWhh, gbih, gbhh, pWdyn, bdyn, hist);

    // --- CGConv 1 ---
    proj_mfma<<<(NN+63)/64, 256, 0, stream>>>(hist, P1h, P1l, Af,Bf,As,Bs);
    cg_agg<<<(NN+3)/4, 256, 0, stream>>>(hist, srcS, eaS, offv, cnt,
                                         c1Wf,c1bf,c1Ws,c1bs, Af,Bf,As,Bs,
                                         c1g,c1b,c1m,c1v, f1);

    // --- CGConv 2 ---
    proj_mfma<<<(NN+63)/64, 256, 0, stream>>>(f1, P2h, P2l, Af,Bf,As,Bs);
    cg_agg<<<(NN+3)/4, 256, 0, stream>>>(f1, srcS, eaS, offv, cnt,
                                         c2Wf,c2bf,c2Ws,c2bs, Af,Bf,As,Bs,
                                         c2g,c2b,c2m,c2v, f2);

    // --- target encoding ---
    target_kernel<<<(BB+3)/4, 256, 0, stream>>>(hist, f2, tgt, Wn, bn_, enc);

    // --- LSTM decoder prep (MFMA gi0) ---
    gi0_mfma<<<BB/16, 512, 0, stream>>>(enc, GIh, GIl, l0bih, l0bhh, gi0);

    // --- LSTM decoder ---
    lstm_mfma<<<BB/LMB, 512, 0, stream>>>(gi0, B0h, B1h,
                                          l1bih, l1bhh, Wop, bop, (float*)d_out);
}

// Round 12
// 617.961 us; speedup vs baseline: 20.9637x; 1.0502x over previous
//
#include <hip/hip_runtime.h>
#include <math.h>

#define NN   50000
#define TT   16
#define EE   800000
#define BB   2000
#define EMBD 32
#define ENC  64
#define DEC  128
#define OUTL 25
#define BN_EPS 1e-5f

typedef short v8s __attribute__((ext_vector_type(8)));
typedef float v4f __attribute__((ext_vector_type(4)));
#define MFMA16(a,b,c) __builtin_amdgcn_mfma_f32_16x16x32_bf16((a),(b),(c),0,0,0)

__device__ __forceinline__ float lrelu(float v){ return v >= 0.f ? v : 0.1f*v; }
__device__ __forceinline__ float fsig(float v){ return __builtin_amdgcn_rcpf(1.f + __expf(-v)); }
__device__ __forceinline__ float ftanh(float v){ return 2.f*__builtin_amdgcn_rcpf(1.f + __expf(-2.f*v)) - 1.f; }
__device__ __forceinline__ float fsoftplus(float v){
    return v > 15.f ? v : __logf(1.f + __expf(v));
}
__device__ __forceinline__ float hsum(float4 a){ return (a.x+a.y)+(a.z+a.w); }

__device__ __forceinline__ unsigned short f2bf(float f){
    unsigned u = __float_as_uint(f);
    u = u + 0x7FFFu + ((u>>16)&1u);
    return (unsigned short)(u>>16);
}
__device__ __forceinline__ float bf2f(unsigned short s){ return __uint_as_float(((unsigned)s)<<16); }

__device__ __forceinline__ v8s as_v8s(int4 v){
    union { int4 i; v8s s; } u; u.i = v; return u.s;
}

__device__ __forceinline__ void cvt8(const float* p, v8s& hi, v8s& lo){
    float4 a0 = *(const float4*)p;
    float4 a1 = *(const float4*)(p+4);
    float av[8] = {a0.x,a0.y,a0.z,a0.w,a1.x,a1.y,a1.z,a1.w};
#pragma unroll
    for (int j=0;j<8;j++){
        unsigned short h = f2bf(av[j]);
        hi[j] = (short)h;
        lo[j] = (short)f2bf(av[j] - bf2f(h));
    }
}
// reconstruct hi+lo, lrelu, re-split
__device__ __forceinline__ void lrelu_resplit(v8s hh, v8s hl, v8s& oh, v8s& ol){
#pragma unroll
    for (int j=0;j<8;j++){
        float v = bf2f((unsigned short)hh[j]) + bf2f((unsigned short)hl[j]);
        float a = lrelu(v);
        unsigned short h = f2bf(a);
        oh[j] = (short)h;
        ol[j] = (short)f2bf(a - bf2f(h));
    }
}

// ---------------- fused packing helpers ----------------
__device__ __forceinline__ void pf_item(const float* W, int K, int KB, int i,
                                        unsigned short* out){
    int l = i & 63, fb = i >> 6;
    int kb = fb % KB, nt = fb / KB;
    int n = nt*16 + (l&15);
    int k0 = kb*32 + ((l>>4)*8);
#pragma unroll
    for (int j=0;j<8;j++) out[i*8+j] = f2bf(W[(size_t)n*K + k0 + j]);
}
__device__ __forceinline__ void phl_item(const float* W, int K, int KB, int i,
                                         unsigned short* hi, unsigned short* lo){
    int l = i & 63, fb = i >> 6;
    int kb = fb % KB, nt = fb / KB;
    int n = nt*16 + (l&15);
    int k0 = kb*32 + ((l>>4)*8);
#pragma unroll
    for (int j=0;j<8;j++){
        float v = W[(size_t)n*K + k0 + j];
        unsigned short h = f2bf(v);
        hi[i*8+j] = h;
        lo[i*8+j] = f2bf(v - bf2f(h));
    }
}
__device__ __forceinline__ void pcat_item(const float* Wa, const float* Wb,
                                          int K1, int K, int KB, int i,
                                          unsigned short* out){
    int l = i & 63, fb = i >> 6;
    int kb = fb % KB, nt = fb / KB;
    int n = nt*16 + (l&15);
    int k0 = kb*32 + ((l>>4)*8);
#pragma unroll
    for (int j=0;j<8;j++){
        int k = k0 + j;
        float v = (k < K1) ? Wa[(size_t)n*K1 + k] : Wb[(size_t)n*(K-K1) + (k-K1)];
        out[i*8+j] = f2bf(v);
    }
}
__device__ __forceinline__ void pproj_item(const float* Wf, const float* Ws, int i,
                                           unsigned short* hi, unsigned short* lo){
    int l = i & 63, fb = i >> 6;
    int kb = fb & 1, nt = fb >> 1;
    int n = nt*16 + (l&15);
    int d = n >> 6, c = n & 63;
    const float* W = (d < 2) ? Wf : Ws;
    int k0 = (d&1)*64 + kb*32 + ((l>>4)*8);
#pragma unroll
    for (int j=0;j<8;j++){
        float v = W[c*130 + k0 + j];
        unsigned short h = f2bf(v);
        hi[i*8+j] = h;
        lo[i*8+j] = f2bf(v - bf2f(h));
    }
}

// ---------------- all weight prep in ONE dispatch ----------------
__global__ void pack_all(
    const float* __restrict__ gWih, const float* __restrict__ gWhh,
    const float* __restrict__ Wdyn,
    const float* __restrict__ l0Whh, const float* __restrict__ l1Wih,
    const float* __restrict__ l1Whh, const float* __restrict__ l0Wih,
    const float* __restrict__ c1Wf, const float* __restrict__ c1Ws,
    const float* __restrict__ c2Wf, const float* __restrict__ c2Ws,
    unsigned short* __restrict__ pWih, unsigned short* __restrict__ pWhh,
    unsigned short* __restrict__ pWdyn,
    unsigned short* __restrict__ B0h, unsigned short* __restrict__ B1h,
    unsigned short* __restrict__ P1h, unsigned short* __restrict__ P1l,
    unsigned short* __restrict__ P2h, unsigned short* __restrict__ P2l,
    unsigned short* __restrict__ GIh, unsigned short* __restrict__ GIl,
    int* __restrict__ cnt, int* __restrict__ gtot)
{
    int i = blockIdx.x*256 + threadIdx.x;
    if (i < 768){ pf_item(gWih, 32, 1, i, pWih); return; }   i -= 768;
    if (i < 1536){ pf_item(gWhh, 64, 2, i, pWhh); return; }  i -= 1536;
    if (i < 512){ pf_item(Wdyn, 64, 2, i, pWdyn); return; }  i -= 512;
    if (i < 8192){ pcat_item(l0Whh, l0Whh, 128, 128, 4, i, B0h); return; } i -= 8192;
    if (i < 16384){ pcat_item(l1Wih, l1Whh, 128, 256, 8, i, B1h); return; } i -= 16384;
    if (i < 2048){ pproj_item(c1Wf, c1Ws, i, P1h, P1l); return; } i -= 2048;
    if (i < 2048){ pproj_item(c2Wf, c2Ws, i, P2h, P2l); return; } i -= 2048;
    if (i < 8192){ phl_item(l0Wih, 128, 4, i, GIh, GIl); return; } i -= 8192;
    if (i < NN){ cnt[i] = 0; return; } i -= NN;
    if (i < 1){ gtot[0] = 0; return; }
}
#define PACK_TOTAL (768+1536+512+8192+16384+2048+2048+8192+NN+1)

// ---------------- GRU encoder v4: MFMA + frag-resident state (unchanged) ----------------
__global__ __launch_bounds__(128) void encoder_mfma(
    const float* __restrict__ x,
    const float* __restrict__ Wip, const float* __restrict__ bip,
    const unsigned short* __restrict__ pWih,
    const unsigned short* __restrict__ pWhh,
    const float* __restrict__ bih, const float* __restrict__ bhh,
    const unsigned short* __restrict__ pWdyn,
    const float* __restrict__ bdyn,
    float* __restrict__ hist)
{
    __shared__ float sxl[512];
    __shared__ unsigned short efh[512], efl[512];      // emb A-frags (kb=0)
    __shared__ unsigned short hfh[2*512], hfl[2*512];  // h A-frags (kb=0,1)
    const int tid = threadIdx.x;
    const int l   = tid & 63;
    const int w   = tid >> 6;
    const int ln  = l & 15, q = l >> 4;
    const int blk = blockIdx.x;

    ((float4*)sxl)[tid] = ((const float4*)x)[(size_t)blk*128 + tid];
    for (int i=tid;i<2*512;i+=128){ hfh[i]=0; hfl[i]=0; }

    const int ek = tid & 31;
    const float w0 = Wip[2*ek], w1 = Wip[2*ek+1], bk = bip[ek];
    const int em0 = tid >> 5;
    const int eoffb = (16*(ek>>3))*8 + (ek&7);

    float bR[2], bZ[2], bNI[2], bNH[2];
    float hprev[2][4];
#pragma unroll
    for (int u=0;u<2;u++){
        int g = 2*w + u;
        int c = g*16 + ln;
        bR[u]  = bih[c]       + bhh[c];
        bZ[u]  = bih[64 + c]  + bhh[64 + c];
        bNI[u] = bih[128 + c];
        bNH[u] = bhh[128 + c];
        hprev[u][0]=0.f; hprev[u][1]=0.f; hprev[u][2]=0.f; hprev[u][3]=0.f;
    }
    const v8s* FIH = (const v8s*)pWih;
    const v8s* FHH = (const v8s*)pWhh;
    const v8s* FDY = (const v8s*)pWdyn;
    __syncthreads();

#pragma unroll 1
    for (int t=0;t<TT;t++){
#pragma unroll
        for (int r=0;r<4;r++){
            int m = em0 + r*4;
            float e = lrelu(w0*sxl[m*32 + 2*t] + w1*sxl[m*32 + 2*t + 1] + bk);
            unsigned short h_ = f2bf(e);
            int off = eoffb + m*8;
            efh[off] = h_;
            efl[off] = f2bf(e - bf2f(h_));
        }
        __syncthreads();                       // BA: frags ready
        v8s eh = *(const v8s*)&efh[l*8];
        v8s el = *(const v8s*)&efl[l*8];
        v8s h0h = *(const v8s*)&hfh[l*8];
        v8s h0l = *(const v8s*)&hfl[l*8];
        v8s h1h = *(const v8s*)&hfh[512 + l*8];
        v8s h1l = *(const v8s*)&hfl[512 + l*8];
        __syncthreads();                       // BB: reads done, writes may begin
#pragma unroll
        for (int u=0;u<2;u++){
            int g = 2*w + u;
            v4f aR = {bR[u],bR[u],bR[u],bR[u]};
            v4f aZ = {bZ[u],bZ[u],bZ[u],bZ[u]};
            v4f aNI= {bNI[u],bNI[u],bNI[u],bNI[u]};
            v4f aNH= {bNH[u],bNH[u],bNH[u],bNH[u]};
            v8s b;
            b = FIH[(g   )*64 + l];   aR = MFMA16(eh,b,aR);  aR = MFMA16(el,b,aR);
            b = FHH[((g)*2+0)*64+l];  aR = MFMA16(h0h,b,aR); aR = MFMA16(h0l,b,aR);
            b = FHH[((g)*2+1)*64+l];  aR = MFMA16(h1h,b,aR); aR = MFMA16(h1l,b,aR);
            b = FIH[(4+g )*64 + l];   aZ = MFMA16(eh,b,aZ);  aZ = MFMA16(el,b,aZ);
            b = FHH[((4+g)*2+0)*64+l];aZ = MFMA16(h0h,b,aZ); aZ = MFMA16(h0l,b,aZ);
            b = FHH[((4+g)*2+1)*64+l];aZ = MFMA16(h1h,b,aZ); aZ = MFMA16(h1l,b,aZ);
            b = FIH[(8+g )*64 + l];   aNI= MFMA16(eh,b,aNI); aNI= MFMA16(el,b,aNI);
            b = FHH[((8+g)*2+0)*64+l];aNH= MFMA16(h0h,b,aNH);aNH= MFMA16(h0l,b,aNH);
            b = FHH[((8+g)*2+1)*64+l];aNH= MFMA16(h1h,b,aNH);aNH= MFMA16(h1l,b,aNH);
#pragma unroll
            for (int i=0;i<4;i++){
                float r_ = fsig(aR[i]);
                float z_ = fsig(aZ[i]);
                float nn_ = ftanh(aNI[i] + r_*aNH[i]);
                float hn = (1.f - z_)*nn_ + z_*hprev[u][i];
                hprev[u][i] = hn;
                int row = q*4 + i, col = g*16 + ln;
                int off = (col>>5)*512 + (16*((col&31)>>3) + row)*8 + (col&7);
                unsigned short hh_ = f2bf(hn);
                hfh[off] = hh_;
                hfl[off] = f2bf(hn - bf2f(hh_));
            }
        }
    }
    __syncthreads();
    {
        v8s a0h,a0l,a1h,a1l;
        lrelu_resplit(*(const v8s*)&hfh[l*8],       *(const v8s*)&hfl[l*8],       a0h, a0l);
        lrelu_resplit(*(const v8s*)&hfh[512 + l*8], *(const v8s*)&hfl[512 + l*8], a1h, a1l);
#pragma unroll
        for (int u=0;u<2;u++){
            int nt = 2*w + u;
            float bb = bdyn[nt*16 + ln];
            v4f acc = {bb,bb,bb,bb};
            v8s b;
            b = FDY[(nt*2+0)*64 + l]; acc = MFMA16(a0h,b,acc); acc = MFMA16(a0l,b,acc);
            b = FDY[(nt*2+1)*64 + l]; acc = MFMA16(a1h,b,acc); acc = MFMA16(a1l,b,acc);
#pragma unroll
            for (int i=0;i<4;i++){
                hist[(size_t)(blk*16 + q*4 + i)*64 + nt*16 + ln] = lrelu(acc[i]);
            }
        }
    }
}

// ---------------- CGConv projections: MFMA (unchanged) ----------------
__global__ __launch_bounds__(256) void proj_mfma(
    const float* __restrict__ xin,
    const unsigned short* __restrict__ Bh, const unsigned short* __restrict__ Bl,
    float* __restrict__ Af, float* __restrict__ Bf,
    float* __restrict__ As, float* __restrict__ Bs)
{
    __shared__ float sx[64*68];
    const int tid = threadIdx.x;
    const int l = tid & 63;
    const int w = tid >> 6;
    const int ln = l & 15, q = l >> 4;
    const int n0 = blockIdx.x*64;

    for (int i=tid;i<64*16;i+=256){
        int nn = i>>4, f4 = i&15;
        float4 v = {0.f,0.f,0.f,0.f};
        if (n0+nn < NN) v = ((const float4*)(xin + (size_t)(n0+nn)*64))[f4];
        *(float4*)&sx[nn*68 + f4*4] = v;
    }
    __syncthreads();

    v8s ah0,al0,ah1,al1;
    cvt8(&sx[(w*16+ln)*68 +      q*8], ah0, al0);
    cvt8(&sx[(w*16+ln)*68 + 32 + q*8], ah1, al1);

    const v8s* FH = (const v8s*)Bh;
    const v8s* FL = (const v8s*)Bl;
#pragma unroll 1
    for (int nt=0; nt<16; nt++){
        v8s bh0 = FH[(nt*2+0)*64 + l], bl0 = FL[(nt*2+0)*64 + l];
        v8s bh1 = FH[(nt*2+1)*64 + l], bl1 = FL[(nt*2+1)*64 + l];
        v4f acc = {0.f,0.f,0.f,0.f};
        acc = MFMA16(ah0,bh0,acc); acc = MFMA16(al0,bh0,acc); acc = MFMA16(ah0,bl0,acc);
        acc = MFMA16(ah1,bh1,acc); acc = MFMA16(al1,bh1,acc); acc = MFMA16(ah1,bl1,acc);
        int d = nt >> 2, col = (nt&3)*16 + ln;
        float* op = (d==0) ? Af : (d==1) ? Bf : (d==2) ? As : Bs;
#pragma unroll
        for (int i=0;i<4;i++){
            int node = n0 + w*16 + q*4 + i;
            if (node < NN) op[(size_t)node*64 + col] = acc[i];
        }
    }
}

// ---------------- dst segment build: histogram + atomic alloc + scatter ----------------
__global__ void count_kernel(const int* __restrict__ ei, int* __restrict__ cnt){
    int e = blockIdx.x*256 + threadIdx.x;
    if (e < EE) atomicAdd(&cnt[ei[EE+e]], 1);
}

__global__ void alloc_kernel(const int* __restrict__ cnt, int* __restrict__ gtot,
                             int* __restrict__ off, int* __restrict__ cur){
    int n = blockIdx.x*256 + threadIdx.x;
    if (n >= NN) return;
    int c = cnt[n];
    int s = atomicAdd(gtot, c);
    off[n] = s;
    cur[n] = s;
}

// scatter + pre-gather (src, e0, e1) into ONE int4 record per edge
// (R11: srcS 4B + eaS 8B were separate arrays -> 2 scattered writes + 2 loads)
__global__ void scatter_kernel(const int* __restrict__ ei, const float* __restrict__ ea,
                               int* __restrict__ cur, int4* __restrict__ recS){
    int e = blockIdx.x*256 + threadIdx.x;
    if (e >= EE) return;
    int d = ei[EE+e];
    int p = atomicAdd(&cur[d], 1);
    int4 r;
    r.x = ei[e];
    r.y = __float_as_int(ea[2*(size_t)e]);
    r.z = __float_as_int(ea[2*(size_t)e+1]);
    r.w = 0;
    recS[p] = r;
}

// ---------------- CGConv aggregate (packed records) ----------------
__global__ __launch_bounds__(256) void cg_agg(
    const float* __restrict__ xin,
    const int4* __restrict__ recS,
    const int* __restrict__ off, const int* __restrict__ cnt,
    const float* __restrict__ Wf, const float* __restrict__ bf,
    const float* __restrict__ Ws, const float* __restrict__ bs,
    const float* __restrict__ Af, const float* __restrict__ Bf,
    const float* __restrict__ As, const float* __restrict__ Bs,
    const float* __restrict__ gamma, const float* __restrict__ beta,
    const float* __restrict__ mean, const float* __restrict__ var,
    float* __restrict__ outp)
{
    const int tid = threadIdx.x;
    const int c = tid & 63, wid = tid >> 6;
    const int n = blockIdx.x*4 + wid;
    if (n >= NN) return;

    const float wf0 = Wf[c*130+128], wf1 = Wf[c*130+129], bfc = bf[c];
    const float ws0 = Ws[c*130+128], ws1 = Ws[c*130+129], bsc = bs[c];
    const float afd = Af[(size_t)n*64+c] + bfc, asd = As[(size_t)n*64+c] + bsc;
    const float* Bfc = Bf + c;
    const float* Bsc = Bs + c;

    float acc = 0.f;
    int i = off[n];
    const int i1 = i + cnt[n];
#pragma unroll 1
    for (; i+1 < i1; i += 2){
        int4 r0 = recS[i], r1 = recS[i+1];
        float e00 = __int_as_float(r0.y), e01 = __int_as_float(r0.z);
        float e10 = __int_as_float(r1.y), e11 = __int_as_float(r1.z);
        float bf0v = Bfc[(size_t)r0.x*64], bs0v = Bsc[(size_t)r0.x*64];
        float bf1v = Bfc[(size_t)r1.x*64], bs1v = Bsc[(size_t)r1.x*64];
        float gf0 = afd + bf0v + wf0*e00 + wf1*e01;
        float gs0 = asd + bs0v + ws0*e00 + ws1*e01;
        float gf1 = afd + bf1v + wf0*e10 + wf1*e11;
        float gs1 = asd + bs1v + ws0*e10 + ws1*e11;
        acc += fsig(gf0)*fsoftplus(gs0);
        acc += fsig(gf1)*fsoftplus(gs1);
    }
    if (i < i1){
        int4 r0 = recS[i];
        float e00 = __int_as_float(r0.y), e01 = __int_as_float(r0.z);
        float gf = afd + Bfc[(size_t)r0.x*64] + wf0*e00 + wf1*e01;
        float gs = asd + Bsc[(size_t)r0.x*64] + ws0*e00 + ws1*e01;
        acc += fsig(gf)*fsoftplus(gs);
    }
    float bn = (acc - mean[c])*rsqrtf(var[c]+BN_EPS)*gamma[c] + beta[c];
    outp[(size_t)n*64+c] = xin[(size_t)n*64+c] + bn;
}

// ---------------- target gather + nbrs linear + concat (unchanged) ----------------
__global__ __launch_bounds__(256) void target_kernel(
    const float* __restrict__ hist, const float* __restrict__ f2,
    const int* __restrict__ tgt,
    const float* __restrict__ Wn, const float* __restrict__ bn_,
    float* __restrict__ enc)
{
    const int tid=threadIdx.x;
    const int c = tid&63, q = tid>>6;
    const int b = blockIdx.x*4 + q;
    if (b>=BB) return;
    const int n = tgt[b];
    float a = bn_[c];
#pragma unroll
    for (int k=0;k<ENC;k++) a += Wn[c*64+k]*f2[(size_t)n*64+k];
    enc[(size_t)b*128 + 64 + c] = lrelu(a);
    enc[(size_t)b*128 + c]      = hist[(size_t)n*64+c];
}

// ---------------- gi0 via MFMA (unchanged) ----------------
__global__ __launch_bounds__(512) void gi0_mfma(
    const float* __restrict__ enc,
    const unsigned short* __restrict__ GIh, const unsigned short* __restrict__ GIl,
    const float* __restrict__ bih0, const float* __restrict__ bhh0,
    float* __restrict__ gi0)
{
    __shared__ float senc[16*132];
    const int tid = threadIdx.x;
    const int l = tid & 63;
    const int w = tid >> 6;
    const int ln = l & 15, q = l >> 4;
    const int b0 = blockIdx.x*16;

    for (int i=tid;i<16*32;i+=512){
        int row = i>>5, f4 = i&31;
        *(float4*)&senc[row*132 + f4*4] = ((const float4*)(enc + (size_t)(b0+row)*128))[f4];
    }
    __syncthreads();

    v8s ah[4], al[4];
#pragma unroll
    for (int kb=0;kb<4;kb++) cvt8(&senc[ln*132 + kb*32 + q*8], ah[kb], al[kb]);

    const v8s* FH = (const v8s*)GIh;
    const v8s* FL = (const v8s*)GIl;
#pragma unroll
    for (int u=0;u<4;u++){
        int nt = w*4 + u;
        int col = nt*16 + ln;
        float bb = bih0[col] + bhh0[col];
        v4f acc = {bb,bb,bb,bb};
#pragma unroll
        for (int kb=0;kb<4;kb++){
            v8s bh = FH[(nt*4+kb)*64 + l];
            v8s bl = FL[(nt*4+kb)*64 + l];
            acc = MFMA16(ah[kb],bh,acc); acc = MFMA16(al[kb],bh,acc); acc = MFMA16(ah[kb],bl,acc);
        }
#pragma unroll
        for (int i=0;i<4;i++)
            gi0[(size_t)(b0 + q*4 + i)*512 + col] = acc[i];
    }
}

// ---------------- 2-layer LSTM decoder v7: ONE barrier/step ----------------
// R11 post-mortem: 3 barriers/step = 10.5k cyc/step vs ~1.5k work. v7:
// h0 AND h1 double-buffered -> layer0 {read h0[p], write h0[1-p]}, B1,
// layer1 {read h0[1-p]+h1[p], write h1[1-p]}. Hazard audit: every
// write-after-read pair on a given buffer is separated by exactly one B1
// (readers pre-B1(t) / writer post-B1(t), or readers pre-B1(t+1) / writer
// post-B1(t+1)). Out-proj has NO barrier: per-wave partials reduced via
// __shfl_xor over the 16 j-lanes, atomicAdd into d_out (zeroed by memset,
// bias added by wave 0 only). Dual hi/lo accumulators halve MFMA chains.
// LDS = 131072(W0) + 16384(h0 x2) + 16384(h1 x2) = 163840 (exactly max).
#define LMB 16
__global__ __launch_bounds__(512)
__attribute__((amdgpu_waves_per_eu(2,2)))
void lstm_mfma(
    const float* __restrict__ gi0,
    const unsigned short* __restrict__ B0h,
    const unsigned short* __restrict__ B1h,
    const float* __restrict__ bih1, const float* __restrict__ bhh1,
    const float* __restrict__ Wop, const float* __restrict__ bop,
    float* __restrict__ outp)
{
    __shared__ int4 sW0[32*4*64];                                // 131072 B
    __shared__ unsigned short h0hi[2][4*512], h0lo[2][4*512];    // 16384 B
    __shared__ unsigned short h1hi[2][4*512], h1lo[2][4*512];    // 16384 B
    const int tid = threadIdx.x;
    const int l = tid & 63;
    const int w = tid >> 6;
    const int c = l & 15;
    const int q = l >> 4;
    const int j = w*16 + c;
    const int b0 = blockIdx.x*LMB;

    {
        const int4* F0 = (const int4*)B0h;
        for (int i=tid;i<32*4*64;i+=512) sW0[i] = F0[i];
    }
    for (int i=tid;i<4*512;i+=512){
        h0hi[0][i]=0; h0lo[0][i]=0; h0hi[1][i]=0; h0lo[1][i]=0;
        h1hi[0][i]=0; h1lo[0][i]=0; h1hi[1][i]=0; h1lo[1][i]=0;
    }

    int4 W1r[32];
    {
        const int4* F1 = (const int4*)B1h;
#pragma unroll
        for (int g=0;g<4;g++)
#pragma unroll
            for (int kb=0;kb<8;kb++) W1r[g*8+kb] = F1[((g*8+w)*8 + kb)*64 + l];
#pragma unroll
        for (int i=0;i<32;i++)
            asm volatile("" : "+v"(W1r[i].x), "+v"(W1r[i].y), "+v"(W1r[i].z), "+v"(W1r[i].w));
    }

    float rgi[4][4];
#pragma unroll
    for (int g=0;g<4;g++)
#pragma unroll
        for (int i=0;i<4;i++)
            rgi[g][i] = gi0[(size_t)(b0 + q*4 + i)*512 + g*128 + j];

    float b1[4];
#pragma unroll
    for (int g=0;g<4;g++) b1[g] = bih1[g*128+j] + bhh1[g*128+j];
    float c0[4] = {0,0,0,0}, c1[4] = {0,0,0,0};
    const float wop0 = Wop[j], wop1 = Wop[128 + j];
    const float bo0 = bop[0], bo1 = bop[1];
    const int kbw = j>>5, qw = (j>>3)&3, jw = j&7;
    __syncthreads();

    int p = 0;
#pragma unroll 1
    for (int t=0;t<OUTL;t++){
        // ---- layer 0: read h0[p], write h0[1-p]; dual hi/lo accumulators ----
        v4f aH[4], aL[4];
#pragma unroll
        for (int g=0;g<4;g++){
            v4f t4 = {rgi[g][0], rgi[g][1], rgi[g][2], rgi[g][3]};
            aH[g] = t4;
            v4f z = {0.f,0.f,0.f,0.f};
            aL[g] = z;
        }
#pragma unroll
        for (int kb=0;kb<4;kb++){
            v8s ah = *(const v8s*)&h0hi[p][kb*512 + l*8];
            v8s al = *(const v8s*)&h0lo[p][kb*512 + l*8];
#pragma unroll
            for (int g=0;g<4;g++){
                v8s bfr = as_v8s(sW0[((g*8+w)*4 + kb)*64 + l]);
                aH[g] = MFMA16(ah, bfr, aH[g]);
                aL[g] = MFMA16(al, bfr, aL[g]);
            }
        }
#pragma unroll
        for (int i=0;i<4;i++){
            float gi_ = aH[0][i]+aL[0][i], gf_ = aH[1][i]+aL[1][i];
            float gg_ = aH[2][i]+aL[2][i], go_ = aH[3][i]+aL[3][i];
            c0[i] = fsig(gf_)*c0[i] + fsig(gi_)*ftanh(gg_);
            float hn = fsig(go_)*ftanh(c0[i]);
            int off = kbw*512 + (qw*16 + q*4 + i)*8 + jw;
            unsigned short h = f2bf(hn);
            h0hi[1-p][off] = h;
            h0lo[1-p][off] = f2bf(hn - bf2f(h));
        }
        __syncthreads();   // B1: the ONLY barrier per step

        // ---- layer 1: read h0[1-p] + h1[p], write h1[1-p] ----
        v4f bH[4], bL[4];
#pragma unroll
        for (int g=0;g<4;g++){
            v4f t4={b1[g],b1[g],b1[g],b1[g]}; bH[g]=t4;
            v4f z={0.f,0.f,0.f,0.f}; bL[g]=z;
        }
#pragma unroll
        for (int kb=0;kb<8;kb++){
            const unsigned short* hb = (kb<4) ? h0hi[1-p] : h1hi[p];
            const unsigned short* lb = (kb<4) ? h0lo[1-p] : h1lo[p];
            int kk = kb & 3;
            v8s ah = *(const v8s*)&hb[kk*512 + l*8];
            v8s al = *(const v8s*)&lb[kk*512 + l*8];
#pragma unroll
            for (int g=0;g<4;g++){
                bH[g] = MFMA16(ah, as_v8s(W1r[g*8+kb]), bH[g]);
                bL[g] = MFMA16(al, as_v8s(W1r[g*8+kb]), bL[g]);
            }
        }
        float h1new[4];
#pragma unroll
        for (int i=0;i<4;i++){
            float gi_ = bH[0][i]+bL[0][i], gf_ = bH[1][i]+bL[1][i];
            float gg_ = bH[2][i]+bL[2][i], go_ = bH[3][i]+bL[3][i];
            c1[i] = fsig(gf_)*c1[i] + fsig(gi_)*ftanh(gg_);
            h1new[i] = fsig(go_)*ftanh(c1[i]);
            int off = kbw*512 + (qw*16 + q*4 + i)*8 + jw;
            unsigned short h = f2bf(h1new[i]);
            h1hi[1-p][off] = h;
            h1lo[1-p][off] = f2bf(h1new[i] - bf2f(h));
        }

        // ---- out-proj: register partials, wave shuffle-reduce, atomicAdd ----
        {
            float v0[4], v1[4];
#pragma unroll
            for (int i=0;i<4;i++){ v0[i] = h1new[i]*wop0; v1[i] = h1new[i]*wop1; }
#pragma unroll
            for (int m=1;m<16;m<<=1){
#pragma unroll
                for (int i=0;i<4;i++){
                    v0[i] += __shfl_xor(v0[i], m);
                    v1[i] += __shfl_xor(v1[i], m);
                }
            }
            if (c == 0){
                if (w == 0){
#pragma unroll
                    for (int i=0;i<4;i++){ v0[i] += bo0; v1[i] += bo1; }
                }
#pragma unroll
                for (int i=0;i<4;i++){
                    size_t base = (size_t)(b0 + q*4 + i)*(OUTL*2) + t*2;
                    atomicAdd(&outp[base    ], v0[i]);
                    atomicAdd(&outp[base + 1], v1[i]);
                }
            }
        }
        p ^= 1;
    }
}

extern "C" void kernel_launch(void* const* d_in, const int* in_sizes, int n_in,
                              void* d_out, int out_size, void* d_ws, size_t ws_size,
                              hipStream_t stream)
{
    const float* x    = (const float*)d_in[0];
    const int*   ei   = (const int*)d_in[1];
    const float* ea   = (const float*)d_in[2];
    const int*   tgt  = (const int*)d_in[3];
    const float* Wip  = (const float*)d_in[4];
    const float* bip  = (const float*)d_in[5];
    const float* gWih = (const float*)d_in[6];
    const float* gWhh = (const float*)d_in[7];
    const float* gbih = (const float*)d_in[8];
    const float* gbhh = (const float*)d_in[9];
    const float* Wdyn = (const float*)d_in[10];
    const float* bdyn = (const float*)d_in[11];
    const float* c1Wf=(const float*)d_in[12]; const float* c1bf=(const float*)d_in[13];
    const float* c1Ws=(const float*)d_in[14]; const float* c1bs=(const float*)d_in[15];
    const float* c1g =(const float*)d_in[16]; const float* c1b =(const float*)d_in[17];
    const float* c1m =(const float*)d_in[18]; const float* c1v =(const float*)d_in[19];
    const float* c2Wf=(const float*)d_in[20]; const float* c2bf=(const float*)d_in[21];
    const float* c2Ws=(const float*)d_in[22]; const float* c2bs=(const float*)d_in[23];
    const float* c2g =(const float*)d_in[24]; const float* c2b =(const float*)d_in[25];
    const float* c2m =(const float*)d_in[26]; const float* c2v =(const float*)d_in[27];
    const float* Wn  =(const float*)d_in[28]; const float* bn_ =(const float*)d_in[29];
    const float* l0Wih=(const float*)d_in[30]; const float* l0Whh=(const float*)d_in[31];
    const float* l0bih=(const float*)d_in[32]; const float* l0bhh=(const float*)d_in[33];
    const float* l1Wih=(const float*)d_in[34]; const float* l1Whh=(const float*)d_in[35];
    const float* l1bih=(const float*)d_in[36]; const float* l1bhh=(const float*)d_in[37];
    const float* Wop =(const float*)d_in[38]; const float* bop=(const float*)d_in[39];

    float* ws = (float*)d_ws;
    size_t o = 0;
    float* hist = ws + o; o += (size_t)NN*ENC;
    float* f1   = ws + o; o += (size_t)NN*ENC;
    float* f2   = ws + o; o += (size_t)NN*ENC;
    float* Af   = ws + o; o += (size_t)NN*ENC;
    float* Bf   = ws + o; o += (size_t)NN*ENC;
    float* As   = ws + o; o += (size_t)NN*ENC;
    float* Bs   = ws + o; o += (size_t)NN*ENC;
    float* enc  = ws + o; o += (size_t)BB*2*ENC;
    float* gi0  = ws + o; o += (size_t)BB*4*DEC;
    unsigned short* pWih  = (unsigned short*)(ws + o); o += (size_t)12*64*8/2;
    unsigned short* pWhh  = (unsigned short*)(ws + o); o += (size_t)24*64*8/2;
    unsigned short* pWdyn = (unsigned short*)(ws + o); o += (size_t)8*64*8/2;
    unsigned short* B0h = (unsigned short*)(ws + o); o += (size_t)32*4*64*8/2;
    unsigned short* B1h = (unsigned short*)(ws + o); o += (size_t)32*8*64*8/2;
    unsigned short* P1h = (unsigned short*)(ws + o); o += (size_t)2048*8/2;
    unsigned short* P1l = (unsigned short*)(ws + o); o += (size_t)2048*8/2;
    unsigned short* P2h = (unsigned short*)(ws + o); o += (size_t)2048*8/2;
    unsigned short* P2l = (unsigned short*)(ws + o); o += (size_t)2048*8/2;
    unsigned short* GIh = (unsigned short*)(ws + o); o += (size_t)8192*8/2;
    unsigned short* GIl = (unsigned short*)(ws + o); o += (size_t)8192*8/2;
    int* cnt    = (int*)(ws + o); o += NN;
    int* offv   = (int*)(ws + o); o += NN+1;
    int* curv   = (int*)(ws + o); o += NN;
    int* gtot   = (int*)(ws + o); o += 1;
    o = (o + 3) & ~(size_t)3;               // align to 16B for int4 records
    int4* recS  = (int4*)(ws + o); o += (size_t)4*EE;

    // --- all weight prep + cnt/gtot zero in one dispatch ---
    pack_all<<<(PACK_TOTAL+255)/256, 256, 0, stream>>>(
        gWih, gWhh, Wdyn, l0Whh, l1Wih, l1Whh, l0Wih,
        c1Wf, c1Ws, c2Wf, c2Ws,
        pWih, pWhh, pWdyn, B0h, B1h, P1h, P1l, P2h, P2l, GIh, GIl, cnt, gtot);

    // --- zero output (lstm accumulates via atomics) ---
    (void)hipMemsetAsync(d_out, 0, (size_t)out_size*sizeof(float), stream);

    // --- dst segment build (order-free atomic allocation) ---
    count_kernel<<<(EE+255)/256, 256, 0, stream>>>(ei, cnt);
    alloc_kernel<<<(NN+255)/256, 256, 0, stream>>>(cnt, gtot, offv, curv);
    scatter_kernel<<<(EE+255)/256, 256, 0, stream>>>(ei, ea, curv, recS);

    // --- history encoder (MFMA) ---
    encoder_mfma<<<NN/16, 128, 0, stream>>>(x, Wip, bip, pWih, pWhh, gbih, gbhh, pWdyn, bdyn, hist);

    // --- CGConv 1 ---
    proj_mfma<<<(NN+63)/64, 256, 0, stream>>>(hist, P1h, P1l, Af,Bf,As,Bs);
    cg_agg<<<(NN+3)/4, 256, 0, stream>>>(hist, recS, offv, cnt,
                                         c1Wf,c1bf,c1Ws,c1bs, Af,Bf,As,Bs,
                                         c1g,c1b,c1m,c1v, f1);

    // --- CGConv 2 ---
    proj_mfma<<<(NN+63)/64, 256, 0, stream>>>(f1, P2h, P2l, Af,Bf,As,Bs);
    cg_agg<<<(NN+3)/4, 256, 0, stream>>>(f1, recS, offv, cnt,
                                         c2Wf,c2bf,c2Ws,c2bs, Af,Bf,As,Bs,
                                         c2g,c2b,c2m,c2v, f2);

    // --- target encoding ---
    target_kernel<<<(BB+3)/4, 256, 0, stream>>>(hist, f2, tgt, Wn, bn_, enc);

    // --- LSTM decoder prep (MFMA gi0) ---
    gi0_mfma<<<BB/16, 512, 0, stream>>>(enc, GIh, GIl, l0bih, l0bhh, gi0);

    // --- LSTM decoder (1-barrier t-loop) ---
    lstm_mfma<<<BB/LMB, 512, 0, stream>>>(gi0, B0h, B1h,
                                          l1bih, l1bhh, Wop, bop, (float*)d_out);
}